// Round 2
// baseline (709.724 us; speedup 1.0000x reference)
//
#include <hip/hip_runtime.h>

// ---------------- CSR build ----------------

__global__ void k_hist(const int* __restrict__ dst, int* __restrict__ cnt, int E) {
    int e = blockIdx.x * blockDim.x + threadIdx.x;
    if (e < E) atomicAdd(&cnt[dst[e]], 1);
}

__global__ void k_dinv(const int* __restrict__ cnt, float* __restrict__ dinv, int n) {
    int i = blockIdx.x * blockDim.x + threadIdx.x;
    if (i < n) dinv[i] = rsqrtf((float)(cnt[i] + 1));  // +1 self-loop
}

__global__ void k_scan_a(const int* __restrict__ cnt, int* __restrict__ roff,
                         int* __restrict__ bsums, int n) {
    __shared__ int s[256];
    int t = threadIdx.x;
    int i = blockIdx.x * 256 + t;
    int v = (i < n) ? cnt[i] : 0;
    s[t] = v;
    __syncthreads();
    for (int o = 1; o < 256; o <<= 1) {
        int x = (t >= o) ? s[t - o] : 0;
        __syncthreads();
        s[t] += x;
        __syncthreads();
    }
    if (i < n) roff[i] = s[t] - v;            // exclusive (local)
    if (t == 255) bsums[blockIdx.x] = s[255]; // block total
}

__global__ void k_scan_b(int* __restrict__ bsums, int nb) {
    __shared__ int s[512];
    int t = threadIdx.x;
    int v = (t < nb) ? bsums[t] : 0;
    s[t] = v;
    __syncthreads();
    for (int o = 1; o < 512; o <<= 1) {
        int x = (t >= o) ? s[t - o] : 0;
        __syncthreads();
        s[t] += x;
        __syncthreads();
    }
    if (t < nb) bsums[t] = s[t] - v;          // exclusive over blocks
}

__global__ void k_scan_c(int* __restrict__ roff, const int* __restrict__ bsums, int n) {
    int i = blockIdx.x * 256 + threadIdx.x;
    if (i < n) roff[i] += bsums[blockIdx.x];
}

// cursor-fill: afterwards roff[v] = END offset of segment v; start(v) = roff[v-1]
__global__ void k_fill(const int* __restrict__ src, const int* __restrict__ dst,
                       int* __restrict__ roff, int* __restrict__ csr, int E) {
    int e = blockIdx.x * blockDim.x + threadIdx.x;
    if (e < E) {
        int d = dst[e];
        int pos = atomicAdd(&roff[d], 1);
        csr[pos] = src[e];
    }
}

// ---------------- fused head weights ----------------
// Wf0 = lin0_w @ out_w[0:64,:], Wf1 = lin1_w @ out_w[64:128,:]
// bf = out_b + lin0_b@out_w_top + lin1_b@out_w_bot
__global__ void k_fuse(const float* __restrict__ lin0_w, const float* __restrict__ lin0_b,
                       const float* __restrict__ lin1_w, const float* __restrict__ lin1_b,
                       const float* __restrict__ out_w, const float* __restrict__ out_b,
                       float* __restrict__ Wf0, float* __restrict__ Wf1, float* __restrict__ bf) {
    int idx = blockIdx.x * blockDim.x + threadIdx.x;
    if (idx < 2560) {
        int i = idx / 40, j = idx % 40;
        float a = 0.f;
        for (int k = 0; k < 64; k++) a += lin0_w[i * 64 + k] * out_w[k * 40 + j];
        Wf0[idx] = a;
    } else if (idx < 5120) {
        int r = idx - 2560;
        int i = r / 40, j = r % 40;
        float a = 0.f;
        for (int k = 0; k < 64; k++) a += lin1_w[i * 64 + k] * out_w[(64 + k) * 40 + j];
        Wf1[r] = a;
    } else if (idx < 5160) {
        int j = idx - 5120;
        float a = out_b[j];
        for (int k = 0; k < 64; k++) {
            a += lin0_b[k] * out_w[k * 40 + j];
            a += lin1_b[k] * out_w[(64 + k) * 40 + j];
        }
        bf[j] = a;
    }
}

// ---------------- GEMMs ----------------

// C[n,64] = A[n,128] @ W[128,64]; 32 rows/block, 8 outs/thread
__global__ __launch_bounds__(256) void k_gemm_128(const float* __restrict__ A,
                                                  const float* __restrict__ W,
                                                  float* __restrict__ C, int n) {
    __shared__ float ws[128 * 64];
    __shared__ float xs[32 * 129];
    int t = threadIdx.x;
    for (int idx = t; idx < 2048; idx += 256) {
        float4 u = *(const float4*)(W + idx * 4);
        ws[idx * 4] = u.x; ws[idx * 4 + 1] = u.y; ws[idx * 4 + 2] = u.z; ws[idx * 4 + 3] = u.w;
    }
    int r0 = blockIdx.x * 32;
    for (int idx = t; idx < 1024; idx += 256) {
        int base = idx * 4;
        int r = base >> 7, k = base & 127;
        int gr = r0 + r; if (gr >= n) gr = n - 1;
        float4 u = *(const float4*)(A + (size_t)gr * 128 + k);
        xs[r * 129 + k]     = u.x;
        xs[r * 129 + k + 1] = u.y;
        xs[r * 129 + k + 2] = u.z;
        xs[r * 129 + k + 3] = u.w;
    }
    __syncthreads();
    int row = t >> 3, c0 = (t & 7) << 3;
    float acc[8];
#pragma unroll
    for (int j = 0; j < 8; j++) acc[j] = 0.f;
    for (int k = 0; k < 128; k++) {
        float a = xs[row * 129 + k];
#pragma unroll
        for (int j = 0; j < 8; j++) acc[j] += a * ws[k * 64 + c0 + j];
    }
    int gr = r0 + row;
    if (gr < n) {
        float4 v0 = {acc[0], acc[1], acc[2], acc[3]};
        float4 v1 = {acc[4], acc[5], acc[6], acc[7]};
        *(float4*)(C + (size_t)gr * 64 + c0) = v0;
        *(float4*)(C + (size_t)gr * 64 + c0 + 4) = v1;
    }
}

// C[n,64] = A[n,64] @ W[64,64]
__global__ __launch_bounds__(256) void k_gemm_64(const float* __restrict__ A,
                                                 const float* __restrict__ W,
                                                 float* __restrict__ C, int n) {
    __shared__ float ws[64 * 64];
    __shared__ float xs[32 * 65];
    int t = threadIdx.x;
    for (int idx = t; idx < 1024; idx += 256) {
        float4 u = *(const float4*)(W + idx * 4);
        ws[idx * 4] = u.x; ws[idx * 4 + 1] = u.y; ws[idx * 4 + 2] = u.z; ws[idx * 4 + 3] = u.w;
    }
    int r0 = blockIdx.x * 32;
    for (int idx = t; idx < 512; idx += 256) {
        int base = idx * 4;
        int r = base >> 6, k = base & 63;
        int gr = r0 + r; if (gr >= n) gr = n - 1;
        float4 u = *(const float4*)(A + (size_t)gr * 64 + k);
        xs[r * 65 + k]     = u.x;
        xs[r * 65 + k + 1] = u.y;
        xs[r * 65 + k + 2] = u.z;
        xs[r * 65 + k + 3] = u.w;
    }
    __syncthreads();
    int row = t >> 3, c0 = (t & 7) << 3;
    float acc[8];
#pragma unroll
    for (int j = 0; j < 8; j++) acc[j] = 0.f;
    for (int k = 0; k < 64; k++) {
        float a = xs[row * 65 + k];
#pragma unroll
        for (int j = 0; j < 8; j++) acc[j] += a * ws[k * 64 + c0 + j];
    }
    int gr = r0 + row;
    if (gr < n) {
        float4 v0 = {acc[0], acc[1], acc[2], acc[3]};
        float4 v1 = {acc[4], acc[5], acc[6], acc[7]};
        *(float4*)(C + (size_t)gr * 64 + c0) = v0;
        *(float4*)(C + (size_t)gr * 64 + c0 + 4) = v1;
    }
}

// O[n,40] = H[n,64] @ Wf[64,40]; 5 outs/thread
__global__ __launch_bounds__(256) void k_gemm40(const float* __restrict__ H,
                                                const float* __restrict__ Wf,
                                                float* __restrict__ O, int n) {
    __shared__ float wfs[64 * 40];
    __shared__ float hs[32 * 65];
    int t = threadIdx.x;
    for (int idx = t; idx < 640; idx += 256) {
        float4 u = *(const float4*)(Wf + idx * 4);
        wfs[idx * 4] = u.x; wfs[idx * 4 + 1] = u.y; wfs[idx * 4 + 2] = u.z; wfs[idx * 4 + 3] = u.w;
    }
    int r0 = blockIdx.x * 32;
    for (int idx = t; idx < 512; idx += 256) {
        int base = idx * 4;
        int r = base >> 6, k = base & 63;
        int gr = r0 + r; if (gr >= n) gr = n - 1;
        float4 u = *(const float4*)(H + (size_t)gr * 64 + k);
        hs[r * 65 + k] = u.x; hs[r * 65 + k + 1] = u.y; hs[r * 65 + k + 2] = u.z; hs[r * 65 + k + 3] = u.w;
    }
    __syncthreads();
    int row = t >> 3, c0 = (t & 7) * 5;
    float acc[5] = {0.f, 0.f, 0.f, 0.f, 0.f};
    for (int k = 0; k < 64; k++) {
        float a = hs[row * 65 + k];
#pragma unroll
        for (int j = 0; j < 5; j++) acc[j] += a * wfs[k * 40 + c0 + j];
    }
    int gr = r0 + row;
    if (gr < n) {
#pragma unroll
        for (int j = 0; j < 5; j++) O[(size_t)gr * 40 + c0 + j] = acc[j];
    }
}

// out[n,40] = O + H2 @ Wf1 + bf   (O read/modify/write in place)
__global__ __launch_bounds__(256) void k_gemm40_final(const float* __restrict__ H,
                                                      const float* __restrict__ Wf,
                                                      const float* __restrict__ bf,
                                                      float* __restrict__ out, int n) {
    __shared__ float wfs[64 * 40];
    __shared__ float hs[32 * 65];
    int t = threadIdx.x;
    for (int idx = t; idx < 640; idx += 256) {
        float4 u = *(const float4*)(Wf + idx * 4);
        wfs[idx * 4] = u.x; wfs[idx * 4 + 1] = u.y; wfs[idx * 4 + 2] = u.z; wfs[idx * 4 + 3] = u.w;
    }
    int r0 = blockIdx.x * 32;
    for (int idx = t; idx < 512; idx += 256) {
        int base = idx * 4;
        int r = base >> 6, k = base & 63;
        int gr = r0 + r; if (gr >= n) gr = n - 1;
        float4 u = *(const float4*)(H + (size_t)gr * 64 + k);
        hs[r * 65 + k] = u.x; hs[r * 65 + k + 1] = u.y; hs[r * 65 + k + 2] = u.z; hs[r * 65 + k + 3] = u.w;
    }
    __syncthreads();
    int row = t >> 3, c0 = (t & 7) * 5;
    float acc[5] = {0.f, 0.f, 0.f, 0.f, 0.f};
    for (int k = 0; k < 64; k++) {
        float a = hs[row * 65 + k];
#pragma unroll
        for (int j = 0; j < 5; j++) acc[j] += a * wfs[k * 40 + c0 + j];
    }
    int gr = r0 + row;
    if (gr < n) {
#pragma unroll
        for (int j = 0; j < 5; j++) {
            size_t p = (size_t)gr * 40 + c0 + j;
            out[p] = out[p] + acc[j] + bf[c0 + j];
        }
    }
}

// ---------------- aggregation: one wave per node, lane = feature ----------------
// H[v] = elu( dinv[v]^2*T[v] + sum_{(s,v)} dinv[s]*dinv[v]*T[s] + bias )
__global__ __launch_bounds__(256) void k_agg(const float* __restrict__ T,
                                             const int* __restrict__ csr,
                                             const int* __restrict__ roffE,  // END offsets
                                             const float* __restrict__ dinv,
                                             const float* __restrict__ bias,
                                             float* __restrict__ H, int n) {
    int lane = threadIdx.x & 63;
    int v = blockIdx.x * 4 + (threadIdx.x >> 6);
    if (v >= n) return;
    int start = (v == 0) ? 0 : roffE[v - 1];
    int end = roffE[v];
    float dv = dinv[v];
    float acc = dv * dv * T[(size_t)v * 64 + lane];
    for (int j = start; j < end; j++) {
        int s = csr[j];
        float w = dinv[s] * dv;
        acc += w * T[(size_t)s * 64 + lane];
    }
    acc += bias[lane];
    H[(size_t)v * 64 + lane] = (acc > 0.f) ? acc : (__expf(acc) - 1.f);
}

// ---------------- launch ----------------

extern "C" void kernel_launch(void* const* d_in, const int* in_sizes, int n_in,
                              void* d_out, int out_size, void* d_ws, size_t ws_size,
                              hipStream_t stream) {
    const float* x       = (const float*)d_in[0];
    const int*   eidx    = (const int*)d_in[1];
    const float* conv0_w = (const float*)d_in[2];
    const float* conv0_b = (const float*)d_in[3];
    const float* lin0_w  = (const float*)d_in[4];
    const float* lin0_b  = (const float*)d_in[5];
    const float* conv1_w = (const float*)d_in[6];
    const float* conv1_b = (const float*)d_in[7];
    const float* lin1_w  = (const float*)d_in[8];
    const float* lin1_b  = (const float*)d_in[9];
    const float* out_w   = (const float*)d_in[10];
    const float* out_b   = (const float*)d_in[11];

    int n = in_sizes[0] / 128;
    int E = in_sizes[1] / 2;
    const int* src = eidx;
    const int* dst = eidx + E;

    char* wsb = (char*)d_ws;
    auto al = [](size_t v) { return (v + 4095) & ~(size_t)4095; };
    size_t o = 0;
    int*   cnt   = (int*)(wsb + o);   o = al(o + (size_t)n * 4);
    float* dinv  = (float*)(wsb + o); o = al(o + (size_t)n * 4);
    int*   roff  = (int*)(wsb + o);   o = al(o + (size_t)n * 4);
    int*   bsums = (int*)(wsb + o);   o = al(o + 512 * 4);
    int*   csr   = (int*)(wsb + o);   o = al(o + (size_t)E * 4);
    float* Wf0   = (float*)(wsb + o); o = al(o + 2560 * 4);
    float* Wf1   = (float*)(wsb + o); o = al(o + 2560 * 4);
    float* bfv   = (float*)(wsb + o); o = al(o + 40 * 4);
    float* A     = (float*)(wsb + o); o = al(o + (size_t)n * 64 * 4);
    float* B     = (float*)(wsb + o); o = al(o + (size_t)n * 64 * 4);
    // total ~59 MB; head partial accumulates directly in d_out (fp32 n*40)
    float* O = (float*)d_out;

    int gE = (E + 255) / 256;
    int gN = (n + 255) / 256;   // must be <= 512 for scan_b (n <= 131072: OK)
    int gR = (n + 31) / 32;
    int gV = (n + 3) / 4;

    hipMemsetAsync(cnt, 0, (size_t)n * 4, stream);
    k_hist<<<gE, 256, 0, stream>>>(dst, cnt, E);
    k_dinv<<<gN, 256, 0, stream>>>(cnt, dinv, n);
    k_scan_a<<<gN, 256, 0, stream>>>(cnt, roff, bsums, n);
    k_scan_b<<<1, 512, 0, stream>>>(bsums, gN);
    k_scan_c<<<gN, 256, 0, stream>>>(roff, bsums, n);
    k_fill<<<gE, 256, 0, stream>>>(src, dst, roff, csr, E);
    k_fuse<<<(5160 + 255) / 256, 256, 0, stream>>>(lin0_w, lin0_b, lin1_w, lin1_b, out_w, out_b,
                                                   Wf0, Wf1, bfv);

    // layer 0
    k_gemm_128<<<gR, 256, 0, stream>>>(x, conv0_w, A, n);
    k_agg<<<gV, 256, 0, stream>>>(A, csr, roff, dinv, conv0_b, B, n);
    // head contribution of h (write O = B @ Wf0 into d_out)
    k_gemm40<<<gR, 256, 0, stream>>>(B, Wf0, O, n);
    // layer 1
    k_gemm_64<<<gR, 256, 0, stream>>>(B, conv1_w, A, n);
    k_agg<<<gV, 256, 0, stream>>>(A, csr, roff, dinv, conv1_b, B, n);
    // final head: out = O + B @ Wf1 + bf
    k_gemm40_final<<<gR, 256, 0, stream>>>(B, Wf1, bfv, O, n);
}

// Round 3
// 512.662 us; speedup vs baseline: 1.3844x; 1.3844x over previous
//
#include <hip/hip_runtime.h>

#define DEVFN __device__ __forceinline__

DEVFN float bf2f(unsigned short u) {
    union { unsigned int i; float f; } c;
    c.i = ((unsigned int)u) << 16;
    return c.f;
}

DEVFN unsigned short f2bf(float f) {
    union { float f; unsigned int i; } c;
    c.f = f;
    unsigned int u = c.i;
    return (unsigned short)((u + 0x7FFFu + ((u >> 16) & 1u)) >> 16);  // RNE
}

// ---------------- CSR build ----------------

__global__ void k_hist(const int* __restrict__ dst, int* __restrict__ cnt, int E) {
    int e = blockIdx.x * blockDim.x + threadIdx.x;
    if (e < E) atomicAdd(&cnt[dst[e]], 1);
}

// scan (exclusive, per block) + dinv in one kernel
__global__ void k_scan_a(const int* __restrict__ cnt, float* __restrict__ dinv,
                         int* __restrict__ roff, int* __restrict__ bsums, int n) {
    __shared__ int s[256];
    int t = threadIdx.x;
    int i = blockIdx.x * 256 + t;
    int v = (i < n) ? cnt[i] : 0;
    if (i < n) dinv[i] = rsqrtf((float)(v + 1));  // +1 self-loop
    s[t] = v;
    __syncthreads();
    for (int o = 1; o < 256; o <<= 1) {
        int x = (t >= o) ? s[t - o] : 0;
        __syncthreads();
        s[t] += x;
        __syncthreads();
    }
    if (i < n) roff[i] = s[t] - v;            // exclusive (local)
    if (t == 255) bsums[blockIdx.x] = s[255]; // block total
}

__global__ void k_scan_b(int* __restrict__ bsums, int nb) {
    __shared__ int s[512];
    int t = threadIdx.x;
    int v = (t < nb) ? bsums[t] : 0;
    s[t] = v;
    __syncthreads();
    for (int o = 1; o < 512; o <<= 1) {
        int x = (t >= o) ? s[t - o] : 0;
        __syncthreads();
        s[t] += x;
        __syncthreads();
    }
    if (t < nb) bsums[t] = s[t] - v;          // exclusive over blocks
}

__global__ void k_scan_c(int* __restrict__ roff, const int* __restrict__ bsums, int n) {
    int i = blockIdx.x * 256 + threadIdx.x;
    if (i < n) roff[i] += bsums[blockIdx.x];
}

// cursor-fill: afterwards roff[v] = END offset of segment v; start(v) = roff[v-1]
__global__ void k_fill(const int* __restrict__ src, const int* __restrict__ dst,
                       int* __restrict__ roff, int* __restrict__ csr, int E) {
    int e = blockIdx.x * blockDim.x + threadIdx.x;
    if (e < E) {
        int d = dst[e];
        int pos = atomicAdd(&roff[d], 1);
        csr[pos] = src[e];
    }
}

// ---------------- fused head weights ----------------
__global__ void k_fuse(const float* __restrict__ lin0_w, const float* __restrict__ lin0_b,
                       const float* __restrict__ lin1_w, const float* __restrict__ lin1_b,
                       const float* __restrict__ out_w, const float* __restrict__ out_b,
                       float* __restrict__ Wf0, float* __restrict__ Wf1, float* __restrict__ bf) {
    int idx = blockIdx.x * blockDim.x + threadIdx.x;
    if (idx < 2560) {
        int i = idx / 40, j = idx % 40;
        float a = 0.f;
        for (int k = 0; k < 64; k++) a += lin0_w[i * 64 + k] * out_w[k * 40 + j];
        Wf0[idx] = a;
    } else if (idx < 5120) {
        int r = idx - 2560;
        int i = r / 40, j = r % 40;
        float a = 0.f;
        for (int k = 0; k < 64; k++) a += lin1_w[i * 64 + k] * out_w[(64 + k) * 40 + j];
        Wf1[r] = a;
    } else if (idx < 5160) {
        int j = idx - 5120;
        float a = out_b[j];
        for (int k = 0; k < 64; k++) {
            a += lin0_b[k] * out_w[k * 40 + j];
            a += lin1_b[k] * out_w[(64 + k) * 40 + j];
        }
        bf[j] = a;
    }
}

// ---------------- transform GEMMs, epilogue folds dinv and casts bf16 ----------------

// Cb[n,64] bf16 = dinv[r] * (A[n,128] @ W[128,64]); 32 rows/block, 8 outs/thread
__global__ __launch_bounds__(256) void k_gemm_128(const float* __restrict__ A,
                                                  const float* __restrict__ W,
                                                  const float* __restrict__ dinv,
                                                  unsigned short* __restrict__ Cb, int n) {
    __shared__ float ws[128 * 64];
    __shared__ float xs[32 * 129];
    int t = threadIdx.x;
    for (int idx = t; idx < 2048; idx += 256) {
        float4 u = *(const float4*)(W + idx * 4);
        ws[idx * 4] = u.x; ws[idx * 4 + 1] = u.y; ws[idx * 4 + 2] = u.z; ws[idx * 4 + 3] = u.w;
    }
    int r0 = blockIdx.x * 32;
    for (int idx = t; idx < 1024; idx += 256) {
        int base = idx * 4;
        int r = base >> 7, k = base & 127;
        int gr = r0 + r; if (gr >= n) gr = n - 1;
        float4 u = *(const float4*)(A + (size_t)gr * 128 + k);
        xs[r * 129 + k]     = u.x;
        xs[r * 129 + k + 1] = u.y;
        xs[r * 129 + k + 2] = u.z;
        xs[r * 129 + k + 3] = u.w;
    }
    __syncthreads();
    int row = t >> 3, c0 = (t & 7) << 3;
    float acc[8];
#pragma unroll
    for (int j = 0; j < 8; j++) acc[j] = 0.f;
    for (int k = 0; k < 128; k++) {
        float a = xs[row * 129 + k];
#pragma unroll
        for (int j = 0; j < 8; j++) acc[j] += a * ws[k * 64 + c0 + j];
    }
    int gr = r0 + row;
    if (gr < n) {
        float dv = dinv[gr];
        union { unsigned short h[8]; uint4 u; } p;
#pragma unroll
        for (int j = 0; j < 8; j++) p.h[j] = f2bf(dv * acc[j]);
        *(uint4*)(Cb + (size_t)gr * 64 + c0) = p.u;
    }
}

// Cb[n,64] bf16 = dinv[r] * (A[n,64] @ W[64,64])
__global__ __launch_bounds__(256) void k_gemm_64(const float* __restrict__ A,
                                                 const float* __restrict__ W,
                                                 const float* __restrict__ dinv,
                                                 unsigned short* __restrict__ Cb, int n) {
    __shared__ float ws[64 * 64];
    __shared__ float xs[32 * 65];
    int t = threadIdx.x;
    for (int idx = t; idx < 1024; idx += 256) {
        float4 u = *(const float4*)(W + idx * 4);
        ws[idx * 4] = u.x; ws[idx * 4 + 1] = u.y; ws[idx * 4 + 2] = u.z; ws[idx * 4 + 3] = u.w;
    }
    int r0 = blockIdx.x * 32;
    for (int idx = t; idx < 512; idx += 256) {
        int base = idx * 4;
        int r = base >> 6, k = base & 63;
        int gr = r0 + r; if (gr >= n) gr = n - 1;
        float4 u = *(const float4*)(A + (size_t)gr * 64 + k);
        xs[r * 65 + k]     = u.x;
        xs[r * 65 + k + 1] = u.y;
        xs[r * 65 + k + 2] = u.z;
        xs[r * 65 + k + 3] = u.w;
    }
    __syncthreads();
    int row = t >> 3, c0 = (t & 7) << 3;
    float acc[8];
#pragma unroll
    for (int j = 0; j < 8; j++) acc[j] = 0.f;
    for (int k = 0; k < 64; k++) {
        float a = xs[row * 65 + k];
#pragma unroll
        for (int j = 0; j < 8; j++) acc[j] += a * ws[k * 64 + c0 + j];
    }
    int gr = r0 + row;
    if (gr < n) {
        float dv = dinv[gr];
        union { unsigned short h[8]; uint4 u; } p;
#pragma unroll
        for (int j = 0; j < 8; j++) p.h[j] = f2bf(dv * acc[j]);
        *(uint4*)(Cb + (size_t)gr * 64 + c0) = p.u;
    }
}

// ---------------- head GEMMs ----------------

// O[n,40] = H[n,64] @ Wf[64,40]; 5 outs/thread
__global__ __launch_bounds__(256) void k_gemm40(const float* __restrict__ H,
                                                const float* __restrict__ Wf,
                                                float* __restrict__ O, int n) {
    __shared__ float wfs[64 * 40];
    __shared__ float hs[32 * 65];
    int t = threadIdx.x;
    for (int idx = t; idx < 640; idx += 256) {
        float4 u = *(const float4*)(Wf + idx * 4);
        wfs[idx * 4] = u.x; wfs[idx * 4 + 1] = u.y; wfs[idx * 4 + 2] = u.z; wfs[idx * 4 + 3] = u.w;
    }
    int r0 = blockIdx.x * 32;
    for (int idx = t; idx < 512; idx += 256) {
        int base = idx * 4;
        int r = base >> 6, k = base & 63;
        int gr = r0 + r; if (gr >= n) gr = n - 1;
        float4 u = *(const float4*)(H + (size_t)gr * 64 + k);
        hs[r * 65 + k] = u.x; hs[r * 65 + k + 1] = u.y; hs[r * 65 + k + 2] = u.z; hs[r * 65 + k + 3] = u.w;
    }
    __syncthreads();
    int row = t >> 3, c0 = (t & 7) * 5;
    float acc[5] = {0.f, 0.f, 0.f, 0.f, 0.f};
    for (int k = 0; k < 64; k++) {
        float a = hs[row * 65 + k];
#pragma unroll
        for (int j = 0; j < 5; j++) acc[j] += a * wfs[k * 40 + c0 + j];
    }
    int gr = r0 + row;
    if (gr < n) {
#pragma unroll
        for (int j = 0; j < 5; j++) O[(size_t)gr * 40 + c0 + j] = acc[j];
    }
}

// out[n,40] += H2 @ Wf1 + bf
__global__ __launch_bounds__(256) void k_gemm40_final(const float* __restrict__ H,
                                                      const float* __restrict__ Wf,
                                                      const float* __restrict__ bf,
                                                      float* __restrict__ out, int n) {
    __shared__ float wfs[64 * 40];
    __shared__ float hs[32 * 65];
    int t = threadIdx.x;
    for (int idx = t; idx < 640; idx += 256) {
        float4 u = *(const float4*)(Wf + idx * 4);
        wfs[idx * 4] = u.x; wfs[idx * 4 + 1] = u.y; wfs[idx * 4 + 2] = u.z; wfs[idx * 4 + 3] = u.w;
    }
    int r0 = blockIdx.x * 32;
    for (int idx = t; idx < 512; idx += 256) {
        int base = idx * 4;
        int r = base >> 6, k = base & 63;
        int gr = r0 + r; if (gr >= n) gr = n - 1;
        float4 u = *(const float4*)(H + (size_t)gr * 64 + k);
        hs[r * 65 + k] = u.x; hs[r * 65 + k + 1] = u.y; hs[r * 65 + k + 2] = u.z; hs[r * 65 + k + 3] = u.w;
    }
    __syncthreads();
    int row = t >> 3, c0 = (t & 7) * 5;
    float acc[5] = {0.f, 0.f, 0.f, 0.f, 0.f};
    for (int k = 0; k < 64; k++) {
        float a = hs[row * 65 + k];
#pragma unroll
        for (int j = 0; j < 5; j++) acc[j] += a * wfs[k * 40 + c0 + j];
    }
    int gr = r0 + row;
    if (gr < n) {
#pragma unroll
        for (int j = 0; j < 5; j++) {
            size_t p = (size_t)gr * 40 + c0 + j;
            out[p] = out[p] + acc[j] + bf[c0 + j];
        }
    }
}

// ---------------- aggregation ----------------
// T is bf16 with dinv pre-folded: T'[s] = dinv[s] * (transform(s))
// H[v] = elu( dv * (T'[v] + sum_{(s,v)} T'[s]) + bias ),  dv = rsqrt(deg+1)
__global__ __launch_bounds__(256) void k_agg(const unsigned short* __restrict__ T,
                                             const int* __restrict__ csr,
                                             const int* __restrict__ roffE,  // END offsets
                                             const float* __restrict__ bias,
                                             float* __restrict__ H, int n) {
    int lane = threadIdx.x & 63;
    int v = blockIdx.x * 4 + (threadIdx.x >> 6);
    if (v >= n) return;
    int start = (v == 0) ? 0 : roffE[v - 1];
    int end = roffE[v];
    float dv = rsqrtf((float)(end - start + 1));
    float acc = bf2f(T[(size_t)v * 64 + lane]);  // self-loop
    for (int base = start; base < end; base += 64) {
        int m = end - base; if (m > 64) m = 64;
        int e = (lane < m) ? csr[base + lane] : 0;  // coalesced chunk of edge srcs
        int j = 0;
        for (; j + 3 < m; j += 4) {
            int s0 = __shfl(e, j);
            int s1 = __shfl(e, j + 1);
            int s2 = __shfl(e, j + 2);
            int s3 = __shfl(e, j + 3);
            float f0 = bf2f(T[(size_t)s0 * 64 + lane]);
            float f1 = bf2f(T[(size_t)s1 * 64 + lane]);
            float f2 = bf2f(T[(size_t)s2 * 64 + lane]);
            float f3 = bf2f(T[(size_t)s3 * 64 + lane]);
            acc += f0; acc += f1; acc += f2; acc += f3;
        }
        for (; j < m; j++) {
            int s = __shfl(e, j);
            acc += bf2f(T[(size_t)s * 64 + lane]);
        }
    }
    acc = dv * acc + bias[lane];
    H[(size_t)v * 64 + lane] = (acc > 0.f) ? acc : (__expf(acc) - 1.f);
}

// ---------------- launch ----------------

extern "C" void kernel_launch(void* const* d_in, const int* in_sizes, int n_in,
                              void* d_out, int out_size, void* d_ws, size_t ws_size,
                              hipStream_t stream) {
    const float* x       = (const float*)d_in[0];
    const int*   eidx    = (const int*)d_in[1];
    const float* conv0_w = (const float*)d_in[2];
    const float* conv0_b = (const float*)d_in[3];
    const float* lin0_w  = (const float*)d_in[4];
    const float* lin0_b  = (const float*)d_in[5];
    const float* conv1_w = (const float*)d_in[6];
    const float* conv1_b = (const float*)d_in[7];
    const float* lin1_w  = (const float*)d_in[8];
    const float* lin1_b  = (const float*)d_in[9];
    const float* out_w   = (const float*)d_in[10];
    const float* out_b   = (const float*)d_in[11];

    int n = in_sizes[0] / 128;
    int E = in_sizes[1] / 2;
    const int* src = eidx;
    const int* dst = eidx + E;

    char* wsb = (char*)d_ws;
    auto al = [](size_t v) { return (v + 4095) & ~(size_t)4095; };
    size_t o = 0;
    int*            cnt   = (int*)(wsb + o);            o = al(o + (size_t)n * 4);
    float*          dinv  = (float*)(wsb + o);          o = al(o + (size_t)n * 4);
    int*            roff  = (int*)(wsb + o);            o = al(o + (size_t)n * 4);
    int*            bsums = (int*)(wsb + o);            o = al(o + 512 * 4);
    int*            csr   = (int*)(wsb + o);            o = al(o + (size_t)E * 4);
    float*          Wf0   = (float*)(wsb + o);          o = al(o + 2560 * 4);
    float*          Wf1   = (float*)(wsb + o);          o = al(o + 2560 * 4);
    float*          bfv   = (float*)(wsb + o);          o = al(o + 40 * 4);
    unsigned short* Ab    = (unsigned short*)(wsb + o); o = al(o + (size_t)n * 64 * 2);
    float*          B     = (float*)(wsb + o);          o = al(o + (size_t)n * 64 * 4);
    float* O = (float*)d_out;  // head partial accumulates in d_out (fp32 n*40)

    int gE = (E + 255) / 256;
    int gN = (n + 255) / 256;   // must be <= 512 for scan_b (n <= 131072: OK)
    int gR = (n + 31) / 32;
    int gV = (n + 3) / 4;

    hipMemsetAsync(cnt, 0, (size_t)n * 4, stream);
    k_hist<<<gE, 256, 0, stream>>>(dst, cnt, E);
    k_scan_a<<<gN, 256, 0, stream>>>(cnt, dinv, roff, bsums, n);
    k_scan_b<<<1, 512, 0, stream>>>(bsums, gN);
    k_scan_c<<<gN, 256, 0, stream>>>(roff, bsums, n);
    k_fill<<<gE, 256, 0, stream>>>(src, dst, roff, csr, E);
    k_fuse<<<(5160 + 255) / 256, 256, 0, stream>>>(lin0_w, lin0_b, lin1_w, lin1_b, out_w, out_b,
                                                   Wf0, Wf1, bfv);

    // layer 0
    k_gemm_128<<<gR, 256, 0, stream>>>(x, conv0_w, dinv, Ab, n);
    k_agg<<<gV, 256, 0, stream>>>(Ab, csr, roff, conv0_b, B, n);
    // head contribution of h (write O = B @ Wf0 into d_out)
    k_gemm40<<<gR, 256, 0, stream>>>(B, Wf0, O, n);
    // layer 1
    k_gemm_64<<<gR, 256, 0, stream>>>(B, conv1_w, dinv, Ab, n);
    k_agg<<<gV, 256, 0, stream>>>(Ab, csr, roff, conv1_b, B, n);
    // final head: out = O + B @ Wf1 + bf
    k_gemm40_final<<<gR, 256, 0, stream>>>(B, Wf1, bfv, O, n);
}

// Round 5
// 495.740 us; speedup vs baseline: 1.4316x; 1.0341x over previous
//
#include <hip/hip_runtime.h>

#define DEVFN __device__ __forceinline__

DEVFN float bf2f(unsigned short u) {
    union { unsigned int i; float f; } c;
    c.i = ((unsigned int)u) << 16;
    return c.f;
}

DEVFN unsigned short f2bf(float f) {
    union { float f; unsigned int i; } c;
    c.f = f;
    unsigned int u = c.i;
    return (unsigned short)((u + 0x7FFFu + ((u >> 16) & 1u)) >> 16);  // RNE
}

DEVFN float4 unp(uint2 u) {
    float4 f;
    f.x = bf2f((unsigned short)(u.x & 0xFFFFu));
    f.y = bf2f((unsigned short)(u.x >> 16));
    f.z = bf2f((unsigned short)(u.y & 0xFFFFu));
    f.w = bf2f((unsigned short)(u.y >> 16));
    return f;
}

// ---------------- CSR build (round-3 proven chain) ----------------

__global__ void k_hist(const int* __restrict__ dst, int* __restrict__ cnt, int E) {
    int e = blockIdx.x * blockDim.x + threadIdx.x;
    if (e < E) atomicAdd(&cnt[dst[e]], 1);
}

// scan (exclusive, per block) + dinv in one kernel
__global__ void k_scan_a(const int* __restrict__ cnt, float* __restrict__ dinv,
                         int* __restrict__ roff, int* __restrict__ bsums, int n) {
    __shared__ int s[256];
    int t = threadIdx.x;
    int i = blockIdx.x * 256 + t;
    int v = (i < n) ? cnt[i] : 0;
    if (i < n) dinv[i] = rsqrtf((float)(v + 1));  // +1 self-loop
    s[t] = v;
    __syncthreads();
    for (int o = 1; o < 256; o <<= 1) {
        int x = (t >= o) ? s[t - o] : 0;
        __syncthreads();
        s[t] += x;
        __syncthreads();
    }
    if (i < n) roff[i] = s[t] - v;            // exclusive (local)
    if (t == 255) bsums[blockIdx.x] = s[255]; // block total
}

__global__ void k_scan_b(int* __restrict__ bsums, int nb) {
    __shared__ int s[512];
    int t = threadIdx.x;
    int v = (t < nb) ? bsums[t] : 0;
    s[t] = v;
    __syncthreads();
    for (int o = 1; o < 512; o <<= 1) {
        int x = (t >= o) ? s[t - o] : 0;
        __syncthreads();
        s[t] += x;
        __syncthreads();
    }
    if (t < nb) bsums[t] = s[t] - v;          // exclusive over blocks
}

__global__ void k_scan_c(int* __restrict__ roff, const int* __restrict__ bsums, int n) {
    int i = blockIdx.x * 256 + threadIdx.x;
    if (i < n) roff[i] += bsums[blockIdx.x];
}

// cursor-fill: afterwards roff[v] = END offset of segment v; start(v) = roff[v-1]
__global__ void k_fill(const int* __restrict__ src, const int* __restrict__ dst,
                       int* __restrict__ roff, int* __restrict__ csr, int E) {
    int e = blockIdx.x * blockDim.x + threadIdx.x;
    if (e < E) {
        int d = dst[e];
        int pos = atomicAdd(&roff[d], 1);
        csr[pos] = src[e];
    }
}

// ---------------- fused head weights ----------------
__global__ void k_fuse(const float* __restrict__ lin0_w, const float* __restrict__ lin0_b,
                       const float* __restrict__ lin1_w, const float* __restrict__ lin1_b,
                       const float* __restrict__ out_w, const float* __restrict__ out_b,
                       float* __restrict__ Wf0, float* __restrict__ Wf1, float* __restrict__ bf) {
    int idx = blockIdx.x * blockDim.x + threadIdx.x;
    if (idx < 2560) {
        int i = idx / 40, j = idx % 40;
        float a = 0.f;
        for (int k = 0; k < 64; k++) a += lin0_w[i * 64 + k] * out_w[k * 40 + j];
        Wf0[idx] = a;
    } else if (idx < 5120) {
        int r = idx - 2560;
        int i = r / 40, j = r % 40;
        float a = 0.f;
        for (int k = 0; k < 64; k++) a += lin1_w[i * 64 + k] * out_w[(64 + k) * 40 + j];
        Wf1[r] = a;
    } else if (idx < 5160) {
        int j = idx - 5120;
        float a = out_b[j];
        for (int k = 0; k < 64; k++) {
            a += lin0_b[k] * out_w[k * 40 + j];
            a += lin1_b[k] * out_w[(64 + k) * 40 + j];
        }
        bf[j] = a;
    }
}

// ---------------- transform GEMMs, epilogue folds dinv and casts bf16 ----------------

__global__ __launch_bounds__(256) void k_gemm_128(const float* __restrict__ A,
                                                  const float* __restrict__ W,
                                                  const float* __restrict__ dinv,
                                                  unsigned short* __restrict__ Cb, int n) {
    __shared__ float ws[128 * 64];
    __shared__ float xs[32 * 129];
    int t = threadIdx.x;
    for (int idx = t; idx < 2048; idx += 256) {
        float4 u = *(const float4*)(W + idx * 4);
        ws[idx * 4] = u.x; ws[idx * 4 + 1] = u.y; ws[idx * 4 + 2] = u.z; ws[idx * 4 + 3] = u.w;
    }
    int r0 = blockIdx.x * 32;
    for (int idx = t; idx < 1024; idx += 256) {
        int base = idx * 4;
        int r = base >> 7, k = base & 127;
        int gr = r0 + r; if (gr >= n) gr = n - 1;
        float4 u = *(const float4*)(A + (size_t)gr * 128 + k);
        xs[r * 129 + k]     = u.x;
        xs[r * 129 + k + 1] = u.y;
        xs[r * 129 + k + 2] = u.z;
        xs[r * 129 + k + 3] = u.w;
    }
    __syncthreads();
    int row = t >> 3, c0 = (t & 7) << 3;
    float acc[8];
#pragma unroll
    for (int j = 0; j < 8; j++) acc[j] = 0.f;
    for (int k = 0; k < 128; k++) {
        float a = xs[row * 129 + k];
#pragma unroll
        for (int j = 0; j < 8; j++) acc[j] += a * ws[k * 64 + c0 + j];
    }
    int gr = r0 + row;
    if (gr < n) {
        float dv = dinv[gr];
        union { unsigned short h[8]; uint4 u; } p;
#pragma unroll
        for (int j = 0; j < 8; j++) p.h[j] = f2bf(dv * acc[j]);
        *(uint4*)(Cb + (size_t)gr * 64 + c0) = p.u;
    }
}

__global__ __launch_bounds__(256) void k_gemm_64(const float* __restrict__ A,
                                                 const float* __restrict__ W,
                                                 const float* __restrict__ dinv,
                                                 unsigned short* __restrict__ Cb, int n) {
    __shared__ float ws[64 * 64];
    __shared__ float xs[32 * 65];
    int t = threadIdx.x;
    for (int idx = t; idx < 1024; idx += 256) {
        float4 u = *(const float4*)(W + idx * 4);
        ws[idx * 4] = u.x; ws[idx * 4 + 1] = u.y; ws[idx * 4 + 2] = u.z; ws[idx * 4 + 3] = u.w;
    }
    int r0 = blockIdx.x * 32;
    for (int idx = t; idx < 512; idx += 256) {
        int base = idx * 4;
        int r = base >> 6, k = base & 63;
        int gr = r0 + r; if (gr >= n) gr = n - 1;
        float4 u = *(const float4*)(A + (size_t)gr * 64 + k);
        xs[r * 65 + k]     = u.x;
        xs[r * 65 + k + 1] = u.y;
        xs[r * 65 + k + 2] = u.z;
        xs[r * 65 + k + 3] = u.w;
    }
    __syncthreads();
    int row = t >> 3, c0 = (t & 7) << 3;
    float acc[8];
#pragma unroll
    for (int j = 0; j < 8; j++) acc[j] = 0.f;
    for (int k = 0; k < 64; k++) {
        float a = xs[row * 65 + k];
#pragma unroll
        for (int j = 0; j < 8; j++) acc[j] += a * ws[k * 64 + c0 + j];
    }
    int gr = r0 + row;
    if (gr < n) {
        float dv = dinv[gr];
        union { unsigned short h[8]; uint4 u; } p;
#pragma unroll
        for (int j = 0; j < 8; j++) p.h[j] = f2bf(dv * acc[j]);
        *(uint4*)(Cb + (size_t)gr * 64 + c0) = p.u;
    }
}

// ---------------- head GEMMs ----------------

__global__ __launch_bounds__(256) void k_gemm40(const float* __restrict__ H,
                                                const float* __restrict__ Wf,
                                                float* __restrict__ O, int n) {
    __shared__ float wfs[64 * 40];
    __shared__ float hs[32 * 65];
    int t = threadIdx.x;
    for (int idx = t; idx < 640; idx += 256) {
        float4 u = *(const float4*)(Wf + idx * 4);
        wfs[idx * 4] = u.x; wfs[idx * 4 + 1] = u.y; wfs[idx * 4 + 2] = u.z; wfs[idx * 4 + 3] = u.w;
    }
    int r0 = blockIdx.x * 32;
    for (int idx = t; idx < 512; idx += 256) {
        int base = idx * 4;
        int r = base >> 6, k = base & 63;
        int gr = r0 + r; if (gr >= n) gr = n - 1;
        float4 u = *(const float4*)(H + (size_t)gr * 64 + k);
        hs[r * 65 + k] = u.x; hs[r * 65 + k + 1] = u.y; hs[r * 65 + k + 2] = u.z; hs[r * 65 + k + 3] = u.w;
    }
    __syncthreads();
    int row = t >> 3, c0 = (t & 7) * 5;
    float acc[5] = {0.f, 0.f, 0.f, 0.f, 0.f};
    for (int k = 0; k < 64; k++) {
        float a = hs[row * 65 + k];
#pragma unroll
        for (int j = 0; j < 5; j++) acc[j] += a * wfs[k * 40 + c0 + j];
    }
    int gr = r0 + row;
    if (gr < n) {
#pragma unroll
        for (int j = 0; j < 5; j++) O[(size_t)gr * 40 + c0 + j] = acc[j];
    }
}

__global__ __launch_bounds__(256) void k_gemm40_final(const float* __restrict__ H,
                                                      const float* __restrict__ Wf,
                                                      const float* __restrict__ bf,
                                                      float* __restrict__ out, int n) {
    __shared__ float wfs[64 * 40];
    __shared__ float hs[32 * 65];
    int t = threadIdx.x;
    for (int idx = t; idx < 640; idx += 256) {
        float4 u = *(const float4*)(Wf + idx * 4);
        wfs[idx * 4] = u.x; wfs[idx * 4 + 1] = u.y; wfs[idx * 4 + 2] = u.z; wfs[idx * 4 + 3] = u.w;
    }
    int r0 = blockIdx.x * 32;
    for (int idx = t; idx < 512; idx += 256) {
        int base = idx * 4;
        int r = base >> 6, k = base & 63;
        int gr = r0 + r; if (gr >= n) gr = n - 1;
        float4 u = *(const float4*)(H + (size_t)gr * 64 + k);
        hs[r * 65 + k] = u.x; hs[r * 65 + k + 1] = u.y; hs[r * 65 + k + 2] = u.z; hs[r * 65 + k + 3] = u.w;
    }
    __syncthreads();
    int row = t >> 3, c0 = (t & 7) * 5;
    float acc[5] = {0.f, 0.f, 0.f, 0.f, 0.f};
    for (int k = 0; k < 64; k++) {
        float a = hs[row * 65 + k];
#pragma unroll
        for (int j = 0; j < 5; j++) acc[j] += a * wfs[k * 40 + c0 + j];
    }
    int gr = r0 + row;
    if (gr < n) {
#pragma unroll
        for (int j = 0; j < 5; j++) {
            size_t p = (size_t)gr * 40 + c0 + j;
            out[p] = out[p] + acc[j] + bf[c0 + j];
        }
    }
}

// ---------------- aggregation: wave/node, 4 lane-groups x 16, 16 rows in flight ----------------
// lane = 16q+h; group q fetches edge j+4t+q, 8 B/lane (features 4h..4h+3).
// H[v] = elu( dv*(T'[v] + sum T'[s]) + bias ),  T' = dinv-folded bf16
__global__ __launch_bounds__(256) void k_agg(const unsigned short* __restrict__ T,
                                             const int* __restrict__ csr,
                                             const int* __restrict__ roffE,  // END offsets
                                             const float* __restrict__ bias,
                                             float* __restrict__ H, int n) {
    int lane = threadIdx.x & 63;
    int q = lane >> 4, h = lane & 15;
    int v = blockIdx.x * 4 + (threadIdx.x >> 6);
    if (v >= n) return;
    int start = (v == 0) ? 0 : roffE[v - 1];
    int end = roffE[v];
    float dv = rsqrtf((float)(end - start + 1));
    float4 acc = {0.f, 0.f, 0.f, 0.f};
    if (q == 0) {  // self-loop row (counted once)
        uint2 u = *(const uint2*)(T + (size_t)v * 64 + h * 4);
        float4 f = unp(u);
        acc.x += f.x; acc.y += f.y; acc.z += f.z; acc.w += f.w;
    }
    for (int base = start; base < end; base += 64) {
        int m = end - base; if (m > 64) m = 64;
        int e = (lane < m) ? csr[base + lane] : 0;
        int j = 0;
        for (; j + 16 <= m; j += 16) {
            int s0 = __shfl(e, j + q);
            int s1 = __shfl(e, j + 4 + q);
            int s2 = __shfl(e, j + 8 + q);
            int s3 = __shfl(e, j + 12 + q);
            uint2 u0 = *(const uint2*)(T + (size_t)s0 * 64 + h * 4);
            uint2 u1 = *(const uint2*)(T + (size_t)s1 * 64 + h * 4);
            uint2 u2 = *(const uint2*)(T + (size_t)s2 * 64 + h * 4);
            uint2 u3 = *(const uint2*)(T + (size_t)s3 * 64 + h * 4);
            float4 f0 = unp(u0), f1 = unp(u1), f2 = unp(u2), f3 = unp(u3);
            acc.x += (f0.x + f1.x) + (f2.x + f3.x);
            acc.y += (f0.y + f1.y) + (f2.y + f3.y);
            acc.z += (f0.z + f1.z) + (f2.z + f3.z);
            acc.w += (f0.w + f1.w) + (f2.w + f3.w);
        }
        for (; j + 4 <= m; j += 4) {
            int s = __shfl(e, j + q);
            uint2 u = *(const uint2*)(T + (size_t)s * 64 + h * 4);
            float4 f = unp(u);
            acc.x += f.x; acc.y += f.y; acc.z += f.z; acc.w += f.w;
        }
        if (j < m) {
            int jj = j + q;
            int s = __shfl(e, jj & 63);
            if (jj < m) {
                uint2 u = *(const uint2*)(T + (size_t)s * 64 + h * 4);
                float4 f = unp(u);
                acc.x += f.x; acc.y += f.y; acc.z += f.z; acc.w += f.w;
            }
        }
    }
    // reduce across the 4 q-groups (xor on lane bits 4,5)
    acc.x += __shfl_xor(acc.x, 16); acc.y += __shfl_xor(acc.y, 16);
    acc.z += __shfl_xor(acc.z, 16); acc.w += __shfl_xor(acc.w, 16);
    acc.x += __shfl_xor(acc.x, 32); acc.y += __shfl_xor(acc.y, 32);
    acc.z += __shfl_xor(acc.z, 32); acc.w += __shfl_xor(acc.w, 32);
    if (q == 0) {
        float4 bb = *(const float4*)(bias + h * 4);
        float4 r;
        r.x = dv * acc.x + bb.x;
        r.y = dv * acc.y + bb.y;
        r.z = dv * acc.z + bb.z;
        r.w = dv * acc.w + bb.w;
        r.x = (r.x > 0.f) ? r.x : (__expf(r.x) - 1.f);
        r.y = (r.y > 0.f) ? r.y : (__expf(r.y) - 1.f);
        r.z = (r.z > 0.f) ? r.z : (__expf(r.z) - 1.f);
        r.w = (r.w > 0.f) ? r.w : (__expf(r.w) - 1.f);
        *(float4*)(H + (size_t)v * 64 + h * 4) = r;
    }
}

// ---------------- launch ----------------

extern "C" void kernel_launch(void* const* d_in, const int* in_sizes, int n_in,
                              void* d_out, int out_size, void* d_ws, size_t ws_size,
                              hipStream_t stream) {
    const float* x       = (const float*)d_in[0];
    const int*   eidx    = (const int*)d_in[1];
    const float* conv0_w = (const float*)d_in[2];
    const float* conv0_b = (const float*)d_in[3];
    const float* lin0_w  = (const float*)d_in[4];
    const float* lin0_b  = (const float*)d_in[5];
    const float* conv1_w = (const float*)d_in[6];
    const float* conv1_b = (const float*)d_in[7];
    const float* lin1_w  = (const float*)d_in[8];
    const float* lin1_b  = (const float*)d_in[9];
    const float* out_w   = (const float*)d_in[10];
    const float* out_b   = (const float*)d_in[11];

    int n = in_sizes[0] / 128;
    int E = in_sizes[1] / 2;
    const int* src = eidx;
    const int* dst = eidx + E;

    char* wsb = (char*)d_ws;
    auto al = [](size_t v) { return (v + 4095) & ~(size_t)4095; };
    size_t o = 0;
    int*            cnt   = (int*)(wsb + o);            o = al(o + (size_t)n * 4);
    float*          dinv  = (float*)(wsb + o);          o = al(o + (size_t)n * 4);
    int*            roff  = (int*)(wsb + o);            o = al(o + (size_t)n * 4);
    int*            bsums = (int*)(wsb + o);            o = al(o + 512 * 4);
    int*            csr   = (int*)(wsb + o);            o = al(o + (size_t)E * 4);
    float*          Wf0   = (float*)(wsb + o);          o = al(o + 2560 * 4);
    float*          Wf1   = (float*)(wsb + o);          o = al(o + 2560 * 4);
    float*          bfv   = (float*)(wsb + o);          o = al(o + 40 * 4);
    unsigned short* Ab    = (unsigned short*)(wsb + o); o = al(o + (size_t)n * 64 * 2);
    float*          B     = (float*)(wsb + o);          o = al(o + (size_t)n * 64 * 4);
    float* O = (float*)d_out;  // head partial accumulates in d_out (fp32 n*40)

    int gE = (E + 255) / 256;
    int gN = (n + 255) / 256;   // must be <= 512 for scan_b (n <= 131072: OK)
    int gR = (n + 31) / 32;
    int gV = (n + 3) / 4;

    hipMemsetAsync(cnt, 0, (size_t)n * 4, stream);
    k_hist<<<gE, 256, 0, stream>>>(dst, cnt, E);
    k_scan_a<<<gN, 256, 0, stream>>>(cnt, dinv, roff, bsums, n);
    k_scan_b<<<1, 512, 0, stream>>>(bsums, gN);
    k_scan_c<<<gN, 256, 0, stream>>>(roff, bsums, n);
    k_fill<<<gE, 256, 0, stream>>>(src, dst, roff, csr, E);
    k_fuse<<<(5160 + 255) / 256, 256, 0, stream>>>(lin0_w, lin0_b, lin1_w, lin1_b, out_w, out_b,
                                                   Wf0, Wf1, bfv);

    // layer 0
    k_gemm_128<<<gR, 256, 0, stream>>>(x, conv0_w, dinv, Ab, n);
    k_agg<<<gV, 256, 0, stream>>>(Ab, csr, roff, conv0_b, B, n);
    // head contribution of h (write O = B @ Wf0 into d_out)
    k_gemm40<<<gR, 256, 0, stream>>>(B, Wf0, O, n);
    // layer 1
    k_gemm_64<<<gR, 256, 0, stream>>>(B, conv1_w, dinv, Ab, n);
    k_agg<<<gV, 256, 0, stream>>>(Ab, csr, roff, conv1_b, B, n);
    // final head: out = O + B @ Wf1 + bf
    k_gemm40_final<<<gR, 256, 0, stream>>>(B, Wf1, bfv, O, n);
}

// Round 6
// 436.117 us; speedup vs baseline: 1.6274x; 1.1367x over previous
//
#include <hip/hip_runtime.h>

#define DEVFN __device__ __forceinline__

DEVFN float bf2f(unsigned short u) {
    union { unsigned int i; float f; } c;
    c.i = ((unsigned int)u) << 16;
    return c.f;
}

DEVFN unsigned short f2bf(float f) {
    union { float f; unsigned int i; } c;
    c.f = f;
    unsigned int u = c.i;
    return (unsigned short)((u + 0x7FFFu + ((u >> 16) & 1u)) >> 16);  // RNE
}

DEVFN float4 unp(uint2 u) {
    float4 f;
    f.x = bf2f((unsigned short)(u.x & 0xFFFFu));
    f.y = bf2f((unsigned short)(u.x >> 16));
    f.z = bf2f((unsigned short)(u.y & 0xFFFFu));
    f.w = bf2f((unsigned short)(u.y >> 16));
    return f;
}

// ---------------- deterministic 2-level bucket partition ----------------
// bucket = 256 consecutive dst nodes (<=1024 buckets); chunk = 4096 edges.
// No inter-block atomics: offsets come from a per-(chunk,bucket) count matrix.

#define CHUNK 4096

// block c: LDS histogram of its chunk -> plain store of row Cmat[c][0..1023]
__global__ __launch_bounds__(256) void k_count(const int* __restrict__ dst,
                                               int* __restrict__ Cmat, int E) {
    __shared__ int lh[1024];
    int t = threadIdx.x;
    for (int b = t; b < 1024; b += 256) lh[b] = 0;
    __syncthreads();
    int i0 = blockIdx.x * CHUNK;
    int i1 = i0 + CHUNK; if (i1 > E) i1 = E;
    for (int i = i0 + t; i < i1; i += 256) atomicAdd(&lh[dst[i] >> 8], 1);
    __syncthreads();
    int* row = Cmat + (size_t)blockIdx.x * 1024;
    for (int b = t; b < 1024; b += 256) row[b] = lh[b];
}

// thread per bucket: exclusive scan down the chunk axis (coalesced across buckets)
__global__ __launch_bounds__(256) void k_colscan(const int* __restrict__ Cmat,
                                                 int* __restrict__ Omat,
                                                 int* __restrict__ btot, int gC) {
    int b = blockIdx.x * 256 + threadIdx.x;  // grid fixed at 4 blocks -> b in [0,1024)
    int run = 0;
    for (int c = 0; c < gC; c++) {
        size_t idx = (size_t)c * 1024 + b;
        int x = Cmat[idx];
        Omat[idx] = run;
        run += x;
    }
    btot[b] = run;
}

// single block: exclusive scan over 1024 buckets -> boff, boff[1024] = E
__global__ __launch_bounds__(1024) void k_bscan(const int* __restrict__ btot,
                                                int* __restrict__ boff) {
    __shared__ int s[1024];
    int t = threadIdx.x;
    int v = btot[t];
    s[t] = v;
    __syncthreads();
    for (int o = 1; o < 1024; o <<= 1) {
        int x = (t >= o) ? s[t - o] : 0;
        __syncthreads();
        s[t] += x;
        __syncthreads();
    }
    boff[t] = s[t] - v;
    if (t == 1023) boff[1024] = s[t];
}

// block c: scatter edges to part[] at deterministic base boff[b]+Omat[c][b] (+LDS rank)
// pack (dst&255)<<24 | src  (src < 2^24)
__global__ __launch_bounds__(256) void k_part2(const int* __restrict__ src,
                                               const int* __restrict__ dst,
                                               const int* __restrict__ Omat,
                                               const int* __restrict__ boff,
                                               unsigned int* __restrict__ part, int E) {
    __shared__ int lb[1024];
    __shared__ int lc[1024];
    int t = threadIdx.x;
    const int* orow = Omat + (size_t)blockIdx.x * 1024;
    for (int b = t; b < 1024; b += 256) {
        lb[b] = boff[b] + orow[b];
        lc[b] = 0;
    }
    __syncthreads();
    int i0 = blockIdx.x * CHUNK;
    int i1 = i0 + CHUNK; if (i1 > E) i1 = E;
    for (int i = i0 + t; i < i1; i += 256) {
        int d = dst[i];
        int b = d >> 8;
        int r = atomicAdd(&lc[b], 1);
        part[lb[b] + r] = (unsigned int)src[i] | ((unsigned int)(d & 255) << 24);
    }
}

// per-bucket local fill: produces dinv, roff (END offsets), csr. Scatter stays in a
// 16KB csr window -> L2-local, full-line evictions.
__global__ __launch_bounds__(256) void k_fill_local(const unsigned int* __restrict__ part,
                                                    const int* __restrict__ boff,
                                                    float* __restrict__ dinv,
                                                    int* __restrict__ roff,
                                                    int* __restrict__ csr, int n) {
    __shared__ int lcnt[256];
    __shared__ int lsc[256];
    __shared__ int lcur[256];
    int b = blockIdx.x, t = threadIdx.x;
    int s0 = boff[b], s1 = boff[b + 1];
    lcnt[t] = 0;
    __syncthreads();
    for (int i = s0 + t; i < s1; i += 256) atomicAdd(&lcnt[part[i] >> 24], 1);
    __syncthreads();
    int v = lcnt[t];
    lsc[t] = v;
    __syncthreads();
    for (int o = 1; o < 256; o <<= 1) {
        int x = (t >= o) ? lsc[t - o] : 0;
        __syncthreads();
        lsc[t] += x;
        __syncthreads();
    }
    int excl = lsc[t] - v;
    int node = (b << 8) + t;
    if (node < n) {
        dinv[node] = rsqrtf((float)(v + 1));  // +1 self-loop
        roff[node] = s0 + excl + v;           // END offset
    }
    lcur[t] = s0 + excl;
    __syncthreads();
    for (int i = s0 + t; i < s1; i += 256) {
        unsigned int p = part[i];
        int pos = atomicAdd(&lcur[p >> 24], 1);
        csr[pos] = (int)(p & 0xFFFFFFu);
    }
}

// ---------------- fused head weights ----------------
__global__ void k_fuse(const float* __restrict__ lin0_w, const float* __restrict__ lin0_b,
                       const float* __restrict__ lin1_w, const float* __restrict__ lin1_b,
                       const float* __restrict__ out_w, const float* __restrict__ out_b,
                       float* __restrict__ Wf0, float* __restrict__ Wf1, float* __restrict__ bf) {
    int idx = blockIdx.x * blockDim.x + threadIdx.x;
    if (idx < 2560) {
        int i = idx / 40, j = idx % 40;
        float a = 0.f;
        for (int k = 0; k < 64; k++) a += lin0_w[i * 64 + k] * out_w[k * 40 + j];
        Wf0[idx] = a;
    } else if (idx < 5120) {
        int r = idx - 2560;
        int i = r / 40, j = r % 40;
        float a = 0.f;
        for (int k = 0; k < 64; k++) a += lin1_w[i * 64 + k] * out_w[(64 + k) * 40 + j];
        Wf1[r] = a;
    } else if (idx < 5160) {
        int j = idx - 5120;
        float a = out_b[j];
        for (int k = 0; k < 64; k++) {
            a += lin0_b[k] * out_w[k * 40 + j];
            a += lin1_b[k] * out_w[(64 + k) * 40 + j];
        }
        bf[j] = a;
    }
}

// ---------------- transform GEMMs, epilogue folds dinv and casts bf16 ----------------

__global__ __launch_bounds__(256) void k_gemm_128(const float* __restrict__ A,
                                                  const float* __restrict__ W,
                                                  const float* __restrict__ dinv,
                                                  unsigned short* __restrict__ Cb, int n) {
    __shared__ float ws[128 * 64];
    __shared__ float xs[32 * 129];
    int t = threadIdx.x;
    for (int idx = t; idx < 2048; idx += 256) {
        float4 u = *(const float4*)(W + idx * 4);
        ws[idx * 4] = u.x; ws[idx * 4 + 1] = u.y; ws[idx * 4 + 2] = u.z; ws[idx * 4 + 3] = u.w;
    }
    int r0 = blockIdx.x * 32;
    for (int idx = t; idx < 1024; idx += 256) {
        int base = idx * 4;
        int r = base >> 7, k = base & 127;
        int gr = r0 + r; if (gr >= n) gr = n - 1;
        float4 u = *(const float4*)(A + (size_t)gr * 128 + k);
        xs[r * 129 + k]     = u.x;
        xs[r * 129 + k + 1] = u.y;
        xs[r * 129 + k + 2] = u.z;
        xs[r * 129 + k + 3] = u.w;
    }
    __syncthreads();
    int row = t >> 3, c0 = (t & 7) << 3;
    float acc[8];
#pragma unroll
    for (int j = 0; j < 8; j++) acc[j] = 0.f;
    for (int k = 0; k < 128; k++) {
        float a = xs[row * 129 + k];
#pragma unroll
        for (int j = 0; j < 8; j++) acc[j] += a * ws[k * 64 + c0 + j];
    }
    int gr = r0 + row;
    if (gr < n) {
        float dv = dinv[gr];
        union { unsigned short h[8]; uint4 u; } p;
#pragma unroll
        for (int j = 0; j < 8; j++) p.h[j] = f2bf(dv * acc[j]);
        *(uint4*)(Cb + (size_t)gr * 64 + c0) = p.u;
    }
}

__global__ __launch_bounds__(256) void k_gemm_64(const float* __restrict__ A,
                                                 const float* __restrict__ W,
                                                 const float* __restrict__ dinv,
                                                 unsigned short* __restrict__ Cb, int n) {
    __shared__ float ws[64 * 64];
    __shared__ float xs[32 * 65];
    int t = threadIdx.x;
    for (int idx = t; idx < 1024; idx += 256) {
        float4 u = *(const float4*)(W + idx * 4);
        ws[idx * 4] = u.x; ws[idx * 4 + 1] = u.y; ws[idx * 4 + 2] = u.z; ws[idx * 4 + 3] = u.w;
    }
    int r0 = blockIdx.x * 32;
    for (int idx = t; idx < 512; idx += 256) {
        int base = idx * 4;
        int r = base >> 6, k = base & 63;
        int gr = r0 + r; if (gr >= n) gr = n - 1;
        float4 u = *(const float4*)(A + (size_t)gr * 64 + k);
        xs[r * 65 + k]     = u.x;
        xs[r * 65 + k + 1] = u.y;
        xs[r * 65 + k + 2] = u.z;
        xs[r * 65 + k + 3] = u.w;
    }
    __syncthreads();
    int row = t >> 3, c0 = (t & 7) << 3;
    float acc[8];
#pragma unroll
    for (int j = 0; j < 8; j++) acc[j] = 0.f;
    for (int k = 0; k < 64; k++) {
        float a = xs[row * 65 + k];
#pragma unroll
        for (int j = 0; j < 8; j++) acc[j] += a * ws[k * 64 + c0 + j];
    }
    int gr = r0 + row;
    if (gr < n) {
        float dv = dinv[gr];
        union { unsigned short h[8]; uint4 u; } p;
#pragma unroll
        for (int j = 0; j < 8; j++) p.h[j] = f2bf(dv * acc[j]);
        *(uint4*)(Cb + (size_t)gr * 64 + c0) = p.u;
    }
}

// ---------------- head GEMMs ----------------

__global__ __launch_bounds__(256) void k_gemm40(const float* __restrict__ H,
                                                const float* __restrict__ Wf,
                                                float* __restrict__ O, int n) {
    __shared__ float wfs[64 * 40];
    __shared__ float hs[32 * 65];
    int t = threadIdx.x;
    for (int idx = t; idx < 640; idx += 256) {
        float4 u = *(const float4*)(Wf + idx * 4);
        wfs[idx * 4] = u.x; wfs[idx * 4 + 1] = u.y; wfs[idx * 4 + 2] = u.z; wfs[idx * 4 + 3] = u.w;
    }
    int r0 = blockIdx.x * 32;
    for (int idx = t; idx < 512; idx += 256) {
        int base = idx * 4;
        int r = base >> 6, k = base & 63;
        int gr = r0 + r; if (gr >= n) gr = n - 1;
        float4 u = *(const float4*)(H + (size_t)gr * 64 + k);
        hs[r * 65 + k] = u.x; hs[r * 65 + k + 1] = u.y; hs[r * 65 + k + 2] = u.z; hs[r * 65 + k + 3] = u.w;
    }
    __syncthreads();
    int row = t >> 3, c0 = (t & 7) * 5;
    float acc[5] = {0.f, 0.f, 0.f, 0.f, 0.f};
    for (int k = 0; k < 64; k++) {
        float a = hs[row * 65 + k];
#pragma unroll
        for (int j = 0; j < 5; j++) acc[j] += a * wfs[k * 40 + c0 + j];
    }
    int gr = r0 + row;
    if (gr < n) {
#pragma unroll
        for (int j = 0; j < 5; j++) O[(size_t)gr * 40 + c0 + j] = acc[j];
    }
}

__global__ __launch_bounds__(256) void k_gemm40_final(const float* __restrict__ H,
                                                      const float* __restrict__ Wf,
                                                      const float* __restrict__ bf,
                                                      float* __restrict__ out, int n) {
    __shared__ float wfs[64 * 40];
    __shared__ float hs[32 * 65];
    int t = threadIdx.x;
    for (int idx = t; idx < 640; idx += 256) {
        float4 u = *(const float4*)(Wf + idx * 4);
        wfs[idx * 4] = u.x; wfs[idx * 4 + 1] = u.y; wfs[idx * 4 + 2] = u.z; wfs[idx * 4 + 3] = u.w;
    }
    int r0 = blockIdx.x * 32;
    for (int idx = t; idx < 512; idx += 256) {
        int base = idx * 4;
        int r = base >> 6, k = base & 63;
        int gr = r0 + r; if (gr >= n) gr = n - 1;
        float4 u = *(const float4*)(H + (size_t)gr * 64 + k);
        hs[r * 65 + k] = u.x; hs[r * 65 + k + 1] = u.y; hs[r * 65 + k + 2] = u.z; hs[r * 65 + k + 3] = u.w;
    }
    __syncthreads();
    int row = t >> 3, c0 = (t & 7) * 5;
    float acc[5] = {0.f, 0.f, 0.f, 0.f, 0.f};
    for (int k = 0; k < 64; k++) {
        float a = hs[row * 65 + k];
#pragma unroll
        for (int j = 0; j < 5; j++) acc[j] += a * wfs[k * 40 + c0 + j];
    }
    int gr = r0 + row;
    if (gr < n) {
#pragma unroll
        for (int j = 0; j < 5; j++) {
            size_t p = (size_t)gr * 40 + c0 + j;
            out[p] = out[p] + acc[j] + bf[c0 + j];
        }
    }
}

// ---------------- aggregation: wave/node, 4 lane-groups x 16, 16 rows in flight ----------------
__global__ __launch_bounds__(256) void k_agg(const unsigned short* __restrict__ T,
                                             const int* __restrict__ csr,
                                             const int* __restrict__ roffE,  // END offsets
                                             const float* __restrict__ bias,
                                             float* __restrict__ H, int n) {
    int lane = threadIdx.x & 63;
    int q = lane >> 4, h = lane & 15;
    int v = blockIdx.x * 4 + (threadIdx.x >> 6);
    if (v >= n) return;
    int start = (v == 0) ? 0 : roffE[v - 1];
    int end = roffE[v];
    float dv = rsqrtf((float)(end - start + 1));
    float4 acc = {0.f, 0.f, 0.f, 0.f};
    if (q == 0) {  // self-loop row (counted once)
        uint2 u = *(const uint2*)(T + (size_t)v * 64 + h * 4);
        float4 f = unp(u);
        acc.x += f.x; acc.y += f.y; acc.z += f.z; acc.w += f.w;
    }
    for (int base = start; base < end; base += 64) {
        int m = end - base; if (m > 64) m = 64;
        int e = (lane < m) ? csr[base + lane] : 0;
        int j = 0;
        for (; j + 16 <= m; j += 16) {
            int s0 = __shfl(e, j + q);
            int s1 = __shfl(e, j + 4 + q);
            int s2 = __shfl(e, j + 8 + q);
            int s3 = __shfl(e, j + 12 + q);
            uint2 u0 = *(const uint2*)(T + (size_t)s0 * 64 + h * 4);
            uint2 u1 = *(const uint2*)(T + (size_t)s1 * 64 + h * 4);
            uint2 u2 = *(const uint2*)(T + (size_t)s2 * 64 + h * 4);
            uint2 u3 = *(const uint2*)(T + (size_t)s3 * 64 + h * 4);
            float4 f0 = unp(u0), f1 = unp(u1), f2 = unp(u2), f3 = unp(u3);
            acc.x += (f0.x + f1.x) + (f2.x + f3.x);
            acc.y += (f0.y + f1.y) + (f2.y + f3.y);
            acc.z += (f0.z + f1.z) + (f2.z + f3.z);
            acc.w += (f0.w + f1.w) + (f2.w + f3.w);
        }
        for (; j + 4 <= m; j += 4) {
            int s = __shfl(e, j + q);
            uint2 u = *(const uint2*)(T + (size_t)s * 64 + h * 4);
            float4 f = unp(u);
            acc.x += f.x; acc.y += f.y; acc.z += f.z; acc.w += f.w;
        }
        if (j < m) {
            int jj = j + q;
            int s = __shfl(e, jj & 63);
            if (jj < m) {
                uint2 u = *(const uint2*)(T + (size_t)s * 64 + h * 4);
                float4 f = unp(u);
                acc.x += f.x; acc.y += f.y; acc.z += f.z; acc.w += f.w;
            }
        }
    }
    acc.x += __shfl_xor(acc.x, 16); acc.y += __shfl_xor(acc.y, 16);
    acc.z += __shfl_xor(acc.z, 16); acc.w += __shfl_xor(acc.w, 16);
    acc.x += __shfl_xor(acc.x, 32); acc.y += __shfl_xor(acc.y, 32);
    acc.z += __shfl_xor(acc.z, 32); acc.w += __shfl_xor(acc.w, 32);
    if (q == 0) {
        float4 bb = *(const float4*)(bias + h * 4);
        float4 r;
        r.x = dv * acc.x + bb.x;
        r.y = dv * acc.y + bb.y;
        r.z = dv * acc.z + bb.z;
        r.w = dv * acc.w + bb.w;
        r.x = (r.x > 0.f) ? r.x : (__expf(r.x) - 1.f);
        r.y = (r.y > 0.f) ? r.y : (__expf(r.y) - 1.f);
        r.z = (r.z > 0.f) ? r.z : (__expf(r.z) - 1.f);
        r.w = (r.w > 0.f) ? r.w : (__expf(r.w) - 1.f);
        *(float4*)(H + (size_t)v * 64 + h * 4) = r;
    }
}

// ---------------- launch ----------------

extern "C" void kernel_launch(void* const* d_in, const int* in_sizes, int n_in,
                              void* d_out, int out_size, void* d_ws, size_t ws_size,
                              hipStream_t stream) {
    const float* x       = (const float*)d_in[0];
    const int*   eidx    = (const int*)d_in[1];
    const float* conv0_w = (const float*)d_in[2];
    const float* conv0_b = (const float*)d_in[3];
    const float* lin0_w  = (const float*)d_in[4];
    const float* lin0_b  = (const float*)d_in[5];
    const float* conv1_w = (const float*)d_in[6];
    const float* conv1_b = (const float*)d_in[7];
    const float* lin1_w  = (const float*)d_in[8];
    const float* lin1_b  = (const float*)d_in[9];
    const float* out_w   = (const float*)d_in[10];
    const float* out_b   = (const float*)d_in[11];

    int n = in_sizes[0] / 128;
    int E = in_sizes[1] / 2;
    const int* src = eidx;
    const int* dst = eidx + E;
    int NB = (n + 255) >> 8;           // buckets of 256 nodes (n <= 262144)
    int gC = (E + CHUNK - 1) / CHUNK;  // chunks

    char* wsb = (char*)d_ws;
    auto al = [](size_t v) { return (v + 4095) & ~(size_t)4095; };
    size_t o = 0;
    int*            Cmat  = (int*)(wsb + o);            o = al(o + (size_t)gC * 1024 * 4);
    int*            Omat  = (int*)(wsb + o);            o = al(o + (size_t)gC * 1024 * 4);
    int*            btot  = (int*)(wsb + o);            o = al(o + 1024 * 4);
    int*            boff  = (int*)(wsb + o);            o = al(o + 1025 * 4);
    float*          dinv  = (float*)(wsb + o);          o = al(o + (size_t)n * 4);
    int*            roff  = (int*)(wsb + o);            o = al(o + (size_t)n * 4);
    unsigned int*   part  = (unsigned int*)(wsb + o);   o = al(o + (size_t)E * 4);
    int*            csr   = (int*)(wsb + o);            o = al(o + (size_t)E * 4);
    float*          Wf0   = (float*)(wsb + o);          o = al(o + 2560 * 4);
    float*          Wf1   = (float*)(wsb + o);          o = al(o + 2560 * 4);
    float*          bfv   = (float*)(wsb + o);          o = al(o + 40 * 4);
    unsigned short* Ab    = (unsigned short*)(wsb + o); o = al(o + (size_t)n * 64 * 2);
    float*          B     = (float*)(wsb + o);          o = al(o + (size_t)n * 64 * 4);
    float* O = (float*)d_out;  // head partial accumulates in d_out (fp32 n*40)

    int gR = (n + 31) / 32;
    int gV = (n + 3) / 4;

    // CSR build — fully deterministic offsets, no inter-block atomics, no memset
    k_count<<<gC, 256, 0, stream>>>(dst, Cmat, E);
    k_colscan<<<4, 256, 0, stream>>>(Cmat, Omat, btot, gC);
    k_bscan<<<1, 1024, 0, stream>>>(btot, boff);
    k_part2<<<gC, 256, 0, stream>>>(src, dst, Omat, boff, part, E);
    k_fill_local<<<NB, 256, 0, stream>>>(part, boff, dinv, roff, csr, n);
    k_fuse<<<(5160 + 255) / 256, 256, 0, stream>>>(lin0_w, lin0_b, lin1_w, lin1_b, out_w, out_b,
                                                   Wf0, Wf1, bfv);

    // layer 0
    k_gemm_128<<<gR, 256, 0, stream>>>(x, conv0_w, dinv, Ab, n);
    k_agg<<<gV, 256, 0, stream>>>(Ab, csr, roff, conv0_b, B, n);
    // head contribution of h (write O = B @ Wf0 into d_out)
    k_gemm40<<<gR, 256, 0, stream>>>(B, Wf0, O, n);
    // layer 1
    k_gemm_64<<<gR, 256, 0, stream>>>(B, conv1_w, dinv, Ab, n);
    k_agg<<<gV, 256, 0, stream>>>(Ab, csr, roff, conv1_b, B, n);
    // final head: out = O + B @ Wf1 + bf
    k_gemm40_final<<<gR, 256, 0, stream>>>(B, Wf1, bfv, O, n);
}

// Round 7
// 358.996 us; speedup vs baseline: 1.9770x; 1.2148x over previous
//
#include <hip/hip_runtime.h>

#define DEVFN __device__ __forceinline__

DEVFN float bf2f(unsigned short u) {
    union { unsigned int i; float f; } c;
    c.i = ((unsigned int)u) << 16;
    return c.f;
}

DEVFN unsigned short f2bf(float f) {
    union { float f; unsigned int i; } c;
    c.f = f;
    unsigned int u = c.i;
    return (unsigned short)((u + 0x7FFFu + ((u >> 16) & 1u)) >> 16);  // RNE
}

DEVFN float4 unp(uint2 u) {
    float4 f;
    f.x = bf2f((unsigned short)(u.x & 0xFFFFu));
    f.y = bf2f((unsigned short)(u.x >> 16));
    f.z = bf2f((unsigned short)(u.y & 0xFFFFu));
    f.w = bf2f((unsigned short)(u.y >> 16));
    return f;
}

// ---------------- deterministic 2-level bucket partition ----------------
// bucket = 256 consecutive dst nodes (<=1024 buckets); chunk = 4096 edges.
// No inter-block atomics: offsets come from a per-(chunk,bucket) count matrix.

#define CHUNK 4096

// block c: LDS histogram of its chunk -> plain store of row Cmat[c][0..1023]
__global__ __launch_bounds__(256) void k_count(const int* __restrict__ dst,
                                               int* __restrict__ Cmat, int E) {
    __shared__ int lh[1024];
    int t = threadIdx.x;
    for (int b = t; b < 1024; b += 256) lh[b] = 0;
    __syncthreads();
    int i0 = blockIdx.x * CHUNK;
    int i1 = i0 + CHUNK; if (i1 > E) i1 = E;
    for (int i = i0 + t; i < i1; i += 256) atomicAdd(&lh[dst[i] >> 8], 1);
    __syncthreads();
    int* row = Cmat + (size_t)blockIdx.x * 1024;
    for (int b = t; b < 1024; b += 256) row[b] = lh[b];
}

// wave-parallel column scan: one wave per bucket, segmented shfl-scan over chunks.
// Cmat is L2-resident (1.6 MB) so the strided lane reads are cheap.
__global__ __launch_bounds__(256) void k_wscan(const int* __restrict__ Cmat,
                                               int* __restrict__ Omat,
                                               int* __restrict__ btot, int gC) {
    int b = (blockIdx.x * 256 + threadIdx.x) >> 6;  // bucket = global wave id, 0..1023
    int lane = threadIdx.x & 63;
    int base = 0;
    for (int c0 = 0; c0 < gC; c0 += 64) {
        int c = c0 + lane;
        int x = (c < gC) ? Cmat[(size_t)c * 1024 + b] : 0;
        int orig = x;
#pragma unroll
        for (int off = 1; off < 64; off <<= 1) {
            int y = __shfl_up(x, off);
            if (lane >= off) x += y;
        }
        if (c < gC) Omat[(size_t)c * 1024 + b] = base + x - orig;  // exclusive
        base += __shfl(x, 63);
    }
    if (lane == 0) btot[b] = base;
}

// single block: exclusive scan over 1024 buckets -> boff, boff[1024] = E
__global__ __launch_bounds__(1024) void k_bscan(const int* __restrict__ btot,
                                                int* __restrict__ boff) {
    __shared__ int s[1024];
    int t = threadIdx.x;
    int v = btot[t];
    s[t] = v;
    __syncthreads();
    for (int o = 1; o < 1024; o <<= 1) {
        int x = (t >= o) ? s[t - o] : 0;
        __syncthreads();
        s[t] += x;
        __syncthreads();
    }
    boff[t] = s[t] - v;
    if (t == 1023) boff[1024] = s[t];
}

// block c: scatter edges to part[] at deterministic base boff[b]+Omat[c][b] (+LDS rank)
// pack (dst&255)<<24 | src  (src < 2^24)
__global__ __launch_bounds__(256) void k_part2(const int* __restrict__ src,
                                               const int* __restrict__ dst,
                                               const int* __restrict__ Omat,
                                               const int* __restrict__ boff,
                                               unsigned int* __restrict__ part, int E) {
    __shared__ int lb[1024];
    __shared__ int lc[1024];
    int t = threadIdx.x;
    const int* orow = Omat + (size_t)blockIdx.x * 1024;
    for (int b = t; b < 1024; b += 256) {
        lb[b] = boff[b] + orow[b];
        lc[b] = 0;
    }
    __syncthreads();
    int i0 = blockIdx.x * CHUNK;
    int i1 = i0 + CHUNK; if (i1 > E) i1 = E;
    for (int i = i0 + t; i < i1; i += 256) {
        int d = dst[i];
        int b = d >> 8;
        int r = atomicAdd(&lc[b], 1);
        part[lb[b] + r] = (unsigned int)src[i] | ((unsigned int)(d & 255) << 24);
    }
}

// per-bucket local fill: produces dinv, roff (END offsets), csr. Scatter stays in a
// 16KB csr window -> L2-local, full-line evictions.
__global__ __launch_bounds__(256) void k_fill_local(const unsigned int* __restrict__ part,
                                                    const int* __restrict__ boff,
                                                    float* __restrict__ dinv,
                                                    int* __restrict__ roff,
                                                    int* __restrict__ csr, int n) {
    __shared__ int lcnt[256];
    __shared__ int lsc[256];
    __shared__ int lcur[256];
    int b = blockIdx.x, t = threadIdx.x;
    int s0 = boff[b], s1 = boff[b + 1];
    lcnt[t] = 0;
    __syncthreads();
    for (int i = s0 + t; i < s1; i += 256) atomicAdd(&lcnt[part[i] >> 24], 1);
    __syncthreads();
    int v = lcnt[t];
    lsc[t] = v;
    __syncthreads();
    for (int o = 1; o < 256; o <<= 1) {
        int x = (t >= o) ? lsc[t - o] : 0;
        __syncthreads();
        lsc[t] += x;
        __syncthreads();
    }
    int excl = lsc[t] - v;
    int node = (b << 8) + t;
    if (node < n) {
        dinv[node] = rsqrtf((float)(v + 1));  // +1 self-loop
        roff[node] = s0 + excl + v;           // END offset
    }
    lcur[t] = s0 + excl;
    __syncthreads();
    for (int i = s0 + t; i < s1; i += 256) {
        unsigned int p = part[i];
        int pos = atomicAdd(&lcur[p >> 24], 1);
        csr[pos] = (int)(p & 0xFFFFFFu);
    }
}

// ---------------- fused head weights ----------------
__global__ void k_fuse(const float* __restrict__ lin0_w, const float* __restrict__ lin0_b,
                       const float* __restrict__ lin1_w, const float* __restrict__ lin1_b,
                       const float* __restrict__ out_w, const float* __restrict__ out_b,
                       float* __restrict__ Wf0, float* __restrict__ Wf1, float* __restrict__ bf) {
    int idx = blockIdx.x * blockDim.x + threadIdx.x;
    if (idx < 2560) {
        int i = idx / 40, j = idx % 40;
        float a = 0.f;
        for (int k = 0; k < 64; k++) a += lin0_w[i * 64 + k] * out_w[k * 40 + j];
        Wf0[idx] = a;
    } else if (idx < 5120) {
        int r = idx - 2560;
        int i = r / 40, j = r % 40;
        float a = 0.f;
        for (int k = 0; k < 64; k++) a += lin1_w[i * 64 + k] * out_w[(64 + k) * 40 + j];
        Wf1[r] = a;
    } else if (idx < 5160) {
        int j = idx - 5120;
        float a = out_b[j];
        for (int k = 0; k < 64; k++) {
            a += lin0_b[k] * out_w[k * 40 + j];
            a += lin1_b[k] * out_w[(64 + k) * 40 + j];
        }
        bf[j] = a;
    }
}

// ---------------- transform GEMMs, epilogue folds dinv and casts bf16 ----------------

__global__ __launch_bounds__(256) void k_gemm_128(const float* __restrict__ A,
                                                  const float* __restrict__ W,
                                                  const float* __restrict__ dinv,
                                                  unsigned short* __restrict__ Cb, int n) {
    __shared__ float ws[128 * 64];
    __shared__ float xs[32 * 129];
    int t = threadIdx.x;
    for (int idx = t; idx < 2048; idx += 256) {
        float4 u = *(const float4*)(W + idx * 4);
        ws[idx * 4] = u.x; ws[idx * 4 + 1] = u.y; ws[idx * 4 + 2] = u.z; ws[idx * 4 + 3] = u.w;
    }
    int r0 = blockIdx.x * 32;
    for (int idx = t; idx < 1024; idx += 256) {
        int base = idx * 4;
        int r = base >> 7, k = base & 127;
        int gr = r0 + r; if (gr >= n) gr = n - 1;
        float4 u = *(const float4*)(A + (size_t)gr * 128 + k);
        xs[r * 129 + k]     = u.x;
        xs[r * 129 + k + 1] = u.y;
        xs[r * 129 + k + 2] = u.z;
        xs[r * 129 + k + 3] = u.w;
    }
    __syncthreads();
    int row = t >> 3, c0 = (t & 7) << 3;
    float acc[8];
#pragma unroll
    for (int j = 0; j < 8; j++) acc[j] = 0.f;
    for (int k = 0; k < 128; k++) {
        float a = xs[row * 129 + k];
#pragma unroll
        for (int j = 0; j < 8; j++) acc[j] += a * ws[k * 64 + c0 + j];
    }
    int gr = r0 + row;
    if (gr < n) {
        float dv = dinv[gr];
        union { unsigned short h[8]; uint4 u; } p;
#pragma unroll
        for (int j = 0; j < 8; j++) p.h[j] = f2bf(dv * acc[j]);
        *(uint4*)(Cb + (size_t)gr * 64 + c0) = p.u;
    }
}

__global__ __launch_bounds__(256) void k_gemm_64(const float* __restrict__ A,
                                                 const float* __restrict__ W,
                                                 const float* __restrict__ dinv,
                                                 unsigned short* __restrict__ Cb, int n) {
    __shared__ float ws[64 * 64];
    __shared__ float xs[32 * 65];
    int t = threadIdx.x;
    for (int idx = t; idx < 1024; idx += 256) {
        float4 u = *(const float4*)(W + idx * 4);
        ws[idx * 4] = u.x; ws[idx * 4 + 1] = u.y; ws[idx * 4 + 2] = u.z; ws[idx * 4 + 3] = u.w;
    }
    int r0 = blockIdx.x * 32;
    for (int idx = t; idx < 512; idx += 256) {
        int base = idx * 4;
        int r = base >> 6, k = base & 63;
        int gr = r0 + r; if (gr >= n) gr = n - 1;
        float4 u = *(const float4*)(A + (size_t)gr * 64 + k);
        xs[r * 65 + k]     = u.x;
        xs[r * 65 + k + 1] = u.y;
        xs[r * 65 + k + 2] = u.z;
        xs[r * 65 + k + 3] = u.w;
    }
    __syncthreads();
    int row = t >> 3, c0 = (t & 7) << 3;
    float acc[8];
#pragma unroll
    for (int j = 0; j < 8; j++) acc[j] = 0.f;
    for (int k = 0; k < 64; k++) {
        float a = xs[row * 65 + k];
#pragma unroll
        for (int j = 0; j < 8; j++) acc[j] += a * ws[k * 64 + c0 + j];
    }
    int gr = r0 + row;
    if (gr < n) {
        float dv = dinv[gr];
        union { unsigned short h[8]; uint4 u; } p;
#pragma unroll
        for (int j = 0; j < 8; j++) p.h[j] = f2bf(dv * acc[j]);
        *(uint4*)(Cb + (size_t)gr * 64 + c0) = p.u;
    }
}

// ---------------- head GEMMs ----------------

__global__ __launch_bounds__(256) void k_gemm40(const float* __restrict__ H,
                                                const float* __restrict__ Wf,
                                                float* __restrict__ O, int n) {
    __shared__ float wfs[64 * 40];
    __shared__ float hs[32 * 65];
    int t = threadIdx.x;
    for (int idx = t; idx < 640; idx += 256) {
        float4 u = *(const float4*)(Wf + idx * 4);
        wfs[idx * 4] = u.x; wfs[idx * 4 + 1] = u.y; wfs[idx * 4 + 2] = u.z; wfs[idx * 4 + 3] = u.w;
    }
    int r0 = blockIdx.x * 32;
    for (int idx = t; idx < 512; idx += 256) {
        int base = idx * 4;
        int r = base >> 6, k = base & 63;
        int gr = r0 + r; if (gr >= n) gr = n - 1;
        float4 u = *(const float4*)(H + (size_t)gr * 64 + k);
        hs[r * 65 + k] = u.x; hs[r * 65 + k + 1] = u.y; hs[r * 65 + k + 2] = u.z; hs[r * 65 + k + 3] = u.w;
    }
    __syncthreads();
    int row = t >> 3, c0 = (t & 7) * 5;
    float acc[5] = {0.f, 0.f, 0.f, 0.f, 0.f};
    for (int k = 0; k < 64; k++) {
        float a = hs[row * 65 + k];
#pragma unroll
        for (int j = 0; j < 5; j++) acc[j] += a * wfs[k * 40 + c0 + j];
    }
    int gr = r0 + row;
    if (gr < n) {
#pragma unroll
        for (int j = 0; j < 5; j++) O[(size_t)gr * 40 + c0 + j] = acc[j];
    }
}

__global__ __launch_bounds__(256) void k_gemm40_final(const float* __restrict__ H,
                                                      const float* __restrict__ Wf,
                                                      const float* __restrict__ bf,
                                                      float* __restrict__ out, int n) {
    __shared__ float wfs[64 * 40];
    __shared__ float hs[32 * 65];
    int t = threadIdx.x;
    for (int idx = t; idx < 640; idx += 256) {
        float4 u = *(const float4*)(Wf + idx * 4);
        wfs[idx * 4] = u.x; wfs[idx * 4 + 1] = u.y; wfs[idx * 4 + 2] = u.z; wfs[idx * 4 + 3] = u.w;
    }
    int r0 = blockIdx.x * 32;
    for (int idx = t; idx < 512; idx += 256) {
        int base = idx * 4;
        int r = base >> 6, k = base & 63;
        int gr = r0 + r; if (gr >= n) gr = n - 1;
        float4 u = *(const float4*)(H + (size_t)gr * 64 + k);
        hs[r * 65 + k] = u.x; hs[r * 65 + k + 1] = u.y; hs[r * 65 + k + 2] = u.z; hs[r * 65 + k + 3] = u.w;
    }
    __syncthreads();
    int row = t >> 3, c0 = (t & 7) * 5;
    float acc[5] = {0.f, 0.f, 0.f, 0.f, 0.f};
    for (int k = 0; k < 64; k++) {
        float a = hs[row * 65 + k];
#pragma unroll
        for (int j = 0; j < 5; j++) acc[j] += a * wfs[k * 40 + c0 + j];
    }
    int gr = r0 + row;
    if (gr < n) {
#pragma unroll
        for (int j = 0; j < 5; j++) {
            size_t p = (size_t)gr * 40 + c0 + j;
            out[p] = out[p] + acc[j] + bf[c0 + j];
        }
    }
}

// ---------------- aggregation: wave/node, 4 lane-groups x 16, 16 rows in flight ----------------
__global__ __launch_bounds__(256) void k_agg(const unsigned short* __restrict__ T,
                                             const int* __restrict__ csr,
                                             const int* __restrict__ roffE,  // END offsets
                                             const float* __restrict__ bias,
                                             float* __restrict__ H, int n) {
    int lane = threadIdx.x & 63;
    int q = lane >> 4, h = lane & 15;
    int v = blockIdx.x * 4 + (threadIdx.x >> 6);
    if (v >= n) return;
    int start = (v == 0) ? 0 : roffE[v - 1];
    int end = roffE[v];
    float dv = rsqrtf((float)(end - start + 1));
    float4 acc = {0.f, 0.f, 0.f, 0.f};
    if (q == 0) {  // self-loop row (counted once)
        uint2 u = *(const uint2*)(T + (size_t)v * 64 + h * 4);
        float4 f = unp(u);
        acc.x += f.x; acc.y += f.y; acc.z += f.z; acc.w += f.w;
    }
    for (int base = start; base < end; base += 64) {
        int m = end - base; if (m > 64) m = 64;
        int e = (lane < m) ? csr[base + lane] : 0;
        int j = 0;
        for (; j + 16 <= m; j += 16) {
            int s0 = __shfl(e, j + q);
            int s1 = __shfl(e, j + 4 + q);
            int s2 = __shfl(e, j + 8 + q);
            int s3 = __shfl(e, j + 12 + q);
            uint2 u0 = *(const uint2*)(T + (size_t)s0 * 64 + h * 4);
            uint2 u1 = *(const uint2*)(T + (size_t)s1 * 64 + h * 4);
            uint2 u2 = *(const uint2*)(T + (size_t)s2 * 64 + h * 4);
            uint2 u3 = *(const uint2*)(T + (size_t)s3 * 64 + h * 4);
            float4 f0 = unp(u0), f1 = unp(u1), f2 = unp(u2), f3 = unp(u3);
            acc.x += (f0.x + f1.x) + (f2.x + f3.x);
            acc.y += (f0.y + f1.y) + (f2.y + f3.y);
            acc.z += (f0.z + f1.z) + (f2.z + f3.z);
            acc.w += (f0.w + f1.w) + (f2.w + f3.w);
        }
        for (; j + 4 <= m; j += 4) {
            int s = __shfl(e, j + q);
            uint2 u = *(const uint2*)(T + (size_t)s * 64 + h * 4);
            float4 f = unp(u);
            acc.x += f.x; acc.y += f.y; acc.z += f.z; acc.w += f.w;
        }
        if (j < m) {
            int jj = j + q;
            int s = __shfl(e, jj & 63);
            if (jj < m) {
                uint2 u = *(const uint2*)(T + (size_t)s * 64 + h * 4);
                float4 f = unp(u);
                acc.x += f.x; acc.y += f.y; acc.z += f.z; acc.w += f.w;
            }
        }
    }
    acc.x += __shfl_xor(acc.x, 16); acc.y += __shfl_xor(acc.y, 16);
    acc.z += __shfl_xor(acc.z, 16); acc.w += __shfl_xor(acc.w, 16);
    acc.x += __shfl_xor(acc.x, 32); acc.y += __shfl_xor(acc.y, 32);
    acc.z += __shfl_xor(acc.z, 32); acc.w += __shfl_xor(acc.w, 32);
    if (q == 0) {
        float4 bb = *(const float4*)(bias + h * 4);
        float4 r;
        r.x = dv * acc.x + bb.x;
        r.y = dv * acc.y + bb.y;
        r.z = dv * acc.z + bb.z;
        r.w = dv * acc.w + bb.w;
        r.x = (r.x > 0.f) ? r.x : (__expf(r.x) - 1.f);
        r.y = (r.y > 0.f) ? r.y : (__expf(r.y) - 1.f);
        r.z = (r.z > 0.f) ? r.z : (__expf(r.z) - 1.f);
        r.w = (r.w > 0.f) ? r.w : (__expf(r.w) - 1.f);
        *(float4*)(H + (size_t)v * 64 + h * 4) = r;
    }
}

// ---------------- launch ----------------

extern "C" void kernel_launch(void* const* d_in, const int* in_sizes, int n_in,
                              void* d_out, int out_size, void* d_ws, size_t ws_size,
                              hipStream_t stream) {
    const float* x       = (const float*)d_in[0];
    const int*   eidx    = (const int*)d_in[1];
    const float* conv0_w = (const float*)d_in[2];
    const float* conv0_b = (const float*)d_in[3];
    const float* lin0_w  = (const float*)d_in[4];
    const float* lin0_b  = (const float*)d_in[5];
    const float* conv1_w = (const float*)d_in[6];
    const float* conv1_b = (const float*)d_in[7];
    const float* lin1_w  = (const float*)d_in[8];
    const float* lin1_b  = (const float*)d_in[9];
    const float* out_w   = (const float*)d_in[10];
    const float* out_b   = (const float*)d_in[11];

    int n = in_sizes[0] / 128;
    int E = in_sizes[1] / 2;
    const int* src = eidx;
    const int* dst = eidx + E;
    int NB = (n + 255) >> 8;           // buckets of 256 nodes (n <= 262144)
    int gC = (E + CHUNK - 1) / CHUNK;  // chunks

    char* wsb = (char*)d_ws;
    auto al = [](size_t v) { return (v + 4095) & ~(size_t)4095; };
    size_t o = 0;
    int*            Cmat  = (int*)(wsb + o);            o = al(o + (size_t)gC * 1024 * 4);
    int*            Omat  = (int*)(wsb + o);            o = al(o + (size_t)gC * 1024 * 4);
    int*            btot  = (int*)(wsb + o);            o = al(o + 1024 * 4);
    int*            boff  = (int*)(wsb + o);            o = al(o + 1025 * 4);
    float*          dinv  = (float*)(wsb + o);          o = al(o + (size_t)n * 4);
    int*            roff  = (int*)(wsb + o);            o = al(o + (size_t)n * 4);
    unsigned int*   part  = (unsigned int*)(wsb + o);   o = al(o + (size_t)E * 4);
    int*            csr   = (int*)(wsb + o);            o = al(o + (size_t)E * 4);
    float*          Wf0   = (float*)(wsb + o);          o = al(o + 2560 * 4);
    float*          Wf1   = (float*)(wsb + o);          o = al(o + 2560 * 4);
    float*          bfv   = (float*)(wsb + o);          o = al(o + 40 * 4);
    unsigned short* Ab    = (unsigned short*)(wsb + o); o = al(o + (size_t)n * 64 * 2);
    float*          B     = (float*)(wsb + o);          o = al(o + (size_t)n * 64 * 4);
    float* O = (float*)d_out;  // head partial accumulates in d_out (fp32 n*40)

    int gR = (n + 31) / 32;
    int gV = (n + 3) / 4;

    // CSR build — fully deterministic offsets, no inter-block atomics, no memset
    k_count<<<gC, 256, 0, stream>>>(dst, Cmat, E);
    k_wscan<<<256, 256, 0, stream>>>(Cmat, Omat, btot, gC);
    k_bscan<<<1, 1024, 0, stream>>>(btot, boff);
    k_part2<<<gC, 256, 0, stream>>>(src, dst, Omat, boff, part, E);
    k_fill_local<<<NB, 256, 0, stream>>>(part, boff, dinv, roff, csr, n);
    k_fuse<<<(5160 + 255) / 256, 256, 0, stream>>>(lin0_w, lin0_b, lin1_w, lin1_b, out_w, out_b,
                                                   Wf0, Wf1, bfv);

    // layer 0
    k_gemm_128<<<gR, 256, 0, stream>>>(x, conv0_w, dinv, Ab, n);
    k_agg<<<gV, 256, 0, stream>>>(Ab, csr, roff, conv0_b, B, n);
    // head contribution of h (write O = B @ Wf0 into d_out)
    k_gemm40<<<gR, 256, 0, stream>>>(B, Wf0, O, n);
    // layer 1
    k_gemm_64<<<gR, 256, 0, stream>>>(B, conv1_w, dinv, Ab, n);
    k_agg<<<gV, 256, 0, stream>>>(Ab, csr, roff, conv1_b, B, n);
    // final head: out = O + B @ Wf1 + bf
    k_gemm40_final<<<gR, 256, 0, stream>>>(B, Wf1, bfv, O, n);
}

// Round 8
// 342.063 us; speedup vs baseline: 2.0748x; 1.0495x over previous
//
#include <hip/hip_runtime.h>

#define DEVFN __device__ __forceinline__

DEVFN float bf2f(unsigned short u) {
    union { unsigned int i; float f; } c;
    c.i = ((unsigned int)u) << 16;
    return c.f;
}

DEVFN unsigned short f2bf(float f) {
    union { float f; unsigned int i; } c;
    c.f = f;
    unsigned int u = c.i;
    return (unsigned short)((u + 0x7FFFu + ((u >> 16) & 1u)) >> 16);  // RNE
}

DEVFN float4 unp(uint2 u) {
    float4 f;
    f.x = bf2f((unsigned short)(u.x & 0xFFFFu));
    f.y = bf2f((unsigned short)(u.x >> 16));
    f.z = bf2f((unsigned short)(u.y & 0xFFFFu));
    f.w = bf2f((unsigned short)(u.y >> 16));
    return f;
}

// ---------------- deterministic 2-level bucket partition ----------------

#define CHUNK 4096

__global__ __launch_bounds__(256) void k_count(const int* __restrict__ dst,
                                               int* __restrict__ Cmat, int E) {
    __shared__ int lh[1024];
    int t = threadIdx.x;
    for (int b = t; b < 1024; b += 256) lh[b] = 0;
    __syncthreads();
    int i0 = blockIdx.x * CHUNK;
    int i1 = i0 + CHUNK; if (i1 > E) i1 = E;
    for (int i = i0 + t; i < i1; i += 256) atomicAdd(&lh[dst[i] >> 8], 1);
    __syncthreads();
    int* row = Cmat + (size_t)blockIdx.x * 1024;
    for (int b = t; b < 1024; b += 256) row[b] = lh[b];
}

__global__ __launch_bounds__(256) void k_wscan(const int* __restrict__ Cmat,
                                               int* __restrict__ Omat,
                                               int* __restrict__ btot, int gC) {
    int b = (blockIdx.x * 256 + threadIdx.x) >> 6;
    int lane = threadIdx.x & 63;
    int base = 0;
    for (int c0 = 0; c0 < gC; c0 += 64) {
        int c = c0 + lane;
        int x = (c < gC) ? Cmat[(size_t)c * 1024 + b] : 0;
        int orig = x;
#pragma unroll
        for (int off = 1; off < 64; off <<= 1) {
            int y = __shfl_up(x, off);
            if (lane >= off) x += y;
        }
        if (c < gC) Omat[(size_t)c * 1024 + b] = base + x - orig;
        base += __shfl(x, 63);
    }
    if (lane == 0) btot[b] = base;
}

__global__ __launch_bounds__(1024) void k_bscan(const int* __restrict__ btot,
                                                int* __restrict__ boff) {
    __shared__ int s[1024];
    int t = threadIdx.x;
    int v = btot[t];
    s[t] = v;
    __syncthreads();
    for (int o = 1; o < 1024; o <<= 1) {
        int x = (t >= o) ? s[t - o] : 0;
        __syncthreads();
        s[t] += x;
        __syncthreads();
    }
    boff[t] = s[t] - v;
    if (t == 1023) boff[1024] = s[t];
}

__global__ __launch_bounds__(256) void k_part2(const int* __restrict__ src,
                                               const int* __restrict__ dst,
                                               const int* __restrict__ Omat,
                                               const int* __restrict__ boff,
                                               unsigned int* __restrict__ part, int E) {
    __shared__ int lb[1024];
    __shared__ int lc[1024];
    int t = threadIdx.x;
    const int* orow = Omat + (size_t)blockIdx.x * 1024;
    for (int b = t; b < 1024; b += 256) {
        lb[b] = boff[b] + orow[b];
        lc[b] = 0;
    }
    __syncthreads();
    int i0 = blockIdx.x * CHUNK;
    int i1 = i0 + CHUNK; if (i1 > E) i1 = E;
    for (int i = i0 + t; i < i1; i += 256) {
        int d = dst[i];
        int b = d >> 8;
        int r = atomicAdd(&lc[b], 1);
        part[lb[b] + r] = (unsigned int)src[i] | ((unsigned int)(d & 255) << 24);
    }
}

__global__ __launch_bounds__(256) void k_fill_local(const unsigned int* __restrict__ part,
                                                    const int* __restrict__ boff,
                                                    float* __restrict__ dinv,
                                                    int* __restrict__ roff,
                                                    int* __restrict__ csr, int n) {
    __shared__ int lcnt[256];
    __shared__ int lsc[256];
    __shared__ int lcur[256];
    int b = blockIdx.x, t = threadIdx.x;
    int s0 = boff[b], s1 = boff[b + 1];
    lcnt[t] = 0;
    __syncthreads();
    for (int i = s0 + t; i < s1; i += 256) atomicAdd(&lcnt[part[i] >> 24], 1);
    __syncthreads();
    int v = lcnt[t];
    lsc[t] = v;
    __syncthreads();
    for (int o = 1; o < 256; o <<= 1) {
        int x = (t >= o) ? lsc[t - o] : 0;
        __syncthreads();
        lsc[t] += x;
        __syncthreads();
    }
    int excl = lsc[t] - v;
    int node = (b << 8) + t;
    if (node < n) {
        dinv[node] = rsqrtf((float)(v + 1));  // +1 self-loop
        roff[node] = s0 + excl + v;           // END offset
    }
    lcur[t] = s0 + excl;
    __syncthreads();
    for (int i = s0 + t; i < s1; i += 256) {
        unsigned int p = part[i];
        int pos = atomicAdd(&lcur[p >> 24], 1);
        csr[pos] = (int)(p & 0xFFFFFFu);
    }
}

// ---------------- fused head weights ----------------
__global__ void k_fuse(const float* __restrict__ lin0_w, const float* __restrict__ lin0_b,
                       const float* __restrict__ lin1_w, const float* __restrict__ lin1_b,
                       const float* __restrict__ out_w, const float* __restrict__ out_b,
                       float* __restrict__ Wf0, float* __restrict__ Wf1, float* __restrict__ bf) {
    int idx = blockIdx.x * blockDim.x + threadIdx.x;
    if (idx < 2560) {
        int i = idx / 40, j = idx % 40;
        float a = 0.f;
        for (int k = 0; k < 64; k++) a += lin0_w[i * 64 + k] * out_w[k * 40 + j];
        Wf0[idx] = a;
    } else if (idx < 5120) {
        int r = idx - 2560;
        int i = r / 40, j = r % 40;
        float a = 0.f;
        for (int k = 0; k < 64; k++) a += lin1_w[i * 64 + k] * out_w[(64 + k) * 40 + j];
        Wf1[r] = a;
    } else if (idx < 5160) {
        int j = idx - 5120;
        float a = out_b[j];
        for (int k = 0; k < 64; k++) {
            a += lin0_b[k] * out_w[k * 40 + j];
            a += lin1_b[k] * out_w[(64 + k) * 40 + j];
        }
        bf[j] = a;
    }
}

// ---------------- transform GEMMs: 128 rows/block, 4 rows x 8 cols per thread ----------------
// x-tile staged bf16 TRANSPOSED in LDS (xs[k][row]) so 4 row-values at one k = one b64 read.
// Epilogue folds dinv and casts bf16.

__global__ __launch_bounds__(256) void k_gemm_128(const float* __restrict__ A,
                                                  const float* __restrict__ W,
                                                  const float* __restrict__ dinv,
                                                  unsigned short* __restrict__ Cb, int n) {
    __shared__ float ws[128 * 64];             // 32 KB
    __shared__ unsigned short xs[128 * 132];   // 33 KB, xs[k*132 + row]
    int t = threadIdx.x;
    for (int idx = t; idx < 2048; idx += 256) {
        float4 u = *(const float4*)(W + idx * 4);
        ws[idx * 4] = u.x; ws[idx * 4 + 1] = u.y; ws[idx * 4 + 2] = u.z; ws[idx * 4 + 3] = u.w;
    }
    int r0 = blockIdx.x * 128;
    for (int idx = t; idx < 4096; idx += 256) {   // 128 rows x 32 float4
        int r = idx >> 5;
        int k = (idx & 31) << 2;
        int gr = r0 + r; if (gr >= n) gr = n - 1;
        float4 u = *(const float4*)(A + (size_t)gr * 128 + k);
        xs[(k + 0) * 132 + r] = f2bf(u.x);
        xs[(k + 1) * 132 + r] = f2bf(u.y);
        xs[(k + 2) * 132 + r] = f2bf(u.z);
        xs[(k + 3) * 132 + r] = f2bf(u.w);
    }
    __syncthreads();
    int cg = t & 7;     // col group: cols cg*8..+7
    int rq = t >> 3;    // row quad: rows rq*4..+3
    float acc[4][8];
#pragma unroll
    for (int i = 0; i < 4; i++)
#pragma unroll
        for (int j = 0; j < 8; j++) acc[i][j] = 0.f;
    const float4* ws4 = (const float4*)ws;
    for (int k = 0; k < 128; k++) {
        uint2 up = *(const uint2*)(xs + k * 132 + rq * 4);
        float4 av = unp(up);
        float4 w0 = ws4[k * 16 + cg * 2];
        float4 w1 = ws4[k * 16 + cg * 2 + 1];
        float a[4] = {av.x, av.y, av.z, av.w};
        float w[8] = {w0.x, w0.y, w0.z, w0.w, w1.x, w1.y, w1.z, w1.w};
#pragma unroll
        for (int i = 0; i < 4; i++)
#pragma unroll
            for (int j = 0; j < 8; j++) acc[i][j] += a[i] * w[j];
    }
#pragma unroll
    for (int i = 0; i < 4; i++) {
        int gr = r0 + rq * 4 + i;
        if (gr < n) {
            float dv = dinv[gr];
            union { unsigned short h[8]; uint4 u; } p;
#pragma unroll
            for (int j = 0; j < 8; j++) p.h[j] = f2bf(dv * acc[i][j]);
            *(uint4*)(Cb + (size_t)gr * 64 + cg * 8) = p.u;
        }
    }
}

__global__ __launch_bounds__(256) void k_gemm_64(const float* __restrict__ A,
                                                 const float* __restrict__ W,
                                                 const float* __restrict__ dinv,
                                                 unsigned short* __restrict__ Cb, int n) {
    __shared__ float ws[64 * 64];              // 16 KB
    __shared__ unsigned short xs[64 * 132];    // 17 KB, xs[k*132 + row]
    int t = threadIdx.x;
    for (int idx = t; idx < 1024; idx += 256) {
        float4 u = *(const float4*)(W + idx * 4);
        ws[idx * 4] = u.x; ws[idx * 4 + 1] = u.y; ws[idx * 4 + 2] = u.z; ws[idx * 4 + 3] = u.w;
    }
    int r0 = blockIdx.x * 128;
    for (int idx = t; idx < 2048; idx += 256) {   // 128 rows x 16 float4
        int r = idx >> 4;
        int k = (idx & 15) << 2;
        int gr = r0 + r; if (gr >= n) gr = n - 1;
        float4 u = *(const float4*)(A + (size_t)gr * 64 + k);
        xs[(k + 0) * 132 + r] = f2bf(u.x);
        xs[(k + 1) * 132 + r] = f2bf(u.y);
        xs[(k + 2) * 132 + r] = f2bf(u.z);
        xs[(k + 3) * 132 + r] = f2bf(u.w);
    }
    __syncthreads();
    int cg = t & 7;
    int rq = t >> 3;
    float acc[4][8];
#pragma unroll
    for (int i = 0; i < 4; i++)
#pragma unroll
        for (int j = 0; j < 8; j++) acc[i][j] = 0.f;
    const float4* ws4 = (const float4*)ws;
    for (int k = 0; k < 64; k++) {
        uint2 up = *(const uint2*)(xs + k * 132 + rq * 4);
        float4 av = unp(up);
        float4 w0 = ws4[k * 16 + cg * 2];
        float4 w1 = ws4[k * 16 + cg * 2 + 1];
        float a[4] = {av.x, av.y, av.z, av.w};
        float w[8] = {w0.x, w0.y, w0.z, w0.w, w1.x, w1.y, w1.z, w1.w};
#pragma unroll
        for (int i = 0; i < 4; i++)
#pragma unroll
            for (int j = 0; j < 8; j++) acc[i][j] += a[i] * w[j];
    }
#pragma unroll
    for (int i = 0; i < 4; i++) {
        int gr = r0 + rq * 4 + i;
        if (gr < n) {
            float dv = dinv[gr];
            union { unsigned short h[8]; uint4 u; } p;
#pragma unroll
            for (int j = 0; j < 8; j++) p.h[j] = f2bf(dv * acc[i][j]);
            *(uint4*)(Cb + (size_t)gr * 64 + cg * 8) = p.u;
        }
    }
}

// ---------------- head GEMMs ----------------

__global__ __launch_bounds__(256) void k_gemm40(const float* __restrict__ H,
                                                const float* __restrict__ Wf,
                                                float* __restrict__ O, int n) {
    __shared__ float wfs[64 * 40];
    __shared__ float hs[32 * 65];
    int t = threadIdx.x;
    for (int idx = t; idx < 640; idx += 256) {
        float4 u = *(const float4*)(Wf + idx * 4);
        wfs[idx * 4] = u.x; wfs[idx * 4 + 1] = u.y; wfs[idx * 4 + 2] = u.z; wfs[idx * 4 + 3] = u.w;
    }
    int r0 = blockIdx.x * 32;
    for (int idx = t; idx < 512; idx += 256) {
        int base = idx * 4;
        int r = base >> 6, k = base & 63;
        int gr = r0 + r; if (gr >= n) gr = n - 1;
        float4 u = *(const float4*)(H + (size_t)gr * 64 + k);
        hs[r * 65 + k] = u.x; hs[r * 65 + k + 1] = u.y; hs[r * 65 + k + 2] = u.z; hs[r * 65 + k + 3] = u.w;
    }
    __syncthreads();
    int row = t >> 3, c0 = (t & 7) * 5;
    float acc[5] = {0.f, 0.f, 0.f, 0.f, 0.f};
    for (int k = 0; k < 64; k++) {
        float a = hs[row * 65 + k];
#pragma unroll
        for (int j = 0; j < 5; j++) acc[j] += a * wfs[k * 40 + c0 + j];
    }
    int gr = r0 + row;
    if (gr < n) {
#pragma unroll
        for (int j = 0; j < 5; j++) O[(size_t)gr * 40 + c0 + j] = acc[j];
    }
}

__global__ __launch_bounds__(256) void k_gemm40_final(const float* __restrict__ H,
                                                      const float* __restrict__ Wf,
                                                      const float* __restrict__ bf,
                                                      float* __restrict__ out, int n) {
    __shared__ float wfs[64 * 40];
    __shared__ float hs[32 * 65];
    int t = threadIdx.x;
    for (int idx = t; idx < 640; idx += 256) {
        float4 u = *(const float4*)(Wf + idx * 4);
        wfs[idx * 4] = u.x; wfs[idx * 4 + 1] = u.y; wfs[idx * 4 + 2] = u.z; wfs[idx * 4 + 3] = u.w;
    }
    int r0 = blockIdx.x * 32;
    for (int idx = t; idx < 512; idx += 256) {
        int base = idx * 4;
        int r = base >> 6, k = base & 63;
        int gr = r0 + r; if (gr >= n) gr = n - 1;
        float4 u = *(const float4*)(H + (size_t)gr * 64 + k);
        hs[r * 65 + k] = u.x; hs[r * 65 + k + 1] = u.y; hs[r * 65 + k + 2] = u.z; hs[r * 65 + k + 3] = u.w;
    }
    __syncthreads();
    int row = t >> 3, c0 = (t & 7) * 5;
    float acc[5] = {0.f, 0.f, 0.f, 0.f, 0.f};
    for (int k = 0; k < 64; k++) {
        float a = hs[row * 65 + k];
#pragma unroll
        for (int j = 0; j < 5; j++) acc[j] += a * wfs[k * 40 + c0 + j];
    }
    int gr = r0 + row;
    if (gr < n) {
#pragma unroll
        for (int j = 0; j < 5; j++) {
            size_t p = (size_t)gr * 40 + c0 + j;
            out[p] = out[p] + acc[j] + bf[c0 + j];
        }
    }
}

// ---------------- aggregation: wave/node, 4 lane-groups x 16, 16 rows in flight ----------------
__global__ __launch_bounds__(256) void k_agg(const unsigned short* __restrict__ T,
                                             const int* __restrict__ csr,
                                             const int* __restrict__ roffE,  // END offsets
                                             const float* __restrict__ bias,
                                             float* __restrict__ H, int n) {
    int lane = threadIdx.x & 63;
    int q = lane >> 4, h = lane & 15;
    int v = blockIdx.x * 4 + (threadIdx.x >> 6);
    if (v >= n) return;
    int start = (v == 0) ? 0 : roffE[v - 1];
    int end = roffE[v];
    float dv = rsqrtf((float)(end - start + 1));
    float4 acc = {0.f, 0.f, 0.f, 0.f};
    if (q == 0) {  // self-loop row (counted once)
        uint2 u = *(const uint2*)(T + (size_t)v * 64 + h * 4);
        float4 f = unp(u);
        acc.x += f.x; acc.y += f.y; acc.z += f.z; acc.w += f.w;
    }
    for (int base = start; base < end; base += 64) {
        int m = end - base; if (m > 64) m = 64;
        int e = (lane < m) ? csr[base + lane] : 0;
        int j = 0;
        for (; j + 16 <= m; j += 16) {
            int s0 = __shfl(e, j + q);
            int s1 = __shfl(e, j + 4 + q);
            int s2 = __shfl(e, j + 8 + q);
            int s3 = __shfl(e, j + 12 + q);
            uint2 u0 = *(const uint2*)(T + (size_t)s0 * 64 + h * 4);
            uint2 u1 = *(const uint2*)(T + (size_t)s1 * 64 + h * 4);
            uint2 u2 = *(const uint2*)(T + (size_t)s2 * 64 + h * 4);
            uint2 u3 = *(const uint2*)(T + (size_t)s3 * 64 + h * 4);
            float4 f0 = unp(u0), f1 = unp(u1), f2 = unp(u2), f3 = unp(u3);
            acc.x += (f0.x + f1.x) + (f2.x + f3.x);
            acc.y += (f0.y + f1.y) + (f2.y + f3.y);
            acc.z += (f0.z + f1.z) + (f2.z + f3.z);
            acc.w += (f0.w + f1.w) + (f2.w + f3.w);
        }
        for (; j + 4 <= m; j += 4) {
            int s = __shfl(e, j + q);
            uint2 u = *(const uint2*)(T + (size_t)s * 64 + h * 4);
            float4 f = unp(u);
            acc.x += f.x; acc.y += f.y; acc.z += f.z; acc.w += f.w;
        }
        if (j < m) {
            int jj = j + q;
            int s = __shfl(e, jj & 63);
            if (jj < m) {
                uint2 u = *(const uint2*)(T + (size_t)s * 64 + h * 4);
                float4 f = unp(u);
                acc.x += f.x; acc.y += f.y; acc.z += f.z; acc.w += f.w;
            }
        }
    }
    acc.x += __shfl_xor(acc.x, 16); acc.y += __shfl_xor(acc.y, 16);
    acc.z += __shfl_xor(acc.z, 16); acc.w += __shfl_xor(acc.w, 16);
    acc.x += __shfl_xor(acc.x, 32); acc.y += __shfl_xor(acc.y, 32);
    acc.z += __shfl_xor(acc.z, 32); acc.w += __shfl_xor(acc.w, 32);
    if (q == 0) {
        float4 bb = *(const float4*)(bias + h * 4);
        float4 r;
        r.x = dv * acc.x + bb.x;
        r.y = dv * acc.y + bb.y;
        r.z = dv * acc.z + bb.z;
        r.w = dv * acc.w + bb.w;
        r.x = (r.x > 0.f) ? r.x : (__expf(r.x) - 1.f);
        r.y = (r.y > 0.f) ? r.y : (__expf(r.y) - 1.f);
        r.z = (r.z > 0.f) ? r.z : (__expf(r.z) - 1.f);
        r.w = (r.w > 0.f) ? r.w : (__expf(r.w) - 1.f);
        *(float4*)(H + (size_t)v * 64 + h * 4) = r;
    }
}

// ---------------- launch ----------------

extern "C" void kernel_launch(void* const* d_in, const int* in_sizes, int n_in,
                              void* d_out, int out_size, void* d_ws, size_t ws_size,
                              hipStream_t stream) {
    const float* x       = (const float*)d_in[0];
    const int*   eidx    = (const int*)d_in[1];
    const float* conv0_w = (const float*)d_in[2];
    const float* conv0_b = (const float*)d_in[3];
    const float* lin0_w  = (const float*)d_in[4];
    const float* lin0_b  = (const float*)d_in[5];
    const float* conv1_w = (const float*)d_in[6];
    const float* conv1_b = (const float*)d_in[7];
    const float* lin1_w  = (const float*)d_in[8];
    const float* lin1_b  = (const float*)d_in[9];
    const float* out_w   = (const float*)d_in[10];
    const float* out_b   = (const float*)d_in[11];

    int n = in_sizes[0] / 128;
    int E = in_sizes[1] / 2;
    const int* src = eidx;
    const int* dst = eidx + E;
    int NB = (n + 255) >> 8;
    int gC = (E + CHUNK - 1) / CHUNK;

    char* wsb = (char*)d_ws;
    auto al = [](size_t v) { return (v + 4095) & ~(size_t)4095; };
    size_t o = 0;
    int*            Cmat  = (int*)(wsb + o);            o = al(o + (size_t)gC * 1024 * 4);
    int*            Omat  = (int*)(wsb + o);            o = al(o + (size_t)gC * 1024 * 4);
    int*            btot  = (int*)(wsb + o);            o = al(o + 1024 * 4);
    int*            boff  = (int*)(wsb + o);            o = al(o + 1025 * 4);
    float*          dinv  = (float*)(wsb + o);          o = al(o + (size_t)n * 4);
    int*            roff  = (int*)(wsb + o);            o = al(o + (size_t)n * 4);
    unsigned int*   part  = (unsigned int*)(wsb + o);   o = al(o + (size_t)E * 4);
    int*            csr   = (int*)(wsb + o);            o = al(o + (size_t)E * 4);
    float*          Wf0   = (float*)(wsb + o);          o = al(o + 2560 * 4);
    float*          Wf1   = (float*)(wsb + o);          o = al(o + 2560 * 4);
    float*          bfv   = (float*)(wsb + o);          o = al(o + 40 * 4);
    unsigned short* Ab    = (unsigned short*)(wsb + o); o = al(o + (size_t)n * 64 * 2);
    float*          B     = (float*)(wsb + o);          o = al(o + (size_t)n * 64 * 4);
    float* O = (float*)d_out;

    int gR40 = (n + 31) / 32;    // head gemms: 32 rows/block
    int gR128 = (n + 127) / 128; // transform gemms: 128 rows/block
    int gV = (n + 3) / 4;

    // CSR build — fully deterministic offsets, no inter-block atomics, no memset
    k_count<<<gC, 256, 0, stream>>>(dst, Cmat, E);
    k_wscan<<<256, 256, 0, stream>>>(Cmat, Omat, btot, gC);
    k_bscan<<<1, 1024, 0, stream>>>(btot, boff);
    k_part2<<<gC, 256, 0, stream>>>(src, dst, Omat, boff, part, E);
    k_fill_local<<<NB, 256, 0, stream>>>(part, boff, dinv, roff, csr, n);
    k_fuse<<<(5160 + 255) / 256, 256, 0, stream>>>(lin0_w, lin0_b, lin1_w, lin1_b, out_w, out_b,
                                                   Wf0, Wf1, bfv);

    // layer 0
    k_gemm_128<<<gR128, 256, 0, stream>>>(x, conv0_w, dinv, Ab, n);
    k_agg<<<gV, 256, 0, stream>>>(Ab, csr, roff, conv0_b, B, n);
    // head contribution of h (write O = B @ Wf0 into d_out)
    k_gemm40<<<gR40, 256, 0, stream>>>(B, Wf0, O, n);
    // layer 1
    k_gemm_64<<<gR128, 256, 0, stream>>>(B, conv1_w, dinv, Ab, n);
    k_agg<<<gV, 256, 0, stream>>>(Ab, csr, roff, conv1_b, B, n);
    // final head: out = O + B @ Wf1 + bf
    k_gemm40_final<<<gR40, 256, 0, stream>>>(B, Wf1, bfv, O, n);
}

// Round 9
// 324.386 us; speedup vs baseline: 2.1879x; 1.0545x over previous
//
#include <hip/hip_runtime.h>

#define DEVFN __device__ __forceinline__

typedef __attribute__((ext_vector_type(8))) short short8;
typedef __attribute__((ext_vector_type(4))) float float4v;

DEVFN float bf2f(unsigned short u) {
    union { unsigned int i; float f; } c;
    c.i = ((unsigned int)u) << 16;
    return c.f;
}

DEVFN unsigned short f2bf(float f) {
    union { float f; unsigned int i; } c;
    c.f = f;
    unsigned int u = c.i;
    return (unsigned short)((u + 0x7FFFu + ((u >> 16) & 1u)) >> 16);  // RNE
}

DEVFN float4 unp(uint2 u) {
    float4 f;
    f.x = bf2f((unsigned short)(u.x & 0xFFFFu));
    f.y = bf2f((unsigned short)(u.x >> 16));
    f.z = bf2f((unsigned short)(u.y & 0xFFFFu));
    f.w = bf2f((unsigned short)(u.y >> 16));
    return f;
}

// ---------------- deterministic 2-level bucket partition ----------------

#define CHUNK 4096

__global__ __launch_bounds__(256) void k_count(const int* __restrict__ dst,
                                               int* __restrict__ Cmat, int E) {
    __shared__ int lh[1024];
    int t = threadIdx.x;
    for (int b = t; b < 1024; b += 256) lh[b] = 0;
    __syncthreads();
    int i0 = blockIdx.x * CHUNK;
    int i1 = i0 + CHUNK; if (i1 > E) i1 = E;
    for (int i = i0 + t; i < i1; i += 256) atomicAdd(&lh[dst[i] >> 8], 1);
    __syncthreads();
    int* row = Cmat + (size_t)blockIdx.x * 1024;
    for (int b = t; b < 1024; b += 256) row[b] = lh[b];
}

__global__ __launch_bounds__(256) void k_wscan(const int* __restrict__ Cmat,
                                               int* __restrict__ Omat,
                                               int* __restrict__ btot, int gC) {
    int b = (blockIdx.x * 256 + threadIdx.x) >> 6;
    int lane = threadIdx.x & 63;
    int base = 0;
    for (int c0 = 0; c0 < gC; c0 += 64) {
        int c = c0 + lane;
        int x = (c < gC) ? Cmat[(size_t)c * 1024 + b] : 0;
        int orig = x;
#pragma unroll
        for (int off = 1; off < 64; off <<= 1) {
            int y = __shfl_up(x, off);
            if (lane >= off) x += y;
        }
        if (c < gC) Omat[(size_t)c * 1024 + b] = base + x - orig;
        base += __shfl(x, 63);
    }
    if (lane == 0) btot[b] = base;
}

__global__ __launch_bounds__(1024) void k_bscan(const int* __restrict__ btot,
                                                int* __restrict__ boff) {
    __shared__ int s[1024];
    int t = threadIdx.x;
    int v = btot[t];
    s[t] = v;
    __syncthreads();
    for (int o = 1; o < 1024; o <<= 1) {
        int x = (t >= o) ? s[t - o] : 0;
        __syncthreads();
        s[t] += x;
        __syncthreads();
    }
    boff[t] = s[t] - v;
    if (t == 1023) boff[1024] = s[t];
}

__global__ __launch_bounds__(256) void k_part2(const int* __restrict__ src,
                                               const int* __restrict__ dst,
                                               const int* __restrict__ Omat,
                                               const int* __restrict__ boff,
                                               unsigned int* __restrict__ part, int E) {
    __shared__ int lb[1024];
    __shared__ int lc[1024];
    int t = threadIdx.x;
    const int* orow = Omat + (size_t)blockIdx.x * 1024;
    for (int b = t; b < 1024; b += 256) {
        lb[b] = boff[b] + orow[b];
        lc[b] = 0;
    }
    __syncthreads();
    int i0 = blockIdx.x * CHUNK;
    int i1 = i0 + CHUNK; if (i1 > E) i1 = E;
    for (int i = i0 + t; i < i1; i += 256) {
        int d = dst[i];
        int b = d >> 8;
        int r = atomicAdd(&lc[b], 1);
        part[lb[b] + r] = (unsigned int)src[i] | ((unsigned int)(d & 255) << 24);
    }
}

__global__ __launch_bounds__(256) void k_fill_local(const unsigned int* __restrict__ part,
                                                    const int* __restrict__ boff,
                                                    float* __restrict__ dinv,
                                                    int* __restrict__ roff,
                                                    int* __restrict__ csr, int n) {
    __shared__ int lcnt[256];
    __shared__ int lsc[256];
    __shared__ int lcur[256];
    int b = blockIdx.x, t = threadIdx.x;
    int s0 = boff[b], s1 = boff[b + 1];
    lcnt[t] = 0;
    __syncthreads();
    for (int i = s0 + t; i < s1; i += 256) atomicAdd(&lcnt[part[i] >> 24], 1);
    __syncthreads();
    int v = lcnt[t];
    lsc[t] = v;
    __syncthreads();
    for (int o = 1; o < 256; o <<= 1) {
        int x = (t >= o) ? lsc[t - o] : 0;
        __syncthreads();
        lsc[t] += x;
        __syncthreads();
    }
    int excl = lsc[t] - v;
    int node = (b << 8) + t;
    if (node < n) {
        dinv[node] = rsqrtf((float)(v + 1));  // +1 self-loop
        roff[node] = s0 + excl + v;           // END offset
    }
    lcur[t] = s0 + excl;
    __syncthreads();
    for (int i = s0 + t; i < s1; i += 256) {
        unsigned int p = part[i];
        int pos = atomicAdd(&lcur[p >> 24], 1);
        csr[pos] = (int)(p & 0xFFFFFFu);
    }
}

// ---------------- fused head weights ----------------
__global__ void k_fuse(const float* __restrict__ lin0_w, const float* __restrict__ lin0_b,
                       const float* __restrict__ lin1_w, const float* __restrict__ lin1_b,
                       const float* __restrict__ out_w, const float* __restrict__ out_b,
                       float* __restrict__ Wf0, float* __restrict__ Wf1, float* __restrict__ bf) {
    int idx = blockIdx.x * blockDim.x + threadIdx.x;
    if (idx < 2560) {
        int i = idx / 40, j = idx % 40;
        float a = 0.f;
        for (int k = 0; k < 64; k++) a += lin0_w[i * 64 + k] * out_w[k * 40 + j];
        Wf0[idx] = a;
    } else if (idx < 5120) {
        int r = idx - 2560;
        int i = r / 40, j = r % 40;
        float a = 0.f;
        for (int k = 0; k < 64; k++) a += lin1_w[i * 64 + k] * out_w[(64 + k) * 40 + j];
        Wf1[r] = a;
    } else if (idx < 5160) {
        int j = idx - 5120;
        float a = out_b[j];
        for (int k = 0; k < 64; k++) {
            a += lin0_b[k] * out_w[k * 40 + j];
            a += lin1_b[k] * out_w[(64 + k) * 40 + j];
        }
        bf[j] = a;
    }
}

// ---------------- W pre-swizzle into MFMA B-fragment order ----------------
// Wb layout: [ks][nt][lane][j] bf16, value = W[ks*32 + (lane>>4)*8 + j][nt*16 + (lane&15)]
// Wb0: conv0_w (K=128 -> 4 ks).  Wb1: conv1_w (K=64 -> 2 ks).
__global__ __launch_bounds__(256) void k_prepw(const float* __restrict__ W0,
                                               const float* __restrict__ W1,
                                               unsigned short* __restrict__ Wb0,
                                               unsigned short* __restrict__ Wb1) {
    int tid = blockIdx.x * 256 + threadIdx.x;
    if (tid < 1024) {
        int ks = tid >> 8, rem = tid & 255;
        int nt = rem >> 6, lane = rem & 63;
        int quad = lane >> 4, c = lane & 15;
        union { unsigned short h[8]; uint4 u[2]; } p;
#pragma unroll
        for (int j = 0; j < 8; j++)
            p.h[j] = f2bf(W0[(ks * 32 + quad * 8 + j) * 64 + nt * 16 + c]);
        *(uint4*)(Wb0 + (size_t)tid * 8) = p.u[0];
    } else if (tid < 1536) {
        int t2 = tid - 1024;
        int ks = t2 >> 8, rem = t2 & 255;
        int nt = rem >> 6, lane = rem & 63;
        int quad = lane >> 4, c = lane & 15;
        union { unsigned short h[8]; uint4 u[2]; } p;
#pragma unroll
        for (int j = 0; j < 8; j++)
            p.h[j] = f2bf(W1[(ks * 32 + quad * 8 + j) * 64 + nt * 16 + c]);
        *(uint4*)(Wb1 + (size_t)t2 * 8) = p.u[0];
    }
}

// ---------------- MFMA transform GEMMs ----------------
// 64 rows/block (4 waves x 16-row tile). A staged in LDS in A-fragment order,
// per (tile,ks,quad) group of 144 bf16 (128 data + 16 pad; b128 reads conflict-free).
// B-frags loaded from pre-swizzled Wb (global, L2-resident). Epilogue folds dinv, casts bf16.

__global__ __launch_bounds__(256) void k_gemm_128(const float* __restrict__ A,
                                                  const unsigned short* __restrict__ Wb,
                                                  const float* __restrict__ dinv,
                                                  unsigned short* __restrict__ Cb, int n) {
    __shared__ unsigned short aLDS[64 * 144];  // (tile*4+ks)*4+quad groups, 18 KB
    int t = threadIdx.x;
    int r0 = blockIdx.x * 64;
    for (int idx = t; idx < 2048; idx += 256) {   // 64 rows x 32 float4
        int r = idx >> 5;
        int k = (idx & 31) << 2;
        int gr = r0 + r; if (gr >= n) gr = n - 1;
        float4 u = *(const float4*)(A + (size_t)gr * 128 + k);
        int tile = r >> 4, m = r & 15;
        int ks = k >> 5, quad = (k >> 3) & 3, j0 = k & 7;
        int g = (tile * 4 + ks) * 4 + quad;
        union { unsigned short h[4]; uint2 u2; } pk;
        pk.h[0] = f2bf(u.x); pk.h[1] = f2bf(u.y); pk.h[2] = f2bf(u.z); pk.h[3] = f2bf(u.w);
        *(uint2*)(aLDS + g * 144 + m * 8 + j0) = pk.u2;
    }
    int lane = t & 63;
    int w = t >> 6;
    short8 bfr[4][4];
#pragma unroll
    for (int ks = 0; ks < 4; ks++)
#pragma unroll
        for (int nt = 0; nt < 4; nt++)
            bfr[ks][nt] = *(const short8*)(Wb + ((size_t)(ks * 4 + nt) * 64 + lane) * 8);
    __syncthreads();
    int quad = lane >> 4, m = lane & 15;
    short8 afr[4];
#pragma unroll
    for (int ks = 0; ks < 4; ks++)
        afr[ks] = *(const short8*)(aLDS + ((w * 4 + ks) * 4 + quad) * 144 + m * 8);
    float4v acc[4] = {};
#pragma unroll
    for (int nt = 0; nt < 4; nt++)
#pragma unroll
        for (int ks = 0; ks < 4; ks++)
            acc[nt] = __builtin_amdgcn_mfma_f32_16x16x32_bf16(afr[ks], bfr[ks][nt], acc[nt], 0, 0, 0);
    float dv[4];
#pragma unroll
    for (int reg = 0; reg < 4; reg++) {
        int gr = r0 + w * 16 + quad * 4 + reg;
        dv[reg] = (gr < n) ? dinv[gr] : 0.f;
    }
#pragma unroll
    for (int nt = 0; nt < 4; nt++)
#pragma unroll
        for (int reg = 0; reg < 4; reg++) {
            int gr = r0 + w * 16 + quad * 4 + reg;
            if (gr < n) Cb[(size_t)gr * 64 + nt * 16 + m] = f2bf(dv[reg] * acc[nt][reg]);
        }
}

__global__ __launch_bounds__(256) void k_gemm_64(const float* __restrict__ A,
                                                 const unsigned short* __restrict__ Wb,
                                                 const float* __restrict__ dinv,
                                                 unsigned short* __restrict__ Cb, int n) {
    __shared__ unsigned short aLDS[32 * 144];  // (tile*2+ks)*4+quad groups, 9 KB
    int t = threadIdx.x;
    int r0 = blockIdx.x * 64;
    for (int idx = t; idx < 1024; idx += 256) {   // 64 rows x 16 float4
        int r = idx >> 4;
        int k = (idx & 15) << 2;
        int gr = r0 + r; if (gr >= n) gr = n - 1;
        float4 u = *(const float4*)(A + (size_t)gr * 64 + k);
        int tile = r >> 4, m = r & 15;
        int ks = k >> 5, quad = (k >> 3) & 3, j0 = k & 7;
        int g = (tile * 2 + ks) * 4 + quad;
        union { unsigned short h[4]; uint2 u2; } pk;
        pk.h[0] = f2bf(u.x); pk.h[1] = f2bf(u.y); pk.h[2] = f2bf(u.z); pk.h[3] = f2bf(u.w);
        *(uint2*)(aLDS + g * 144 + m * 8 + j0) = pk.u2;
    }
    int lane = t & 63;
    int w = t >> 6;
    short8 bfr[2][4];
#pragma unroll
    for (int ks = 0; ks < 2; ks++)
#pragma unroll
        for (int nt = 0; nt < 4; nt++)
            bfr[ks][nt] = *(const short8*)(Wb + ((size_t)(ks * 4 + nt) * 64 + lane) * 8);
    __syncthreads();
    int quad = lane >> 4, m = lane & 15;
    short8 afr[2];
#pragma unroll
    for (int ks = 0; ks < 2; ks++)
        afr[ks] = *(const short8*)(aLDS + ((w * 2 + ks) * 4 + quad) * 144 + m * 8);
    float4v acc[4] = {};
#pragma unroll
    for (int nt = 0; nt < 4; nt++)
#pragma unroll
        for (int ks = 0; ks < 2; ks++)
            acc[nt] = __builtin_amdgcn_mfma_f32_16x16x32_bf16(afr[ks], bfr[ks][nt], acc[nt], 0, 0, 0);
    float dv[4];
#pragma unroll
    for (int reg = 0; reg < 4; reg++) {
        int gr = r0 + w * 16 + quad * 4 + reg;
        dv[reg] = (gr < n) ? dinv[gr] : 0.f;
    }
#pragma unroll
    for (int nt = 0; nt < 4; nt++)
#pragma unroll
        for (int reg = 0; reg < 4; reg++) {
            int gr = r0 + w * 16 + quad * 4 + reg;
            if (gr < n) Cb[(size_t)gr * 64 + nt * 16 + m] = f2bf(dv[reg] * acc[nt][reg]);
        }
}

// ---------------- head GEMMs ----------------

__global__ __launch_bounds__(256) void k_gemm40(const float* __restrict__ H,
                                                const float* __restrict__ Wf,
                                                float* __restrict__ O, int n) {
    __shared__ float wfs[64 * 40];
    __shared__ float hs[32 * 65];
    int t = threadIdx.x;
    for (int idx = t; idx < 640; idx += 256) {
        float4 u = *(const float4*)(Wf + idx * 4);
        wfs[idx * 4] = u.x; wfs[idx * 4 + 1] = u.y; wfs[idx * 4 + 2] = u.z; wfs[idx * 4 + 3] = u.w;
    }
    int r0 = blockIdx.x * 32;
    for (int idx = t; idx < 512; idx += 256) {
        int base = idx * 4;
        int r = base >> 6, k = base & 63;
        int gr = r0 + r; if (gr >= n) gr = n - 1;
        float4 u = *(const float4*)(H + (size_t)gr * 64 + k);
        hs[r * 65 + k] = u.x; hs[r * 65 + k + 1] = u.y; hs[r * 65 + k + 2] = u.z; hs[r * 65 + k + 3] = u.w;
    }
    __syncthreads();
    int row = t >> 3, c0 = (t & 7) * 5;
    float acc[5] = {0.f, 0.f, 0.f, 0.f, 0.f};
    for (int k = 0; k < 64; k++) {
        float a = hs[row * 65 + k];
#pragma unroll
        for (int j = 0; j < 5; j++) acc[j] += a * wfs[k * 40 + c0 + j];
    }
    int gr = r0 + row;
    if (gr < n) {
#pragma unroll
        for (int j = 0; j < 5; j++) O[(size_t)gr * 40 + c0 + j] = acc[j];
    }
}

__global__ __launch_bounds__(256) void k_gemm40_final(const float* __restrict__ H,
                                                      const float* __restrict__ Wf,
                                                      const float* __restrict__ bf,
                                                      float* __restrict__ out, int n) {
    __shared__ float wfs[64 * 40];
    __shared__ float hs[32 * 65];
    int t = threadIdx.x;
    for (int idx = t; idx < 640; idx += 256) {
        float4 u = *(const float4*)(Wf + idx * 4);
        wfs[idx * 4] = u.x; wfs[idx * 4 + 1] = u.y; wfs[idx * 4 + 2] = u.z; wfs[idx * 4 + 3] = u.w;
    }
    int r0 = blockIdx.x * 32;
    for (int idx = t; idx < 512; idx += 256) {
        int base = idx * 4;
        int r = base >> 6, k = base & 63;
        int gr = r0 + r; if (gr >= n) gr = n - 1;
        float4 u = *(const float4*)(H + (size_t)gr * 64 + k);
        hs[r * 65 + k] = u.x; hs[r * 65 + k + 1] = u.y; hs[r * 65 + k + 2] = u.z; hs[r * 65 + k + 3] = u.w;
    }
    __syncthreads();
    int row = t >> 3, c0 = (t & 7) * 5;
    float acc[5] = {0.f, 0.f, 0.f, 0.f, 0.f};
    for (int k = 0; k < 64; k++) {
        float a = hs[row * 65 + k];
#pragma unroll
        for (int j = 0; j < 5; j++) acc[j] += a * wfs[k * 40 + c0 + j];
    }
    int gr = r0 + row;
    if (gr < n) {
#pragma unroll
        for (int j = 0; j < 5; j++) {
            size_t p = (size_t)gr * 40 + c0 + j;
            out[p] = out[p] + acc[j] + bf[c0 + j];
        }
    }
}

// ---------------- aggregation: wave/node, 4 lane-groups x 16, 16 rows in flight ----------------
__global__ __launch_bounds__(256) void k_agg(const unsigned short* __restrict__ T,
                                             const int* __restrict__ csr,
                                             const int* __restrict__ roffE,  // END offsets
                                             const float* __restrict__ bias,
                                             float* __restrict__ H, int n) {
    int lane = threadIdx.x & 63;
    int q = lane >> 4, h = lane & 15;
    int v = blockIdx.x * 4 + (threadIdx.x >> 6);
    if (v >= n) return;
    int start = (v == 0) ? 0 : roffE[v - 1];
    int end = roffE[v];
    float dv = rsqrtf((float)(end - start + 1));
    float4 acc = {0.f, 0.f, 0.f, 0.f};
    if (q == 0) {  // self-loop row (counted once)
        uint2 u = *(const uint2*)(T + (size_t)v * 64 + h * 4);
        float4 f = unp(u);
        acc.x += f.x; acc.y += f.y; acc.z += f.z; acc.w += f.w;
    }
    for (int base = start; base < end; base += 64) {
        int m = end - base; if (m > 64) m = 64;
        int e = (lane < m) ? csr[base + lane] : 0;
        int j = 0;
        for (; j + 16 <= m; j += 16) {
            int s0 = __shfl(e, j + q);
            int s1 = __shfl(e, j + 4 + q);
            int s2 = __shfl(e, j + 8 + q);
            int s3 = __shfl(e, j + 12 + q);
            uint2 u0 = *(const uint2*)(T + (size_t)s0 * 64 + h * 4);
            uint2 u1 = *(const uint2*)(T + (size_t)s1 * 64 + h * 4);
            uint2 u2 = *(const uint2*)(T + (size_t)s2 * 64 + h * 4);
            uint2 u3 = *(const uint2*)(T + (size_t)s3 * 64 + h * 4);
            float4 f0 = unp(u0), f1 = unp(u1), f2 = unp(u2), f3 = unp(u3);
            acc.x += (f0.x + f1.x) + (f2.x + f3.x);
            acc.y += (f0.y + f1.y) + (f2.y + f3.y);
            acc.z += (f0.z + f1.z) + (f2.z + f3.z);
            acc.w += (f0.w + f1.w) + (f2.w + f3.w);
        }
        for (; j + 4 <= m; j += 4) {
            int s = __shfl(e, j + q);
            uint2 u = *(const uint2*)(T + (size_t)s * 64 + h * 4);
            float4 f = unp(u);
            acc.x += f.x; acc.y += f.y; acc.z += f.z; acc.w += f.w;
        }
        if (j < m) {
            int jj = j + q;
            int s = __shfl(e, jj & 63);
            if (jj < m) {
                uint2 u = *(const uint2*)(T + (size_t)s * 64 + h * 4);
                float4 f = unp(u);
                acc.x += f.x; acc.y += f.y; acc.z += f.z; acc.w += f.w;
            }
        }
    }
    acc.x += __shfl_xor(acc.x, 16); acc.y += __shfl_xor(acc.y, 16);
    acc.z += __shfl_xor(acc.z, 16); acc.w += __shfl_xor(acc.w, 16);
    acc.x += __shfl_xor(acc.x, 32); acc.y += __shfl_xor(acc.y, 32);
    acc.z += __shfl_xor(acc.z, 32); acc.w += __shfl_xor(acc.w, 32);
    if (q == 0) {
        float4 bb = *(const float4*)(bias + h * 4);
        float4 r;
        r.x = dv * acc.x + bb.x;
        r.y = dv * acc.y + bb.y;
        r.z = dv * acc.z + bb.z;
        r.w = dv * acc.w + bb.w;
        r.x = (r.x > 0.f) ? r.x : (__expf(r.x) - 1.f);
        r.y = (r.y > 0.f) ? r.y : (__expf(r.y) - 1.f);
        r.z = (r.z > 0.f) ? r.z : (__expf(r.z) - 1.f);
        r.w = (r.w > 0.f) ? r.w : (__expf(r.w) - 1.f);
        *(float4*)(H + (size_t)v * 64 + h * 4) = r;
    }
}

// ---------------- launch ----------------

extern "C" void kernel_launch(void* const* d_in, const int* in_sizes, int n_in,
                              void* d_out, int out_size, void* d_ws, size_t ws_size,
                              hipStream_t stream) {
    const float* x       = (const float*)d_in[0];
    const int*   eidx    = (const int*)d_in[1];
    const float* conv0_w = (const float*)d_in[2];
    const float* conv0_b = (const float*)d_in[3];
    const float* lin0_w  = (const float*)d_in[4];
    const float* lin0_b  = (const float*)d_in[5];
    const float* conv1_w = (const float*)d_in[6];
    const float* conv1_b = (const float*)d_in[7];
    const float* lin1_w  = (const float*)d_in[8];
    const float* lin1_b  = (const float*)d_in[9];
    const float* out_w   = (const float*)d_in[10];
    const float* out_b   = (const float*)d_in[11];

    int n = in_sizes[0] / 128;
    int E = in_sizes[1] / 2;
    const int* src = eidx;
    const int* dst = eidx + E;
    int NB = (n + 255) >> 8;
    int gC = (E + CHUNK - 1) / CHUNK;

    char* wsb = (char*)d_ws;
    auto al = [](size_t v) { return (v + 4095) & ~(size_t)4095; };
    size_t o = 0;
    int*            Cmat  = (int*)(wsb + o);            o = al(o + (size_t)gC * 1024 * 4);
    int*            Omat  = (int*)(wsb + o);            o = al(o + (size_t)gC * 1024 * 4);
    int*            btot  = (int*)(wsb + o);            o = al(o + 1024 * 4);
    int*            boff  = (int*)(wsb + o);            o = al(o + 1025 * 4);
    float*          dinv  = (float*)(wsb + o);          o = al(o + (size_t)n * 4);
    int*            roff  = (int*)(wsb + o);            o = al(o + (size_t)n * 4);
    unsigned int*   part  = (unsigned int*)(wsb + o);   o = al(o + (size_t)E * 4);
    int*            csr   = (int*)(wsb + o);            o = al(o + (size_t)E * 4);
    float*          Wf0   = (float*)(wsb + o);          o = al(o + 2560 * 4);
    float*          Wf1   = (float*)(wsb + o);          o = al(o + 2560 * 4);
    float*          bfv   = (float*)(wsb + o);          o = al(o + 40 * 4);
    unsigned short* Wb0   = (unsigned short*)(wsb + o); o = al(o + 8192 * 2);
    unsigned short* Wb1   = (unsigned short*)(wsb + o); o = al(o + 4096 * 2);
    unsigned short* Ab    = (unsigned short*)(wsb + o); o = al(o + (size_t)n * 64 * 2);
    float*          B     = (float*)(wsb + o);          o = al(o + (size_t)n * 64 * 4);
    float* O = (float*)d_out;

    int gR40 = (n + 31) / 32;   // head gemms: 32 rows/block
    int gT = (n + 63) / 64;     // MFMA transform gemms: 64 rows/block
    int gV = (n + 3) / 4;

    // CSR build — fully deterministic offsets, no inter-block atomics, no memset
    k_count<<<gC, 256, 0, stream>>>(dst, Cmat, E);
    k_wscan<<<256, 256, 0, stream>>>(Cmat, Omat, btot, gC);
    k_bscan<<<1, 1024, 0, stream>>>(btot, boff);
    k_part2<<<gC, 256, 0, stream>>>(src, dst, Omat, boff, part, E);
    k_fill_local<<<NB, 256, 0, stream>>>(part, boff, dinv, roff, csr, n);
    k_fuse<<<(5160 + 255) / 256, 256, 0, stream>>>(lin0_w, lin0_b, lin1_w, lin1_b, out_w, out_b,
                                                   Wf0, Wf1, bfv);
    k_prepw<<<6, 256, 0, stream>>>(conv0_w, conv1_w, Wb0, Wb1);

    // layer 0
    k_gemm_128<<<gT, 256, 0, stream>>>(x, Wb0, dinv, Ab, n);
    k_agg<<<gV, 256, 0, stream>>>(Ab, csr, roff, conv0_b, B, n);
    // head contribution of h (write O = B @ Wf0 into d_out)
    k_gemm40<<<gR40, 256, 0, stream>>>(B, Wf0, O, n);
    // layer 1
    k_gemm_64<<<gT, 256, 0, stream>>>(B, Wb1, dinv, Ab, n);
    k_agg<<<gV, 256, 0, stream>>>(Ab, csr, roff, conv1_b, B, n);
    // final head: out = O + B @ Wf1 + bf
    k_gemm40_final<<<gR40, 256, 0, stream>>>(B, Wf1, bfv, O, n);
}

// Round 10
// 297.807 us; speedup vs baseline: 2.3832x; 1.0892x over previous
//
#include <hip/hip_runtime.h>

#define DEVFN __device__ __forceinline__

typedef __attribute__((ext_vector_type(8))) short short8;
typedef __attribute__((ext_vector_type(4))) float float4v;

DEVFN float bf2f(unsigned short u) {
    union { unsigned int i; float f; } c;
    c.i = ((unsigned int)u) << 16;
    return c.f;
}

DEVFN unsigned short f2bf(float f) {
    union { float f; unsigned int i; } c;
    c.f = f;
    unsigned int u = c.i;
    return (unsigned short)((u + 0x7FFFu + ((u >> 16) & 1u)) >> 16);  // RNE
}

// accumulate 8 bf16 (uint4) into 8 fp32
DEVFN void addu4(float* acc, uint4 u) {
    unsigned int w[4] = {u.x, u.y, u.z, u.w};
#pragma unroll
    for (int k = 0; k < 4; k++) {
        union { unsigned int i; float f; } lo, hi;
        lo.i = w[k] << 16;
        hi.i = w[k] & 0xFFFF0000u;
        acc[2 * k]     += lo.f;
        acc[2 * k + 1] += hi.f;
    }
}

// ---------------- deterministic 2-level bucket partition ----------------

#define CHUNK 4096

__global__ __launch_bounds__(256) void k_count(const int* __restrict__ dst,
                                               int* __restrict__ Cmat, int E) {
    __shared__ int lh[1024];
    int t = threadIdx.x;
    for (int b = t; b < 1024; b += 256) lh[b] = 0;
    __syncthreads();
    int i0 = blockIdx.x * CHUNK;
    int i1 = i0 + CHUNK; if (i1 > E) i1 = E;
    for (int i = i0 + t; i < i1; i += 256) atomicAdd(&lh[dst[i] >> 8], 1);
    __syncthreads();
    int* row = Cmat + (size_t)blockIdx.x * 1024;
    for (int b = t; b < 1024; b += 256) row[b] = lh[b];
}

__global__ __launch_bounds__(256) void k_wscan(const int* __restrict__ Cmat,
                                               int* __restrict__ Omat,
                                               int* __restrict__ btot, int gC) {
    int b = (blockIdx.x * 256 + threadIdx.x) >> 6;
    int lane = threadIdx.x & 63;
    int base = 0;
    for (int c0 = 0; c0 < gC; c0 += 64) {
        int c = c0 + lane;
        int x = (c < gC) ? Cmat[(size_t)c * 1024 + b] : 0;
        int orig = x;
#pragma unroll
        for (int off = 1; off < 64; off <<= 1) {
            int y = __shfl_up(x, off);
            if (lane >= off) x += y;
        }
        if (c < gC) Omat[(size_t)c * 1024 + b] = base + x - orig;
        base += __shfl(x, 63);
    }
    if (lane == 0) btot[b] = base;
}

__global__ __launch_bounds__(1024) void k_bscan(const int* __restrict__ btot,
                                                int* __restrict__ boff) {
    __shared__ int s[1024];
    int t = threadIdx.x;
    int v = btot[t];
    s[t] = v;
    __syncthreads();
    for (int o = 1; o < 1024; o <<= 1) {
        int x = (t >= o) ? s[t - o] : 0;
        __syncthreads();
        s[t] += x;
        __syncthreads();
    }
    boff[t] = s[t] - v;
    if (t == 1023) boff[1024] = s[t];
}

__global__ __launch_bounds__(256) void k_part2(const int* __restrict__ src,
                                               const int* __restrict__ dst,
                                               const int* __restrict__ Omat,
                                               const int* __restrict__ boff,
                                               unsigned int* __restrict__ part, int E) {
    __shared__ int lb[1024];
    __shared__ int lc[1024];
    int t = threadIdx.x;
    const int* orow = Omat + (size_t)blockIdx.x * 1024;
    for (int b = t; b < 1024; b += 256) {
        lb[b] = boff[b] + orow[b];
        lc[b] = 0;
    }
    __syncthreads();
    int i0 = blockIdx.x * CHUNK;
    int i1 = i0 + CHUNK; if (i1 > E) i1 = E;
    for (int i = i0 + t; i < i1; i += 256) {
        int d = dst[i];
        int b = d >> 8;
        int r = atomicAdd(&lc[b], 1);
        part[lb[b] + r] = (unsigned int)src[i] | ((unsigned int)(d & 255) << 24);
    }
}

__global__ __launch_bounds__(256) void k_fill_local(const unsigned int* __restrict__ part,
                                                    const int* __restrict__ boff,
                                                    float* __restrict__ dinv,
                                                    int* __restrict__ roff,
                                                    int* __restrict__ csr, int n) {
    __shared__ int lcnt[256];
    __shared__ int lsc[256];
    __shared__ int lcur[256];
    int b = blockIdx.x, t = threadIdx.x;
    int s0 = boff[b], s1 = boff[b + 1];
    lcnt[t] = 0;
    __syncthreads();
    for (int i = s0 + t; i < s1; i += 256) atomicAdd(&lcnt[part[i] >> 24], 1);
    __syncthreads();
    int v = lcnt[t];
    lsc[t] = v;
    __syncthreads();
    for (int o = 1; o < 256; o <<= 1) {
        int x = (t >= o) ? lsc[t - o] : 0;
        __syncthreads();
        lsc[t] += x;
        __syncthreads();
    }
    int excl = lsc[t] - v;
    int node = (b << 8) + t;
    if (node < n) {
        dinv[node] = rsqrtf((float)(v + 1));  // +1 self-loop
        roff[node] = s0 + excl + v;           // END offset
    }
    lcur[t] = s0 + excl;
    __syncthreads();
    for (int i = s0 + t; i < s1; i += 256) {
        unsigned int p = part[i];
        int pos = atomicAdd(&lcur[p >> 24], 1);
        csr[pos] = (int)(p & 0xFFFFFFu);
    }
}

// ---------------- fused head weights ----------------
__global__ void k_fuse(const float* __restrict__ lin0_w, const float* __restrict__ lin0_b,
                       const float* __restrict__ lin1_w, const float* __restrict__ lin1_b,
                       const float* __restrict__ out_w, const float* __restrict__ out_b,
                       float* __restrict__ Wf0, float* __restrict__ Wf1, float* __restrict__ bf) {
    int idx = blockIdx.x * blockDim.x + threadIdx.x;
    if (idx < 2560) {
        int i = idx / 40, j = idx % 40;
        float a = 0.f;
        for (int k = 0; k < 64; k++) a += lin0_w[i * 64 + k] * out_w[k * 40 + j];
        Wf0[idx] = a;
    } else if (idx < 5120) {
        int r = idx - 2560;
        int i = r / 40, j = r % 40;
        float a = 0.f;
        for (int k = 0; k < 64; k++) a += lin1_w[i * 64 + k] * out_w[(64 + k) * 40 + j];
        Wf1[r] = a;
    } else if (idx < 5160) {
        int j = idx - 5120;
        float a = out_b[j];
        for (int k = 0; k < 64; k++) {
            a += lin0_b[k] * out_w[k * 40 + j];
            a += lin1_b[k] * out_w[(64 + k) * 40 + j];
        }
        bf[j] = a;
    }
}

// ---------------- weight pre-swizzle into MFMA B-fragment order ----------------
// Wb:  [ks][nt][lane][j] bf16, value = W[ks*32 + (lane>>4)*8 + j][nt*16 + (lane&15)]
// Wb0: conv0_w (K=128, nt 0..3).  Wb1: conv1_w (K=64, nt 0..3).
// Wfb0/Wfb1: head weights (K=64, nt 0..2, cols padded 40->48 with zeros).
__global__ __launch_bounds__(256) void k_prepw(const float* __restrict__ W0,
                                               const float* __restrict__ W1,
                                               const float* __restrict__ Wf0,
                                               const float* __restrict__ Wf1,
                                               unsigned short* __restrict__ Wb0,
                                               unsigned short* __restrict__ Wb1,
                                               unsigned short* __restrict__ Wfb0,
                                               unsigned short* __restrict__ Wfb1) {
    int tid = blockIdx.x * 256 + threadIdx.x;
    if (tid < 1024) {
        int ks = tid >> 8, rem = tid & 255;
        int nt = rem >> 6, lane = rem & 63;
        int quad = lane >> 4, c = lane & 15;
        union { unsigned short h[8]; uint4 u; } p;
#pragma unroll
        for (int j = 0; j < 8; j++)
            p.h[j] = f2bf(W0[(ks * 32 + quad * 8 + j) * 64 + nt * 16 + c]);
        *(uint4*)(Wb0 + (size_t)tid * 8) = p.u;
    } else if (tid < 1536) {
        int t2 = tid - 1024;
        int ks = t2 >> 8, rem = t2 & 255;
        int nt = rem >> 6, lane = rem & 63;
        int quad = lane >> 4, c = lane & 15;
        union { unsigned short h[8]; uint4 u; } p;
#pragma unroll
        for (int j = 0; j < 8; j++)
            p.h[j] = f2bf(W1[(ks * 32 + quad * 8 + j) * 64 + nt * 16 + c]);
        *(uint4*)(Wb1 + (size_t)t2 * 8) = p.u;
    } else if (tid < 1920) {
        int t2 = tid - 1536;          // 0..383
        int ks = t2 / 192;
        int rem = t2 % 192;
        int nt = rem >> 6, lane = rem & 63;
        int quad = lane >> 4, c = lane & 15;
        int col = nt * 16 + c;
        union { unsigned short h[8]; uint4 u; } p;
#pragma unroll
        for (int j = 0; j < 8; j++)
            p.h[j] = (col < 40) ? f2bf(Wf0[(ks * 32 + quad * 8 + j) * 40 + col]) : (unsigned short)0;
        *(uint4*)(Wfb0 + ((size_t)(ks * 3 + nt) * 64 + lane) * 8) = p.u;
    } else if (tid < 2304) {
        int t2 = tid - 1920;
        int ks = t2 / 192;
        int rem = t2 % 192;
        int nt = rem >> 6, lane = rem & 63;
        int quad = lane >> 4, c = lane & 15;
        int col = nt * 16 + c;
        union { unsigned short h[8]; uint4 u; } p;
#pragma unroll
        for (int j = 0; j < 8; j++)
            p.h[j] = (col < 40) ? f2bf(Wf1[(ks * 32 + quad * 8 + j) * 40 + col]) : (unsigned short)0;
        *(uint4*)(Wfb1 + ((size_t)(ks * 3 + nt) * 64 + lane) * 8) = p.u;
    }
}

// ---------------- MFMA transform GEMMs ----------------
// 64 rows/block (4 waves x 16-row tile). A staged in LDS in A-fragment order,
// per (tile,ks,quad) group of 144 bf16. B-frags from pre-swizzled Wb.
// Epilogue folds dinv, casts bf16.

__global__ __launch_bounds__(256) void k_gemm_128(const float* __restrict__ A,
                                                  const unsigned short* __restrict__ Wb,
                                                  const float* __restrict__ dinv,
                                                  unsigned short* __restrict__ Cb, int n) {
    __shared__ unsigned short aLDS[64 * 144];  // 18 KB
    int t = threadIdx.x;
    int r0 = blockIdx.x * 64;
    for (int idx = t; idx < 2048; idx += 256) {   // 64 rows x 32 float4
        int r = idx >> 5;
        int k = (idx & 31) << 2;
        int gr = r0 + r; if (gr >= n) gr = n - 1;
        float4 u = *(const float4*)(A + (size_t)gr * 128 + k);
        int tile = r >> 4, m = r & 15;
        int ks = k >> 5, quad = (k >> 3) & 3, j0 = k & 7;
        int g = (tile * 4 + ks) * 4 + quad;
        union { unsigned short h[4]; uint2 u2; } pk;
        pk.h[0] = f2bf(u.x); pk.h[1] = f2bf(u.y); pk.h[2] = f2bf(u.z); pk.h[3] = f2bf(u.w);
        *(uint2*)(aLDS + g * 144 + m * 8 + j0) = pk.u2;
    }
    int lane = t & 63;
    int w = t >> 6;
    short8 bfr[4][4];
#pragma unroll
    for (int ks = 0; ks < 4; ks++)
#pragma unroll
        for (int nt = 0; nt < 4; nt++)
            bfr[ks][nt] = *(const short8*)(Wb + ((size_t)(ks * 4 + nt) * 64 + lane) * 8);
    __syncthreads();
    int quad = lane >> 4, m = lane & 15;
    short8 afr[4];
#pragma unroll
    for (int ks = 0; ks < 4; ks++)
        afr[ks] = *(const short8*)(aLDS + ((w * 4 + ks) * 4 + quad) * 144 + m * 8);
    float4v acc[4] = {};
#pragma unroll
    for (int nt = 0; nt < 4; nt++)
#pragma unroll
        for (int ks = 0; ks < 4; ks++)
            acc[nt] = __builtin_amdgcn_mfma_f32_16x16x32_bf16(afr[ks], bfr[ks][nt], acc[nt], 0, 0, 0);
    float dv[4];
#pragma unroll
    for (int reg = 0; reg < 4; reg++) {
        int gr = r0 + w * 16 + quad * 4 + reg;
        dv[reg] = (gr < n) ? dinv[gr] : 0.f;
    }
#pragma unroll
    for (int nt = 0; nt < 4; nt++)
#pragma unroll
        for (int reg = 0; reg < 4; reg++) {
            int gr = r0 + w * 16 + quad * 4 + reg;
            if (gr < n) Cb[(size_t)gr * 64 + nt * 16 + m] = f2bf(dv[reg] * acc[nt][reg]);
        }
}

// A input is bf16 (row-major n x 64) — staging is a pure uint4 copy.
__global__ __launch_bounds__(256) void k_gemm_64(const unsigned short* __restrict__ A,
                                                 const unsigned short* __restrict__ Wb,
                                                 const float* __restrict__ dinv,
                                                 unsigned short* __restrict__ Cb, int n) {
    __shared__ unsigned short aLDS[32 * 144];  // 9 KB
    int t = threadIdx.x;
    int r0 = blockIdx.x * 64;
    for (int idx = t; idx < 512; idx += 256) {   // 64 rows x 8 uint4
        int r = idx >> 3, j = idx & 7;
        int gr = r0 + r; if (gr >= n) gr = n - 1;
        uint4 u = *(const uint4*)(A + (size_t)gr * 64 + j * 8);
        int tile = r >> 4, m = r & 15;
        int ks = j >> 2, quad = j & 3;
        *(uint4*)(aLDS + ((tile * 2 + ks) * 4 + quad) * 144 + m * 8) = u;
    }
    int lane = t & 63;
    int w = t >> 6;
    short8 bfr[2][4];
#pragma unroll
    for (int ks = 0; ks < 2; ks++)
#pragma unroll
        for (int nt = 0; nt < 4; nt++)
            bfr[ks][nt] = *(const short8*)(Wb + ((size_t)(ks * 4 + nt) * 64 + lane) * 8);
    __syncthreads();
    int quad = lane >> 4, m = lane & 15;
    short8 afr[2];
#pragma unroll
    for (int ks = 0; ks < 2; ks++)
        afr[ks] = *(const short8*)(aLDS + ((w * 2 + ks) * 4 + quad) * 144 + m * 8);
    float4v acc[4] = {};
#pragma unroll
    for (int nt = 0; nt < 4; nt++)
#pragma unroll
        for (int ks = 0; ks < 2; ks++)
            acc[nt] = __builtin_amdgcn_mfma_f32_16x16x32_bf16(afr[ks], bfr[ks][nt], acc[nt], 0, 0, 0);
    float dv[4];
#pragma unroll
    for (int reg = 0; reg < 4; reg++) {
        int gr = r0 + w * 16 + quad * 4 + reg;
        dv[reg] = (gr < n) ? dinv[gr] : 0.f;
    }
#pragma unroll
    for (int nt = 0; nt < 4; nt++)
#pragma unroll
        for (int reg = 0; reg < 4; reg++) {
            int gr = r0 + w * 16 + quad * 4 + reg;
            if (gr < n) Cb[(size_t)gr * 64 + nt * 16 + m] = f2bf(dv[reg] * acc[nt][reg]);
        }
}

// ---------------- MFMA head GEMM: O[n,40] (+)= Hb[n,64] @ Wf[64,40] (+ bf) ----------------
// add=0: O = Hb@Wf.  add=1: O += Hb@Wf + bf.
__global__ __launch_bounds__(256) void k_head(const unsigned short* __restrict__ Hb,
                                              const unsigned short* __restrict__ Wfb,
                                              const float* __restrict__ bfv,
                                              float* __restrict__ O, int n, int add) {
    __shared__ unsigned short aLDS[32 * 144];  // 9 KB
    int t = threadIdx.x;
    int r0 = blockIdx.x * 64;
    for (int idx = t; idx < 512; idx += 256) {
        int r = idx >> 3, j = idx & 7;
        int gr = r0 + r; if (gr >= n) gr = n - 1;
        uint4 u = *(const uint4*)(Hb + (size_t)gr * 64 + j * 8);
        int tile = r >> 4, m = r & 15;
        int ks = j >> 2, quad = j & 3;
        *(uint4*)(aLDS + ((tile * 2 + ks) * 4 + quad) * 144 + m * 8) = u;
    }
    int lane = t & 63;
    int w = t >> 6;
    short8 bfr[2][3];
#pragma unroll
    for (int ks = 0; ks < 2; ks++)
#pragma unroll
        for (int nt = 0; nt < 3; nt++)
            bfr[ks][nt] = *(const short8*)(Wfb + ((size_t)(ks * 3 + nt) * 64 + lane) * 8);
    __syncthreads();
    int quad = lane >> 4, m = lane & 15;
    short8 afr[2];
#pragma unroll
    for (int ks = 0; ks < 2; ks++)
        afr[ks] = *(const short8*)(aLDS + ((w * 2 + ks) * 4 + quad) * 144 + m * 8);
    float4v acc[3] = {};
#pragma unroll
    for (int nt = 0; nt < 3; nt++)
#pragma unroll
        for (int ks = 0; ks < 2; ks++)
            acc[nt] = __builtin_amdgcn_mfma_f32_16x16x32_bf16(afr[ks], bfr[ks][nt], acc[nt], 0, 0, 0);
#pragma unroll
    for (int nt = 0; nt < 3; nt++) {
        int col = nt * 16 + m;
        if (col < 40) {
            float bb = add ? bfv[col] : 0.f;
#pragma unroll
            for (int reg = 0; reg < 4; reg++) {
                int gr = r0 + w * 16 + quad * 4 + reg;
                if (gr < n) {
                    size_t p = (size_t)gr * 40 + col;
                    if (add) O[p] = O[p] + acc[nt][reg] + bb;
                    else     O[p] = acc[nt][reg];
                }
            }
        }
    }
}

// ---------------- aggregation: wave/node, 8 lane-groups x 8 feature-lanes ----------------
// uint4 (16 B) row loads; T is dinv-folded bf16; output Hb bf16.
// H[v] = elu( dv*(T'[v] + sum T'[s]) + bias )
__global__ __launch_bounds__(256) void k_agg(const unsigned short* __restrict__ T,
                                             const int* __restrict__ csr,
                                             const int* __restrict__ roffE,  // END offsets
                                             const float* __restrict__ bias,
                                             unsigned short* __restrict__ Hb, int n) {
    int lane = threadIdx.x & 63;
    int q = lane >> 3, h = lane & 7;
    int v = blockIdx.x * 4 + (threadIdx.x >> 6);
    if (v >= n) return;
    int start = (v == 0) ? 0 : roffE[v - 1];
    int end = roffE[v];
    float dv = rsqrtf((float)(end - start + 1));
    float acc[8] = {0.f, 0.f, 0.f, 0.f, 0.f, 0.f, 0.f, 0.f};
    if (q == 0) {  // self-loop row
        uint4 u = *(const uint4*)(T + (size_t)v * 64 + h * 8);
        addu4(acc, u);
    }
    for (int base = start; base < end; base += 64) {
        int m = end - base; if (m > 64) m = 64;
        int e = (lane < m) ? csr[base + lane] : 0;
        int j = 0;
        for (; j + 32 <= m; j += 32) {
            int s0 = __shfl(e, j + q);
            int s1 = __shfl(e, j + 8 + q);
            int s2 = __shfl(e, j + 16 + q);
            int s3 = __shfl(e, j + 24 + q);
            uint4 u0 = *(const uint4*)(T + (size_t)s0 * 64 + h * 8);
            uint4 u1 = *(const uint4*)(T + (size_t)s1 * 64 + h * 8);
            uint4 u2 = *(const uint4*)(T + (size_t)s2 * 64 + h * 8);
            uint4 u3 = *(const uint4*)(T + (size_t)s3 * 64 + h * 8);
            addu4(acc, u0); addu4(acc, u1); addu4(acc, u2); addu4(acc, u3);
        }
        if (j + 16 <= m) {
            int s0 = __shfl(e, j + q);
            int s1 = __shfl(e, j + 8 + q);
            uint4 u0 = *(const uint4*)(T + (size_t)s0 * 64 + h * 8);
            uint4 u1 = *(const uint4*)(T + (size_t)s1 * 64 + h * 8);
            addu4(acc, u0); addu4(acc, u1);
            j += 16;
        }
        if (j + 8 <= m) {
            int s = __shfl(e, j + q);
            uint4 u = *(const uint4*)(T + (size_t)s * 64 + h * 8);
            addu4(acc, u);
            j += 8;
        }
        if (j < m) {
            int jj = j + q;
            int s = __shfl(e, jj & 63);
            if (jj < m) {
                uint4 u = *(const uint4*)(T + (size_t)s * 64 + h * 8);
                addu4(acc, u);
            }
        }
    }
#pragma unroll
    for (int i = 0; i < 8; i++) {
        acc[i] += __shfl_xor(acc[i], 8);
        acc[i] += __shfl_xor(acc[i], 16);
        acc[i] += __shfl_xor(acc[i], 32);
    }
    if (q == 0) {
        float4 b0 = *(const float4*)(bias + h * 8);
        float4 b1 = *(const float4*)(bias + h * 8 + 4);
        float bb[8] = {b0.x, b0.y, b0.z, b0.w, b1.x, b1.y, b1.z, b1.w};
        union { unsigned short hh[8]; uint4 u; } p;
#pragma unroll
        for (int i = 0; i < 8; i++) {
            float r = dv * acc[i] + bb[i];
            r = (r > 0.f) ? r : (__expf(r) - 1.f);
            p.hh[i] = f2bf(r);
        }
        *(uint4*)(Hb + (size_t)v * 64 + h * 8) = p.u;
    }
}

// ---------------- launch ----------------

extern "C" void kernel_launch(void* const* d_in, const int* in_sizes, int n_in,
                              void* d_out, int out_size, void* d_ws, size_t ws_size,
                              hipStream_t stream) {
    const float* x       = (const float*)d_in[0];
    const int*   eidx    = (const int*)d_in[1];
    const float* conv0_w = (const float*)d_in[2];
    const float* conv0_b = (const float*)d_in[3];
    const float* lin0_w  = (const float*)d_in[4];
    const float* lin0_b  = (const float*)d_in[5];
    const float* conv1_w = (const float*)d_in[6];
    const float* conv1_b = (const float*)d_in[7];
    const float* lin1_w  = (const float*)d_in[8];
    const float* lin1_b  = (const float*)d_in[9];
    const float* out_w   = (const float*)d_in[10];
    const float* out_b   = (const float*)d_in[11];

    int n = in_sizes[0] / 128;
    int E = in_sizes[1] / 2;
    const int* src = eidx;
    const int* dst = eidx + E;
    int NB = (n + 255) >> 8;
    int gC = (E + CHUNK - 1) / CHUNK;

    char* wsb = (char*)d_ws;
    auto al = [](size_t v) { return (v + 4095) & ~(size_t)4095; };
    size_t o = 0;
    int*            Cmat  = (int*)(wsb + o);            o = al(o + (size_t)gC * 1024 * 4);
    int*            Omat  = (int*)(wsb + o);            o = al(o + (size_t)gC * 1024 * 4);
    int*            btot  = (int*)(wsb + o);            o = al(o + 1024 * 4);
    int*            boff  = (int*)(wsb + o);            o = al(o + 1025 * 4);
    float*          dinv  = (float*)(wsb + o);          o = al(o + (size_t)n * 4);
    int*            roff  = (int*)(wsb + o);            o = al(o + (size_t)n * 4);
    unsigned int*   part  = (unsigned int*)(wsb + o);   o = al(o + (size_t)E * 4);
    int*            csr   = (int*)(wsb + o);            o = al(o + (size_t)E * 4);
    float*          Wf0   = (float*)(wsb + o);          o = al(o + 2560 * 4);
    float*          Wf1   = (float*)(wsb + o);          o = al(o + 2560 * 4);
    float*          bfv   = (float*)(wsb + o);          o = al(o + 40 * 4);
    unsigned short* Wb0   = (unsigned short*)(wsb + o); o = al(o + 8192 * 2);
    unsigned short* Wb1   = (unsigned short*)(wsb + o); o = al(o + 4096 * 2);
    unsigned short* Wfb0  = (unsigned short*)(wsb + o); o = al(o + 3072 * 2);
    unsigned short* Wfb1  = (unsigned short*)(wsb + o); o = al(o + 3072 * 2);
    unsigned short* Ab    = (unsigned short*)(wsb + o); o = al(o + (size_t)n * 64 * 2);
    unsigned short* Hb    = (unsigned short*)(wsb + o); o = al(o + (size_t)n * 64 * 2);
    float* O = (float*)d_out;

    int gT = (n + 63) / 64;     // MFMA gemms: 64 rows/block
    int gV = (n + 3) / 4;

    // CSR build — fully deterministic offsets, no inter-block atomics, no memset
    k_count<<<gC, 256, 0, stream>>>(dst, Cmat, E);
    k_wscan<<<256, 256, 0, stream>>>(Cmat, Omat, btot, gC);
    k_bscan<<<1, 1024, 0, stream>>>(btot, boff);
    k_part2<<<gC, 256, 0, stream>>>(src, dst, Omat, boff, part, E);
    k_fill_local<<<NB, 256, 0, stream>>>(part, boff, dinv, roff, csr, n);
    k_fuse<<<(5160 + 255) / 256, 256, 0, stream>>>(lin0_w, lin0_b, lin1_w, lin1_b, out_w, out_b,
                                                   Wf0, Wf1, bfv);
    k_prepw<<<9, 256, 0, stream>>>(conv0_w, conv1_w, Wf0, Wf1, Wb0, Wb1, Wfb0, Wfb1);

    // layer 0
    k_gemm_128<<<gT, 256, 0, stream>>>(x, Wb0, dinv, Ab, n);
    k_agg<<<gV, 256, 0, stream>>>(Ab, csr, roff, conv0_b, Hb, n);
    // head contribution of h0 (write O = Hb @ Wf0 into d_out)
    k_head<<<gT, 256, 0, stream>>>(Hb, Wfb0, bfv, O, n, 0);
    // layer 1
    k_gemm_64<<<gT, 256, 0, stream>>>(Hb, Wb1, dinv, Ab, n);
    k_agg<<<gV, 256, 0, stream>>>(Ab, csr, roff, conv1_b, Hb, n);
    // final head: out = O + Hb @ Wf1 + bf
    k_head<<<gT, 256, 0, stream>>>(Hb, Wfb1, bfv, O, n, 1);
}

// Round 11
// 275.596 us; speedup vs baseline: 2.5752x; 1.0806x over previous
//
#include <hip/hip_runtime.h>

#define DEVFN __device__ __forceinline__

typedef __attribute__((ext_vector_type(8))) short short8;
typedef __attribute__((ext_vector_type(4))) float float4v;

DEVFN float bf2f(unsigned short u) {
    union { unsigned int i; float f; } c;
    c.i = ((unsigned int)u) << 16;
    return c.f;
}

DEVFN unsigned short f2bf(float f) {
    union { float f; unsigned int i; } c;
    c.f = f;
    unsigned int u = c.i;
    return (unsigned short)((u + 0x7FFFu + ((u >> 16) & 1u)) >> 16);  // RNE
}

// accumulate 8 bf16 (uint4) into 8 fp32
DEVFN void addu4(float* acc, uint4 u) {
    unsigned int w[4] = {u.x, u.y, u.z, u.w};
#pragma unroll
    for (int k = 0; k < 4; k++) {
        union { unsigned int i; float f; } lo, hi;
        lo.i = w[k] << 16;
        hi.i = w[k] & 0xFFFF0000u;
        acc[2 * k]     += lo.f;
        acc[2 * k + 1] += hi.f;
    }
}

// ---------------- deterministic 2-level bucket partition ----------------

#define CHUNK 4096

__global__ __launch_bounds__(256) void k_count(const int* __restrict__ dst,
                                               int* __restrict__ Cmat, int E) {
    __shared__ int lh[1024];
    int t = threadIdx.x;
    for (int b = t; b < 1024; b += 256) lh[b] = 0;
    __syncthreads();
    int i0 = blockIdx.x * CHUNK;
    int i1 = i0 + CHUNK; if (i1 > E) i1 = E;
    for (int i = i0 + t; i < i1; i += 256) atomicAdd(&lh[dst[i] >> 8], 1);
    __syncthreads();
    int* row = Cmat + (size_t)blockIdx.x * 1024;
    for (int b = t; b < 1024; b += 256) row[b] = lh[b];
}

__global__ __launch_bounds__(256) void k_wscan(const int* __restrict__ Cmat,
                                               int* __restrict__ Omat,
                                               int* __restrict__ btot, int gC) {
    int b = (blockIdx.x * 256 + threadIdx.x) >> 6;
    int lane = threadIdx.x & 63;
    int base = 0;
    for (int c0 = 0; c0 < gC; c0 += 64) {
        int c = c0 + lane;
        int x = (c < gC) ? Cmat[(size_t)c * 1024 + b] : 0;
        int orig = x;
#pragma unroll
        for (int off = 1; off < 64; off <<= 1) {
            int y = __shfl_up(x, off);
            if (lane >= off) x += y;
        }
        if (c < gC) Omat[(size_t)c * 1024 + b] = base + x - orig;
        base += __shfl(x, 63);
    }
    if (lane == 0) btot[b] = base;
}

__global__ __launch_bounds__(1024) void k_bscan(const int* __restrict__ btot,
                                                int* __restrict__ boff) {
    __shared__ int s[1024];
    int t = threadIdx.x;
    int v = btot[t];
    s[t] = v;
    __syncthreads();
    for (int o = 1; o < 1024; o <<= 1) {
        int x = (t >= o) ? s[t - o] : 0;
        __syncthreads();
        s[t] += x;
        __syncthreads();
    }
    boff[t] = s[t] - v;
    if (t == 1023) boff[1024] = s[t];
}

__global__ __launch_bounds__(256) void k_part2(const int* __restrict__ src,
                                               const int* __restrict__ dst,
                                               const int* __restrict__ Omat,
                                               const int* __restrict__ boff,
                                               unsigned int* __restrict__ part, int E) {
    __shared__ int lb[1024];
    __shared__ int lc[1024];
    int t = threadIdx.x;
    const int* orow = Omat + (size_t)blockIdx.x * 1024;
    for (int b = t; b < 1024; b += 256) {
        lb[b] = boff[b] + orow[b];
        lc[b] = 0;
    }
    __syncthreads();
    int i0 = blockIdx.x * CHUNK;
    int i1 = i0 + CHUNK; if (i1 > E) i1 = E;
    for (int i = i0 + t; i < i1; i += 256) {
        int d = dst[i];
        int b = d >> 8;
        int r = atomicAdd(&lc[b], 1);
        part[lb[b] + r] = (unsigned int)src[i] | ((unsigned int)(d & 255) << 24);
    }
}

__global__ __launch_bounds__(256) void k_fill_local(const unsigned int* __restrict__ part,
                                                    const int* __restrict__ boff,
                                                    float* __restrict__ dinv,
                                                    int* __restrict__ roff,
                                                    int* __restrict__ csr, int n) {
    __shared__ int lcnt[256];
    __shared__ int lsc[256];
    __shared__ int lcur[256];
    int b = blockIdx.x, t = threadIdx.x;
    int s0 = boff[b], s1 = boff[b + 1];
    lcnt[t] = 0;
    __syncthreads();
    for (int i = s0 + t; i < s1; i += 256) atomicAdd(&lcnt[part[i] >> 24], 1);
    __syncthreads();
    int v = lcnt[t];
    lsc[t] = v;
    __syncthreads();
    for (int o = 1; o < 256; o <<= 1) {
        int x = (t >= o) ? lsc[t - o] : 0;
        __syncthreads();
        lsc[t] += x;
        __syncthreads();
    }
    int excl = lsc[t] - v;
    int node = (b << 8) + t;
    if (node < n) {
        dinv[node] = rsqrtf((float)(v + 1));  // +1 self-loop
        roff[node] = s0 + excl + v;           // END offset
    }
    lcur[t] = s0 + excl;
    __syncthreads();
    for (int i = s0 + t; i < s1; i += 256) {
        unsigned int p = part[i];
        int pos = atomicAdd(&lcur[p >> 24], 1);
        csr[pos] = (int)(p & 0xFFFFFFu);
    }
}

// ---------------- fused prep: head-weight fusion + all B-fragment swizzles + bias ----------------
// Wb0: conv0_w (K=128, nt 0..3).  Wb1: conv1_w (K=64, nt 0..3).
// Wfb0/Wfb1: (lin @ out_w half) computed on the fly (K=64, nt 0..2, cols 40 padded to 48).
// bfv[40] = out_b + lin0_b@out_w_top + lin1_b@out_w_bot.
// Wb layout: [ks][nt][lane][j] bf16, value = W[ks*32 + (lane>>4)*8 + j][nt*16 + (lane&15)]
__global__ __launch_bounds__(256) void k_prep(const float* __restrict__ W0,
                                              const float* __restrict__ W1,
                                              const float* __restrict__ lin0_w, const float* __restrict__ lin0_b,
                                              const float* __restrict__ lin1_w, const float* __restrict__ lin1_b,
                                              const float* __restrict__ out_w, const float* __restrict__ out_b,
                                              unsigned short* __restrict__ Wb0,
                                              unsigned short* __restrict__ Wb1,
                                              unsigned short* __restrict__ Wfb0,
                                              unsigned short* __restrict__ Wfb1,
                                              float* __restrict__ bfv) {
    int tid = blockIdx.x * 256 + threadIdx.x;
    if (tid < 1024) {
        int ks = tid >> 8, rem = tid & 255;
        int nt = rem >> 6, lane = rem & 63;
        int quad = lane >> 4, c = lane & 15;
        union { unsigned short h[8]; uint4 u; } p;
#pragma unroll
        for (int j = 0; j < 8; j++)
            p.h[j] = f2bf(W0[(ks * 32 + quad * 8 + j) * 64 + nt * 16 + c]);
        *(uint4*)(Wb0 + (size_t)tid * 8) = p.u;
    } else if (tid < 1536) {
        int t2 = tid - 1024;
        int ks = t2 >> 8, rem = t2 & 255;
        int nt = rem >> 6, lane = rem & 63;
        int quad = lane >> 4, c = lane & 15;
        union { unsigned short h[8]; uint4 u; } p;
#pragma unroll
        for (int j = 0; j < 8; j++)
            p.h[j] = f2bf(W1[(ks * 32 + quad * 8 + j) * 64 + nt * 16 + c]);
        *(uint4*)(Wb1 + (size_t)t2 * 8) = p.u;
    } else if (tid < 1920) {
        int t2 = tid - 1536;          // 0..383
        int ks = t2 / 192;
        int rem = t2 % 192;
        int nt = rem >> 6, lane = rem & 63;
        int quad = lane >> 4, c = lane & 15;
        int col = nt * 16 + c;
        union { unsigned short h[8]; uint4 u; } p;
#pragma unroll
        for (int j = 0; j < 8; j++) {
            unsigned short r = 0;
            if (col < 40) {
                int i = ks * 32 + quad * 8 + j;
                float a = 0.f;
                for (int k = 0; k < 64; k++) a += lin0_w[i * 64 + k] * out_w[k * 40 + col];
                r = f2bf(a);
            }
            p.h[j] = r;
        }
        *(uint4*)(Wfb0 + ((size_t)(ks * 3 + nt) * 64 + lane) * 8) = p.u;
    } else if (tid < 2304) {
        int t2 = tid - 1920;
        int ks = t2 / 192;
        int rem = t2 % 192;
        int nt = rem >> 6, lane = rem & 63;
        int quad = lane >> 4, c = lane & 15;
        int col = nt * 16 + c;
        union { unsigned short h[8]; uint4 u; } p;
#pragma unroll
        for (int j = 0; j < 8; j++) {
            unsigned short r = 0;
            if (col < 40) {
                int i = ks * 32 + quad * 8 + j;
                float a = 0.f;
                for (int k = 0; k < 64; k++) a += lin1_w[i * 64 + k] * out_w[(64 + k) * 40 + col];
                r = f2bf(a);
            }
            p.h[j] = r;
        }
        *(uint4*)(Wfb1 + ((size_t)(ks * 3 + nt) * 64 + lane) * 8) = p.u;
    } else if (tid < 2344) {
        int j = tid - 2304;
        float a = out_b[j];
        for (int k = 0; k < 64; k++) {
            a += lin0_b[k] * out_w[k * 40 + j];
            a += lin1_b[k] * out_w[(64 + k) * 40 + j];
        }
        bfv[j] = a;
    }
}

// ---------------- MFMA transform GEMM (layer 0, fp32 input K=128) ----------------

__global__ __launch_bounds__(256) void k_gemm_128(const float* __restrict__ A,
                                                  const unsigned short* __restrict__ Wb,
                                                  const float* __restrict__ dinv,
                                                  unsigned short* __restrict__ Cb, int n) {
    __shared__ unsigned short aLDS[64 * 144];  // 18 KB
    int t = threadIdx.x;
    int r0 = blockIdx.x * 64;
    for (int idx = t; idx < 2048; idx += 256) {   // 64 rows x 32 float4
        int r = idx >> 5;
        int k = (idx & 31) << 2;
        int gr = r0 + r; if (gr >= n) gr = n - 1;
        float4 u = *(const float4*)(A + (size_t)gr * 128 + k);
        int tile = r >> 4, m = r & 15;
        int ks = k >> 5, quad = (k >> 3) & 3, j0 = k & 7;
        int g = (tile * 4 + ks) * 4 + quad;
        union { unsigned short h[4]; uint2 u2; } pk;
        pk.h[0] = f2bf(u.x); pk.h[1] = f2bf(u.y); pk.h[2] = f2bf(u.z); pk.h[3] = f2bf(u.w);
        *(uint2*)(aLDS + g * 144 + m * 8 + j0) = pk.u2;
    }
    int lane = t & 63;
    int w = t >> 6;
    short8 bfr[4][4];
#pragma unroll
    for (int ks = 0; ks < 4; ks++)
#pragma unroll
        for (int nt = 0; nt < 4; nt++)
            bfr[ks][nt] = *(const short8*)(Wb + ((size_t)(ks * 4 + nt) * 64 + lane) * 8);
    __syncthreads();
    int quad = lane >> 4, m = lane & 15;
    short8 afr[4];
#pragma unroll
    for (int ks = 0; ks < 4; ks++)
        afr[ks] = *(const short8*)(aLDS + ((w * 4 + ks) * 4 + quad) * 144 + m * 8);
    float4v acc[4] = {};
#pragma unroll
    for (int nt = 0; nt < 4; nt++)
#pragma unroll
        for (int ks = 0; ks < 4; ks++)
            acc[nt] = __builtin_amdgcn_mfma_f32_16x16x32_bf16(afr[ks], bfr[ks][nt], acc[nt], 0, 0, 0);
    float dv[4];
#pragma unroll
    for (int reg = 0; reg < 4; reg++) {
        int gr = r0 + w * 16 + quad * 4 + reg;
        dv[reg] = (gr < n) ? dinv[gr] : 0.f;
    }
#pragma unroll
    for (int nt = 0; nt < 4; nt++)
#pragma unroll
        for (int reg = 0; reg < 4; reg++) {
            int gr = r0 + w * 16 + quad * 4 + reg;
            if (gr < n) Cb[(size_t)gr * 64 + nt * 16 + m] = f2bf(dv[reg] * acc[nt][reg]);
        }
}

// ---------------- fused mid kernel: Ab = dinv*(Hb@conv1_w), O = Hb@Wf0 ----------------
// One Hb staging feeds both MFMA weight sets.
__global__ __launch_bounds__(256) void k_mid(const unsigned short* __restrict__ Hb,
                                             const unsigned short* __restrict__ Wb,    // conv1, 2ks x 4nt
                                             const unsigned short* __restrict__ Wfb,   // head0, 2ks x 3nt
                                             const float* __restrict__ dinv,
                                             unsigned short* __restrict__ Ab,
                                             float* __restrict__ O, int n) {
    __shared__ unsigned short aLDS[32 * 144];  // 9 KB
    int t = threadIdx.x;
    int r0 = blockIdx.x * 64;
    for (int idx = t; idx < 512; idx += 256) {
        int r = idx >> 3, j = idx & 7;
        int gr = r0 + r; if (gr >= n) gr = n - 1;
        uint4 u = *(const uint4*)(Hb + (size_t)gr * 64 + j * 8);
        int tile = r >> 4, m = r & 15;
        int ks = j >> 2, quad = j & 3;
        *(uint4*)(aLDS + ((tile * 2 + ks) * 4 + quad) * 144 + m * 8) = u;
    }
    int lane = t & 63;
    int w = t >> 6;
    short8 bG[2][4], bH[2][3];
#pragma unroll
    for (int ks = 0; ks < 2; ks++) {
#pragma unroll
        for (int nt = 0; nt < 4; nt++)
            bG[ks][nt] = *(const short8*)(Wb + ((size_t)(ks * 4 + nt) * 64 + lane) * 8);
#pragma unroll
        for (int nt = 0; nt < 3; nt++)
            bH[ks][nt] = *(const short8*)(Wfb + ((size_t)(ks * 3 + nt) * 64 + lane) * 8);
    }
    __syncthreads();
    int quad = lane >> 4, m = lane & 15;
    short8 afr[2];
#pragma unroll
    for (int ks = 0; ks < 2; ks++)
        afr[ks] = *(const short8*)(aLDS + ((w * 2 + ks) * 4 + quad) * 144 + m * 8);
    float4v accG[4] = {};
    float4v accH[3] = {};
#pragma unroll
    for (int nt = 0; nt < 4; nt++)
#pragma unroll
        for (int ks = 0; ks < 2; ks++)
            accG[nt] = __builtin_amdgcn_mfma_f32_16x16x32_bf16(afr[ks], bG[ks][nt], accG[nt], 0, 0, 0);
#pragma unroll
    for (int nt = 0; nt < 3; nt++)
#pragma unroll
        for (int ks = 0; ks < 2; ks++)
            accH[nt] = __builtin_amdgcn_mfma_f32_16x16x32_bf16(afr[ks], bH[ks][nt], accH[nt], 0, 0, 0);
    float dv[4];
#pragma unroll
    for (int reg = 0; reg < 4; reg++) {
        int gr = r0 + w * 16 + quad * 4 + reg;
        dv[reg] = (gr < n) ? dinv[gr] : 0.f;
    }
#pragma unroll
    for (int nt = 0; nt < 4; nt++)
#pragma unroll
        for (int reg = 0; reg < 4; reg++) {
            int gr = r0 + w * 16 + quad * 4 + reg;
            if (gr < n) Ab[(size_t)gr * 64 + nt * 16 + m] = f2bf(dv[reg] * accG[nt][reg]);
        }
#pragma unroll
    for (int nt = 0; nt < 3; nt++) {
        int col = nt * 16 + m;
        if (col < 40) {
#pragma unroll
            for (int reg = 0; reg < 4; reg++) {
                int gr = r0 + w * 16 + quad * 4 + reg;
                if (gr < n) O[(size_t)gr * 40 + col] = accH[nt][reg];
            }
        }
    }
}

// ---------------- final head: O += Hb @ Wf1 + bf ----------------
__global__ __launch_bounds__(256) void k_head(const unsigned short* __restrict__ Hb,
                                              const unsigned short* __restrict__ Wfb,
                                              const float* __restrict__ bfv,
                                              float* __restrict__ O, int n) {
    __shared__ unsigned short aLDS[32 * 144];  // 9 KB
    int t = threadIdx.x;
    int r0 = blockIdx.x * 64;
    for (int idx = t; idx < 512; idx += 256) {
        int r = idx >> 3, j = idx & 7;
        int gr = r0 + r; if (gr >= n) gr = n - 1;
        uint4 u = *(const uint4*)(Hb + (size_t)gr * 64 + j * 8);
        int tile = r >> 4, m = r & 15;
        int ks = j >> 2, quad = j & 3;
        *(uint4*)(aLDS + ((tile * 2 + ks) * 4 + quad) * 144 + m * 8) = u;
    }
    int lane = t & 63;
    int w = t >> 6;
    short8 bfr[2][3];
#pragma unroll
    for (int ks = 0; ks < 2; ks++)
#pragma unroll
        for (int nt = 0; nt < 3; nt++)
            bfr[ks][nt] = *(const short8*)(Wfb + ((size_t)(ks * 3 + nt) * 64 + lane) * 8);
    __syncthreads();
    int quad = lane >> 4, m = lane & 15;
    short8 afr[2];
#pragma unroll
    for (int ks = 0; ks < 2; ks++)
        afr[ks] = *(const short8*)(aLDS + ((w * 2 + ks) * 4 + quad) * 144 + m * 8);
    float4v acc[3] = {};
#pragma unroll
    for (int nt = 0; nt < 3; nt++)
#pragma unroll
        for (int ks = 0; ks < 2; ks++)
            acc[nt] = __builtin_amdgcn_mfma_f32_16x16x32_bf16(afr[ks], bfr[ks][nt], acc[nt], 0, 0, 0);
#pragma unroll
    for (int nt = 0; nt < 3; nt++) {
        int col = nt * 16 + m;
        if (col < 40) {
            float bb = bfv[col];
#pragma unroll
            for (int reg = 0; reg < 4; reg++) {
                int gr = r0 + w * 16 + quad * 4 + reg;
                if (gr < n) {
                    size_t p = (size_t)gr * 40 + col;
                    O[p] = O[p] + acc[nt][reg] + bb;
                }
            }
        }
    }
}

// ---------------- aggregation: 2 nodes/wave, 4 lane-groups x 8 feature-lanes per node ----------------
// Half-wave (32 lanes) = one node. uint4 (16 B) row loads; deg-16 node issues 4 loads/lane.
// T is dinv-folded bf16; output Hb bf16.  H[v] = elu( dv*(T'[v] + sum T'[s]) + bias )
__global__ __launch_bounds__(256) void k_agg(const unsigned short* __restrict__ T,
                                             const int* __restrict__ csr,
                                             const int* __restrict__ roffE,  // END offsets
                                             const float* __restrict__ bias,
                                             unsigned short* __restrict__ Hb, int n) {
    int lane = threadIdx.x & 63;
    int half = lane >> 5;              // node within the wave
    int sub = lane & 31;
    int q = sub >> 3, h = sub & 7;     // 4 groups x 8 feature-lanes
    int hb = half << 5;                // shfl base for this node's csr lanes
    int v = blockIdx.x * 8 + ((threadIdx.x >> 6) << 1) + half;
    if (v >= n) return;
    int start = (v == 0) ? 0 : roffE[v - 1];
    int end = roffE[v];
    float dv = rsqrtf((float)(end - start + 1));
    float acc[8] = {0.f, 0.f, 0.f, 0.f, 0.f, 0.f, 0.f, 0.f};
    if (q == 0) {  // self-loop row
        uint4 u = *(const uint4*)(T + (size_t)v * 64 + h * 8);
        addu4(acc, u);
    }
    for (int base = start; base < end; base += 32) {
        int m = end - base; if (m > 32) m = 32;
        int e = (sub < m) ? csr[base + sub] : 0;
        int j = 0;
        for (; j + 16 <= m; j += 16) {
            int s0 = __shfl(e, hb + j + q);
            int s1 = __shfl(e, hb + j + 4 + q);
            int s2 = __shfl(e, hb + j + 8 + q);
            int s3 = __shfl(e, hb + j + 12 + q);
            uint4 u0 = *(const uint4*)(T + (size_t)s0 * 64 + h * 8);
            uint4 u1 = *(const uint4*)(T + (size_t)s1 * 64 + h * 8);
            uint4 u2 = *(const uint4*)(T + (size_t)s2 * 64 + h * 8);
            uint4 u3 = *(const uint4*)(T + (size_t)s3 * 64 + h * 8);
            addu4(acc, u0); addu4(acc, u1); addu4(acc, u2); addu4(acc, u3);
        }
        if (j + 8 <= m) {
            int s0 = __shfl(e, hb + j + q);
            int s1 = __shfl(e, hb + j + 4 + q);
            uint4 u0 = *(const uint4*)(T + (size_t)s0 * 64 + h * 8);
            uint4 u1 = *(const uint4*)(T + (size_t)s1 * 64 + h * 8);
            addu4(acc, u0); addu4(acc, u1);
            j += 8;
        }
        if (j + 4 <= m) {
            int s = __shfl(e, hb + j + q);
            uint4 u = *(const uint4*)(T + (size_t)s * 64 + h * 8);
            addu4(acc, u);
            j += 4;
        }
        if (j < m) {
            int jj = j + q;
            int s = __shfl(e, hb + (jj & 31));
            if (jj < m) {
                uint4 u = *(const uint4*)(T + (size_t)s * 64 + h * 8);
                addu4(acc, u);
            }
        }
    }
#pragma unroll
    for (int i = 0; i < 8; i++) {
        acc[i] += __shfl_xor(acc[i], 8);
        acc[i] += __shfl_xor(acc[i], 16);
    }
    if (q == 0) {
        float4 b0 = *(const float4*)(bias + h * 8);
        float4 b1 = *(const float4*)(bias + h * 8 + 4);
        float bb[8] = {b0.x, b0.y, b0.z, b0.w, b1.x, b1.y, b1.z, b1.w};
        union { unsigned short hh[8]; uint4 u; } p;
#pragma unroll
        for (int i = 0; i < 8; i++) {
            float r = dv * acc[i] + bb[i];
            r = (r > 0.f) ? r : (__expf(r) - 1.f);
            p.hh[i] = f2bf(r);
        }
        *(uint4*)(Hb + (size_t)v * 64 + h * 8) = p.u;
    }
}

// ---------------- launch ----------------

extern "C" void kernel_launch(void* const* d_in, const int* in_sizes, int n_in,
                              void* d_out, int out_size, void* d_ws, size_t ws_size,
                              hipStream_t stream) {
    const float* x       = (const float*)d_in[0];
    const int*   eidx    = (const int*)d_in[1];
    const float* conv0_w = (const float*)d_in[2];
    const float* conv0_b = (const float*)d_in[3];
    const float* lin0_w  = (const float*)d_in[4];
    const float* lin0_b  = (const float*)d_in[5];
    const float* conv1_w = (const float*)d_in[6];
    const float* conv1_b = (const float*)d_in[7];
    const float* lin1_w  = (const float*)d_in[8];
    const float* lin1_b  = (const float*)d_in[9];
    const float* out_w   = (const float*)d_in[10];
    const float* out_b   = (const float*)d_in[11];

    int n = in_sizes[0] / 128;
    int E = in_sizes[1] / 2;
    const int* src = eidx;
    const int* dst = eidx + E;
    int NB = (n + 255) >> 8;
    int gC = (E + CHUNK - 1) / CHUNK;

    char* wsb = (char*)d_ws;
    auto al = [](size_t v) { return (v + 4095) & ~(size_t)4095; };
    size_t o = 0;
    int*            Cmat  = (int*)(wsb + o);            o = al(o + (size_t)gC * 1024 * 4);
    int*            Omat  = (int*)(wsb + o);            o = al(o + (size_t)gC * 1024 * 4);
    int*            btot  = (int*)(wsb + o);            o = al(o + 1024 * 4);
    int*            boff  = (int*)(wsb + o);            o = al(o + 1025 * 4);
    float*          dinv  = (float*)(wsb + o);          o = al(o + (size_t)n * 4);
    int*            roff  = (int*)(wsb + o);            o = al(o + (size_t)n * 4);
    unsigned int*   part  = (unsigned int*)(wsb + o);   o = al(o + (size_t)E * 4);
    int*            csr   = (int*)(wsb + o);            o = al(o + (size_t)E * 4);
    float*          bfv   = (float*)(wsb + o);          o = al(o + 40 * 4);
    unsigned short* Wb0   = (unsigned short*)(wsb + o); o = al(o + 8192 * 2);
    unsigned short* Wb1   = (unsigned short*)(wsb + o); o = al(o + 4096 * 2);
    unsigned short* Wfb0  = (unsigned short*)(wsb + o); o = al(o + 3072 * 2);
    unsigned short* Wfb1  = (unsigned short*)(wsb + o); o = al(o + 3072 * 2);
    unsigned short* Ab    = (unsigned short*)(wsb + o); o = al(o + (size_t)n * 64 * 2);
    unsigned short* Hb    = (unsigned short*)(wsb + o); o = al(o + (size_t)n * 64 * 2);
    float* O = (float*)d_out;

    int gT = (n + 63) / 64;     // MFMA gemms: 64 rows/block
    int gV = (n + 7) / 8;       // agg: 8 nodes/block (2 per wave)

    // CSR build — fully deterministic offsets, no inter-block atomics, no memset
    k_count<<<gC, 256, 0, stream>>>(dst, Cmat, E);
    k_wscan<<<256, 256, 0, stream>>>(Cmat, Omat, btot, gC);
    k_bscan<<<1, 1024, 0, stream>>>(btot, boff);
    k_part2<<<gC, 256, 0, stream>>>(src, dst, Omat, boff, part, E);
    k_fill_local<<<NB, 256, 0, stream>>>(part, boff, dinv, roff, csr, n);
    k_prep<<<10, 256, 0, stream>>>(conv0_w, conv1_w, lin0_w, lin0_b, lin1_w, lin1_b,
                                   out_w, out_b, Wb0, Wb1, Wfb0, Wfb1, bfv);

    // layer 0
    k_gemm_128<<<gT, 256, 0, stream>>>(x, Wb0, dinv, Ab, n);
    k_agg<<<gV, 256, 0, stream>>>(Ab, csr, roff, conv0_b, Hb, n);
    // fused: Ab = dinv*(Hb@conv1_w), O = Hb@Wf0
    k_mid<<<gT, 256, 0, stream>>>(Hb, Wb1, Wfb0, dinv, Ab, O, n);
    // layer 1
    k_agg<<<gV, 256, 0, stream>>>(Ab, csr, roff, conv1_b, Hb, n);
    // final head: O += Hb @ Wf1 + bf
    k_head<<<gT, 256, 0, stream>>>(Hb, Wfb1, bfv, O, n);
}